// Round 4
// baseline (22719.670 us; speedup 1.0000x reference)
//
#include <hip/hip_runtime.h>
#include <hip/hip_cooperative_groups.h>
#include <math.h>

namespace cg = cooperative_groups;

#define NN 20000
#define FF 32
#define TT 12
#define HH 64
#define EE 320000
#define OUTD 12

constexpr int NT = (NN + 63) / 64;   // 313 row tiles

__device__ __forceinline__ float sigmoidf_(float x) { return 1.f / (1.f + expf(-x)); }

// ---------------- preprocessing ----------------

__global__ void deg_init_kernel(float* deg) {
    int i = blockIdx.x * 256 + threadIdx.x;
    if (i < NN) deg[i] = 1.0f;   // self-loop weight 1
}

__global__ void edge_accum_kernel(const int* ei, const float* ea, float* deg, int* cnt) {
    int e = blockIdx.x * 256 + threadIdx.x;
    if (e >= EE) return;
    int d = ei[EE + e];
    float w = ea[e * 2 + 1];
    atomicAdd(&deg[d], w);
    atomicAdd(&cnt[d], 1);
}

__global__ void dinv_kernel(const float* deg, float* dinv) {
    int i = blockIdx.x * 256 + threadIdx.x;
    if (i < NN) dinv[i] = rsqrtf(deg[i]);
}

__global__ void scan_kernel(const int* cnt, int* rowptr, int* cursor) {
    __shared__ int wsum[16];
    int tid = threadIdx.x;
    int lane = tid & 63, w = tid >> 6;
    int run = 0;
    for (int base = 0; base < NN; base += 1024) {
        int idx = base + tid;
        int c = (idx < NN) ? cnt[idx] : 0;
        int v = c;
        #pragma unroll
        for (int off = 1; off < 64; off <<= 1) {
            int t = __shfl_up(v, off, 64);
            if (lane >= off) v += t;
        }
        if (lane == 63) wsum[w] = v;
        __syncthreads();
        if (tid < 16) {
            int x = wsum[tid];
            #pragma unroll
            for (int off = 1; off < 16; off <<= 1) {
                int t = __shfl_up(x, off, 64);
                if (tid >= off) x += t;
            }
            wsum[tid] = x;
        }
        __syncthreads();
        int waveoff = (w > 0) ? wsum[w - 1] : 0;
        int excl = run + waveoff + (v - c);
        if (idx < NN) { rowptr[idx] = excl; cursor[idx] = excl; }
        run += wsum[15];
        __syncthreads();
    }
    if (tid == 0) rowptr[NN] = run;
}

__global__ void fill_kernel(const int* ei, const float* ea, const float* dinv,
                            int* cursor, int* colIdx, float* valArr) {
    int e = blockIdx.x * 256 + threadIdx.x;
    if (e >= EE) return;
    int s = ei[e], d = ei[EE + e];
    float w = ea[e * 2 + 1];
    int pos = atomicAdd(&cursor[d], 1);
    colIdx[pos] = s;
    valArr[pos] = dinv[s] * w * dinv[d];
}

__global__ void transpose_kernel(const float* x, float* xT) {
    int i = blockIdx.x * 256 + threadIdx.x;
    if (i >= TT * NN * FF) return;
    int f = i & 31;
    int rest = i >> 5;
    int n = rest % NN;
    int t = rest / NN;
    xT[i] = x[n * (FF * TT) + f * TT + t];
}

__global__ void ipwT_kernel(const float* ipw, float* ipwT) {
    int i = blockIdx.x * 256 + threadIdx.x;
    if (i >= 192 * 64) return;
    int k = i / 192, j = i % 192;
    ipwT[i] = ipw[j * 64 + k];
}

// raw normalized aggregation, width-32 (for x, all t at once)
__global__ void gather_raw32(const float* __restrict__ srcbase, const float* __restrict__ dinv,
                             const int* __restrict__ rowptr, const int* __restrict__ colIdx,
                             const float* __restrict__ valArr, float* __restrict__ dstbase) {
    const float* src = srcbase + (size_t)blockIdx.y * NN * 32;
    float* dst = dstbase + (size_t)blockIdx.y * NN * 32;
    int node = blockIdx.x * 8 + threadIdx.x / 32;
    int lane = threadIdx.x % 32;
    float di = dinv[node];
    float acc = di * di * src[node * 32 + lane];
    int s = rowptr[node], e = rowptr[node + 1];
    int j = s;
    for (; j + 3 < e; j += 4) {
        int c0 = colIdx[j], c1 = colIdx[j + 1], c2 = colIdx[j + 2], c3 = colIdx[j + 3];
        float v0 = valArr[j], v1 = valArr[j + 1], v2 = valArr[j + 2], v3 = valArr[j + 3];
        acc += v0 * src[c0 * 32 + lane] + v1 * src[c1 * 32 + lane]
             + v2 * src[c2 * 32 + lane] + v3 * src[c3 * 32 + lane];
    }
    for (; j < e; ++j) acc += valArr[j] * src[colIdx[j] * 32 + lane];
    dst[node * 32 + lane] = acc;
}

// ---------------- standalone tiled GEMM (pre/post phases) ----------------
// EPI 0: out0 = sigmoid(acc + bias)
// EPI 1: out0[row*ostr + y*64 + col] = acc + bias  (qkv strips)
template<int K, int EPI>
__launch_bounds__(256, 2)
__global__ void gemm64(const float* __restrict__ A1,
                       const float* __restrict__ B0, const float* __restrict__ B1,
                       const float* __restrict__ B2, int brstride,
                       const float* __restrict__ b0, const float* __restrict__ b1,
                       const float* __restrict__ b2,
                       float* __restrict__ out0, int ostr, int nrows) {
    __shared__ __align__(16) float AsT[32 * 68];
    __shared__ __align__(16) float Bs[32 * 68];
    const int tid = threadIdx.x;
    const int tx = tid & 15, ty = tid >> 4;
    const int row0 = blockIdx.x * 64;
    const int y = blockIdx.y;
    const float* B = (y == 0) ? B0 : ((y == 1) ? B1 : B2);
    const float* bias = (y == 0) ? b0 : ((y == 1) ? b1 : b2);

    float acc[4][4];
    #pragma unroll
    for (int i = 0; i < 4; ++i)
        #pragma unroll
        for (int j = 0; j < 4; ++j) acc[i][j] = 0.f;

    for (int kc = 0; kc < K; kc += 32) {
        #pragma unroll
        for (int i = 0; i < 8; ++i) {
            int idx = tid + i * 256;
            int kk = idx & 31, rr = idx >> 5;
            int grow = row0 + rr;
            AsT[kk * 68 + rr] = (grow < nrows) ? A1[(size_t)grow * K + kc + kk] : 0.f;
        }
        #pragma unroll
        for (int i = 0; i < 8; ++i) {
            int idx = tid + i * 256;
            int kk = idx >> 6, cc = idx & 63;
            Bs[kk * 68 + cc] = B[(size_t)(kc + kk) * brstride + cc];
        }
        __syncthreads();
        #pragma unroll
        for (int k = 0; k < 32; ++k) {
            float4 a4 = *reinterpret_cast<const float4*>(&AsT[k * 68 + ty * 4]);
            float4 b4 = *reinterpret_cast<const float4*>(&Bs[k * 68 + tx * 4]);
            float av[4] = {a4.x, a4.y, a4.z, a4.w};
            float bv[4] = {b4.x, b4.y, b4.z, b4.w};
            #pragma unroll
            for (int i = 0; i < 4; ++i)
                #pragma unroll
                for (int j = 0; j < 4; ++j) acc[i][j] += av[i] * bv[j];
        }
        __syncthreads();
    }

    #pragma unroll
    for (int i = 0; i < 4; ++i) {
        int row = row0 + ty * 4 + i;
        if (row >= nrows) continue;
        int colb = tx * 4;
        float4 r4;
        float* rv = (float*)&r4;
        if constexpr (EPI == 0) {
            #pragma unroll
            for (int j = 0; j < 4; ++j) rv[j] = sigmoidf_(acc[i][j] + bias[colb + j]);
            *reinterpret_cast<float4*>(&out0[(size_t)row * 64 + colb]) = r4;
        } else {
            #pragma unroll
            for (int j = 0; j < 4; ++j) rv[j] = acc[i][j] + bias[colb + j];
            *reinterpret_cast<float4*>(&out0[(size_t)row * ostr + y * 64 + colb]) = r4;
        }
    }
}

// ---------------- persistent cooperative GRU loop ----------------

struct GruParams {
    const float* xT; const float* g0all;
    const float* Wu0; const float* Wr0; const float* Wc0;
    const float* bu0; const float* br0; const float* bc0;
    const float* Wg1; const float* bg1;
    const float* Wu1; const float* Wr1; const float* Wc1;
    const float* bu1; const float* br1; const float* bc1;
    const float* dinv; const int* rowptr; const int* colIdx; const float* valArr;
    float* h0a; float* h0b; float* h1a; float* h1b;
    float* u; float* rh; float* pre1u; float* pre1r; float* pre1c;
    float* hseq;
};

// generic 64x64 tile GEMM: A via fetch functor, B = weight[k][64] row-major
template<int K, typename FA, typename EP>
__device__ __forceinline__ void tile_gemm(float* AsT, float* Bs,
                                          const float* __restrict__ W, int row0,
                                          FA fa, EP ep) {
    const int tid = threadIdx.x;
    const int tx = tid & 15, ty = tid >> 4;
    float acc[4][4];
    #pragma unroll
    for (int i = 0; i < 4; ++i)
        #pragma unroll
        for (int j = 0; j < 4; ++j) acc[i][j] = 0.f;

    for (int kc = 0; kc < K; kc += 32) {
        #pragma unroll
        for (int i = 0; i < 8; ++i) {
            int idx = tid + i * 256;
            int kk = idx & 31, rr = idx >> 5;
            int grow = row0 + rr;
            AsT[kk * 68 + rr] = (grow < NN) ? fa(grow, kc + kk) : 0.f;
        }
        #pragma unroll
        for (int i = 0; i < 8; ++i) {
            int idx = tid + i * 256;
            int kk = idx >> 6, cc = idx & 63;
            Bs[kk * 68 + cc] = W[(kc + kk) * 64 + cc];
        }
        __syncthreads();
        #pragma unroll
        for (int k = 0; k < 32; ++k) {
            float4 a4 = *reinterpret_cast<const float4*>(&AsT[k * 68 + ty * 4]);
            float4 b4 = *reinterpret_cast<const float4*>(&Bs[k * 68 + tx * 4]);
            float av[4] = {a4.x, a4.y, a4.z, a4.w};
            float bv[4] = {b4.x, b4.y, b4.z, b4.w};
            #pragma unroll
            for (int i = 0; i < 4; ++i)
                #pragma unroll
                for (int j = 0; j < 4; ++j) acc[i][j] += av[i] * bv[j];
        }
        __syncthreads();
    }
    ep(acc);
}

__launch_bounds__(256, 3)
__global__ void gru_persistent(GruParams P) {
    cg::grid_group grid = cg::this_grid();
    // LDS layout: AGG 64x65 (4160) | G1 64x65 (4160) | BS 32x68 (2176) ; AST aliases AGG
    __shared__ __align__(16) float smem[10496];
    float* AGG = smem;
    float* G1  = smem + 4160;
    float* BS  = smem + 8320;
    float* AST = smem;

    const int tid = threadIdx.x;
    const int tx = tid & 15, ty = tid >> 4;

    float* h0c = P.h0a; float* h0n = P.h0b;
    float* h1c = P.h1a; float* h1n = P.h1b;

    for (int t = 0; t < TT; ++t) {
        const float* xt = P.xT + (size_t)t * NN * FF;
        const float* g0 = P.g0all + (size_t)t * NN * HH;

        // ---- P1: u = sig([x|g0|h0]@Wu0+bu0), rh = sig(...Wr0+br0)*h0 ----
        for (int j = blockIdx.x; j < 2 * NT; j += gridDim.x) {
            int tile = j >> 1; int isr = j & 1;
            int row0 = tile * 64;
            const float* W = isr ? P.Wr0 : P.Wu0;
            const float* bb = isr ? P.br0 : P.bu0;
            tile_gemm<160>(AST, BS, W, row0,
                [&](int grow, int k) -> float {
                    if (k < 32) return xt[(size_t)grow * 32 + k];
                    if (k < 96) return g0[(size_t)grow * 64 + (k - 32)];
                    return h0c[(size_t)grow * 64 + (k - 96)];
                },
                [&](float (&acc)[4][4]) {
                    #pragma unroll
                    for (int i = 0; i < 4; ++i) {
                        int row = row0 + ty * 4 + i;
                        if (row >= NN) continue;
                        int colb = tx * 4;
                        float4 r4; float* rv = (float*)&r4;
                        if (!isr) {
                            #pragma unroll
                            for (int jj = 0; jj < 4; ++jj) rv[jj] = sigmoidf_(acc[i][jj] + bb[colb + jj]);
                            *reinterpret_cast<float4*>(&P.u[(size_t)row * 64 + colb]) = r4;
                        } else {
                            float4 h4 = *reinterpret_cast<const float4*>(&h0c[(size_t)row * 64 + colb]);
                            const float* hv = (const float*)&h4;
                            #pragma unroll
                            for (int jj = 0; jj < 4; ++jj) rv[jj] = sigmoidf_(acc[i][jj] + bb[colb + jj]) * hv[jj];
                            *reinterpret_cast<float4*>(&P.rh[(size_t)row * 64 + colb]) = r4;
                        }
                    }
                });
        }
        grid.sync();

        // ---- P2: c = tanh([x|g0|rh]@Wc0+bc0); h0' = u*h0+(1-u)*c ----
        for (int j = blockIdx.x; j < NT; j += gridDim.x) {
            int row0 = j * 64;
            tile_gemm<160>(AST, BS, P.Wc0, row0,
                [&](int grow, int k) -> float {
                    if (k < 32) return xt[(size_t)grow * 32 + k];
                    if (k < 96) return g0[(size_t)grow * 64 + (k - 32)];
                    return P.rh[(size_t)grow * 64 + (k - 96)];
                },
                [&](float (&acc)[4][4]) {
                    #pragma unroll
                    for (int i = 0; i < 4; ++i) {
                        int row = row0 + ty * 4 + i;
                        if (row >= NN) continue;
                        int colb = tx * 4;
                        float4 u4 = *reinterpret_cast<const float4*>(&P.u[(size_t)row * 64 + colb]);
                        float4 h4 = *reinterpret_cast<const float4*>(&h0c[(size_t)row * 64 + colb]);
                        const float* uv = (const float*)&u4;
                        const float* hv = (const float*)&h4;
                        float4 r4; float* rv = (float*)&r4;
                        #pragma unroll
                        for (int jj = 0; jj < 4; ++jj) {
                            float cval = tanhf(acc[i][jj] + P.bc0[colb + jj]);
                            rv[jj] = uv[jj] * hv[jj] + (1.f - uv[jj]) * cval;
                        }
                        *reinterpret_cast<float4*>(&h0n[(size_t)row * 64 + colb]) = r4;
                    }
                });
        }
        grid.sync();

        // ---- P34: gather(h0') -> g1 (LDS) -> pre1[strip] = [h0'|g1]@W1[0:128]+b1 ----
        for (int j = blockIdx.x; j < 3 * NT; j += gridDim.x) {
            int strip = j / NT;
            int tile = j - strip * NT;
            int row0 = tile * 64;
            // (a) gather into AGG
            {
                int lane = tid & 63, wv = tid >> 6;
                for (int nl = wv; nl < 64; nl += 4) {
                    int node = row0 + nl;
                    float a = 0.f;
                    if (node < NN) {
                        float di = P.dinv[node];
                        a = di * di * h0n[(size_t)node * 64 + lane];
                        int s = P.rowptr[node], e = P.rowptr[node + 1];
                        int jj = s;
                        for (; jj + 3 < e; jj += 4) {
                            int c0 = P.colIdx[jj], c1 = P.colIdx[jj + 1];
                            int c2 = P.colIdx[jj + 2], c3 = P.colIdx[jj + 3];
                            float v0 = P.valArr[jj], v1 = P.valArr[jj + 1];
                            float v2 = P.valArr[jj + 2], v3 = P.valArr[jj + 3];
                            a += v0 * h0n[(size_t)c0 * 64 + lane] + v1 * h0n[(size_t)c1 * 64 + lane]
                               + v2 * h0n[(size_t)c2 * 64 + lane] + v3 * h0n[(size_t)c3 * 64 + lane];
                        }
                        for (; jj < e; ++jj) a += P.valArr[jj] * h0n[(size_t)P.colIdx[jj] * 64 + lane];
                    }
                    AGG[nl * 65 + lane] = a;
                }
            }
            __syncthreads();
            // (b) g1 = sigmoid(AGG @ Wg1 + bg1) -> G1
            {
                float acc[4][4];
                #pragma unroll
                for (int i = 0; i < 4; ++i)
                    #pragma unroll
                    for (int jj = 0; jj < 4; ++jj) acc[i][jj] = 0.f;
                for (int kc = 0; kc < 64; kc += 32) {
                    #pragma unroll
                    for (int i = 0; i < 8; ++i) {
                        int idx = tid + i * 256;
                        int kk = idx >> 6, cc = idx & 63;
                        BS[kk * 68 + cc] = P.Wg1[(kc + kk) * 64 + cc];
                    }
                    __syncthreads();
                    #pragma unroll
                    for (int k = 0; k < 32; ++k) {
                        float av[4];
                        #pragma unroll
                        for (int i = 0; i < 4; ++i) av[i] = AGG[(ty * 4 + i) * 65 + kc + k];
                        float4 b4 = *reinterpret_cast<const float4*>(&BS[k * 68 + tx * 4]);
                        const float* bv = (const float*)&b4;
                        #pragma unroll
                        for (int i = 0; i < 4; ++i)
                            #pragma unroll
                            for (int jj = 0; jj < 4; ++jj) acc[i][jj] += av[i] * bv[jj];
                    }
                    __syncthreads();
                }
                #pragma unroll
                for (int i = 0; i < 4; ++i)
                    #pragma unroll
                    for (int jj = 0; jj < 4; ++jj)
                        G1[(ty * 4 + i) * 65 + tx * 4 + jj] = sigmoidf_(acc[i][jj] + P.bg1[tx * 4 + jj]);
            }
            __syncthreads();
            // (c) pre1[strip] = [h0'|g1] @ W1strip[0:128] + b1strip  (K=128)
            {
                const float* W1 = (strip == 0) ? P.Wu1 : (strip == 1) ? P.Wr1 : P.Wc1;
                const float* b1 = (strip == 0) ? P.bu1 : (strip == 1) ? P.br1 : P.bc1;
                float* dst = (strip == 0) ? P.pre1u : (strip == 1) ? P.pre1r : P.pre1c;
                float acc[4][4];
                #pragma unroll
                for (int i = 0; i < 4; ++i)
                    #pragma unroll
                    for (int jj = 0; jj < 4; ++jj) acc[i][jj] = 0.f;
                for (int kc = 0; kc < 128; kc += 32) {
                    #pragma unroll
                    for (int i = 0; i < 8; ++i) {
                        int idx = tid + i * 256;
                        int kk = idx & 31, rr = idx >> 5;
                        int k = kc + kk;
                        float v;
                        if (k < 64) {
                            int grow = row0 + rr;
                            v = (grow < NN) ? h0n[(size_t)grow * 64 + k] : 0.f;
                        } else {
                            v = G1[rr * 65 + (k - 64)];
                        }
                        AST[kk * 68 + rr] = v;
                    }
                    #pragma unroll
                    for (int i = 0; i < 8; ++i) {
                        int idx = tid + i * 256;
                        int kk = idx >> 6, cc = idx & 63;
                        BS[kk * 68 + cc] = W1[(kc + kk) * 64 + cc];
                    }
                    __syncthreads();
                    #pragma unroll
                    for (int k = 0; k < 32; ++k) {
                        float4 a4 = *reinterpret_cast<const float4*>(&AST[k * 68 + ty * 4]);
                        float4 b4 = *reinterpret_cast<const float4*>(&BS[k * 68 + tx * 4]);
                        const float* av = (const float*)&a4;
                        const float* bv = (const float*)&b4;
                        #pragma unroll
                        for (int i = 0; i < 4; ++i)
                            #pragma unroll
                            for (int jj = 0; jj < 4; ++jj) acc[i][jj] += av[i] * bv[jj];
                    }
                    __syncthreads();
                }
                #pragma unroll
                for (int i = 0; i < 4; ++i) {
                    int row = row0 + ty * 4 + i;
                    if (row >= NN) continue;
                    int colb = tx * 4;
                    float4 r4; float* rv = (float*)&r4;
                    #pragma unroll
                    for (int jj = 0; jj < 4; ++jj) rv[jj] = acc[i][jj] + b1[colb + jj];
                    *reinterpret_cast<float4*>(&dst[(size_t)row * 64 + colb]) = r4;
                }
            }
            __syncthreads();
        }
        grid.sync();

        // ---- P5: u1 = sig(h1@Wu1h + pre1u), rh1 = sig(h1@Wr1h + pre1r)*h1 ----
        for (int j = blockIdx.x; j < 2 * NT; j += gridDim.x) {
            int tile = j >> 1; int isr = j & 1;
            int row0 = tile * 64;
            const float* W = (isr ? P.Wr1 : P.Wu1) + 128 * 64;
            const float* pre = isr ? P.pre1r : P.pre1u;
            tile_gemm<64>(AST, BS, W, row0,
                [&](int grow, int k) -> float {
                    return h1c[(size_t)grow * 64 + k];
                },
                [&](float (&acc)[4][4]) {
                    #pragma unroll
                    for (int i = 0; i < 4; ++i) {
                        int row = row0 + ty * 4 + i;
                        if (row >= NN) continue;
                        int colb = tx * 4;
                        float4 p4 = *reinterpret_cast<const float4*>(&pre[(size_t)row * 64 + colb]);
                        const float* pv = (const float*)&p4;
                        float4 r4; float* rv = (float*)&r4;
                        if (!isr) {
                            #pragma unroll
                            for (int jj = 0; jj < 4; ++jj) rv[jj] = sigmoidf_(acc[i][jj] + pv[jj]);
                            *reinterpret_cast<float4*>(&P.u[(size_t)row * 64 + colb]) = r4;
                        } else {
                            float4 h4 = *reinterpret_cast<const float4*>(&h1c[(size_t)row * 64 + colb]);
                            const float* hv = (const float*)&h4;
                            #pragma unroll
                            for (int jj = 0; jj < 4; ++jj) rv[jj] = sigmoidf_(acc[i][jj] + pv[jj]) * hv[jj];
                            *reinterpret_cast<float4*>(&P.rh[(size_t)row * 64 + colb]) = r4;
                        }
                    }
                });
        }
        grid.sync();

        // ---- P6: c1 = tanh(rh1@Wc1h + pre1c); h1' = u1*h1+(1-u1)*c1 -> h1n, hseq ----
        {
            float* hs = P.hseq + (size_t)t * NN * HH;
            for (int j = blockIdx.x; j < NT; j += gridDim.x) {
                int row0 = j * 64;
                tile_gemm<64>(AST, BS, P.Wc1 + 128 * 64, row0,
                    [&](int grow, int k) -> float {
                        return P.rh[(size_t)grow * 64 + k];
                    },
                    [&](float (&acc)[4][4]) {
                        #pragma unroll
                        for (int i = 0; i < 4; ++i) {
                            int row = row0 + ty * 4 + i;
                            if (row >= NN) continue;
                            int colb = tx * 4;
                            float4 p4 = *reinterpret_cast<const float4*>(&P.pre1c[(size_t)row * 64 + colb]);
                            float4 u4 = *reinterpret_cast<const float4*>(&P.u[(size_t)row * 64 + colb]);
                            float4 h4 = *reinterpret_cast<const float4*>(&h1c[(size_t)row * 64 + colb]);
                            const float* pv = (const float*)&p4;
                            const float* uv = (const float*)&u4;
                            const float* hv = (const float*)&h4;
                            float4 r4; float* rv = (float*)&r4;
                            #pragma unroll
                            for (int jj = 0; jj < 4; ++jj) {
                                float cval = tanhf(acc[i][jj] + pv[jj]);
                                rv[jj] = uv[jj] * hv[jj] + (1.f - uv[jj]) * cval;
                            }
                            *reinterpret_cast<float4*>(&h1n[(size_t)row * 64 + colb]) = r4;
                            *reinterpret_cast<float4*>(&hs[(size_t)row * 64 + colb]) = r4;
                        }
                    });
            }
        }
        grid.sync();

        // swap states
        float* tmp;
        tmp = h0c; h0c = h0n; h0n = tmp;
        tmp = h1c; h1c = h1n; h1n = tmp;
    }
}

// ---------------- attention core (unchanged from R3) ----------------
__global__ void attn_core(const float* __restrict__ qkv,
                          const float* __restrict__ opw, const float* __restrict__ opb,
                          const float* __restrict__ ow, const float* __restrict__ ob,
                          float* __restrict__ out) {
    __shared__ float smem[4 * 2768];
    int w = threadIdx.x >> 6;
    int lane = threadIdx.x & 63;
    int node = blockIdx.x * 4 + w;
    float* shq = smem + w * 2768;
    float* sp  = shq + 2352;
    float* sob = shq + 2640;
    float* sha = shq + 2704;

    for (int idx = lane; idx < TT * 192; idx += 64) {
        int t = idx / 192, j = idx - t * 192;
        shq[t * 196 + j] = qkv[((size_t)t * NN + node) * 192 + j];
    }
    __syncthreads();

    if (lane < 24) {
        int hd = lane / 12, tq = lane % 12;
        const float* qrow = shq + tq * 196 + hd * 32;
        float sc[12];
        float mx = -1e30f;
        #pragma unroll
        for (int s = 0; s < 12; ++s) {
            const float* krow = shq + s * 196 + 64 + hd * 32;
            float a = 0.f;
            #pragma unroll
            for (int d = 0; d < 32; ++d) a += qrow[d] * krow[d];
            a *= 0.17677669529663687f;
            sc[s] = a; mx = fmaxf(mx, a);
        }
        float sum = 0.f;
        #pragma unroll
        for (int s = 0; s < 12; ++s) { sc[s] = expf(sc[s] - mx); sum += sc[s]; }
        float inv = 1.f / sum;
        #pragma unroll
        for (int s = 0; s < 12; ++s) sp[(hd * 12 + tq) * 12 + s] = sc[s] * inv;
    }
    __syncthreads();

    {
        int d = lane, hd = d >> 5;
        float acc = 0.f;
        #pragma unroll
        for (int s = 0; s < 12; ++s) {
            float ts = 0.f;
            #pragma unroll
            for (int t = 0; t < 12; ++t) ts += sp[(hd * 12 + t) * 12 + s];
            acc += ts * shq[s * 196 + 128 + d];
        }
        sob[d] = acc * (1.f / 12.f);
    }
    __syncthreads();

    {
        int d = lane;
        float acc = opb[d];
        const float* wrow = opw + d * 64;
        #pragma unroll
        for (int k = 0; k < 64; ++k) acc += sob[k] * wrow[k];
        sha[d] = acc;
    }
    __syncthreads();

    if (lane < OUTD) {
        float acc = ob[lane];
        #pragma unroll
        for (int k = 0; k < 64; ++k) acc += sha[k] * ow[k * OUTD + lane];
        out[(size_t)node * OUTD + lane] = acc;
    }
}

// ---------------- launcher ----------------

extern "C" void kernel_launch(void* const* d_in, const int* in_sizes, int n_in,
                              void* d_out, int out_size, void* d_ws, size_t ws_size,
                              hipStream_t stream) {
    const float* x   = (const float*)d_in[0];
    const int*   ei  = (const int*)d_in[1];
    const float* ea  = (const float*)d_in[2];
    const float* Wg0 = (const float*)d_in[3];
    const float* bg0 = (const float*)d_in[4];
    const float* Wu0 = (const float*)d_in[5];
    const float* bu0 = (const float*)d_in[6];
    const float* Wr0 = (const float*)d_in[7];
    const float* br0 = (const float*)d_in[8];
    const float* Wc0 = (const float*)d_in[9];
    const float* bc0 = (const float*)d_in[10];
    const float* Wg1 = (const float*)d_in[11];
    const float* bg1 = (const float*)d_in[12];
    const float* Wu1 = (const float*)d_in[13];
    const float* bu1 = (const float*)d_in[14];
    const float* Wr1 = (const float*)d_in[15];
    const float* br1 = (const float*)d_in[16];
    const float* Wc1 = (const float*)d_in[17];
    const float* bc1 = (const float*)d_in[18];
    const float* ipw = (const float*)d_in[19];
    const float* ipb = (const float*)d_in[20];
    const float* opw = (const float*)d_in[21];
    const float* opb = (const float*)d_in[22];
    const float* ow  = (const float*)d_in[23];
    const float* ob  = (const float*)d_in[24];
    float* out = (float*)d_out;

    char* p = (char*)d_ws;
    auto alloc = [&](size_t bytes) { char* r = p; p += (bytes + 255) & ~(size_t)255; return (void*)r; };
    // persistent across the call
    float* hseq = (float*)alloc((size_t)TT * NN * HH * 4);
    float* ipwT = (float*)alloc((size_t)64 * 192 * 4);
    // union region: loop-phase buffers vs qkv
    char* ubase = p;
    float* xT     = (float*)alloc((size_t)TT * NN * FF * 4);
    float* aggx   = (float*)alloc((size_t)TT * NN * FF * 4);
    float* g0all  = (float*)alloc((size_t)TT * NN * HH * 4);
    float* deg    = (float*)alloc((size_t)NN * 4);
    float* dinv   = (float*)alloc((size_t)NN * 4);
    int*   cnt    = (int*)  alloc((size_t)NN * 4);
    int*   rowptr = (int*)  alloc((size_t)(NN + 1) * 4);
    int*   cursor = (int*)  alloc((size_t)NN * 4);
    int*   colIdx = (int*)  alloc((size_t)EE * 4);
    float* valArr = (float*)alloc((size_t)EE * 4);
    float* u      = (float*)alloc((size_t)NN * HH * 4);
    float* rh     = (float*)alloc((size_t)NN * HH * 4);
    float* pre1u  = (float*)alloc((size_t)NN * HH * 4);
    float* pre1r  = (float*)alloc((size_t)NN * HH * 4);
    float* pre1c  = (float*)alloc((size_t)NN * HH * 4);
    float* h0a    = (float*)alloc((size_t)NN * HH * 4);
    float* h0b    = (float*)alloc((size_t)NN * HH * 4);
    float* h1a    = (float*)alloc((size_t)NN * HH * 4);
    float* h1b    = (float*)alloc((size_t)NN * HH * 4);
    size_t qkv_bytes = (size_t)TT * NN * 192 * 4;
    float* qkv = (float*)ubase;
    char* endA = p;
    char* endB = ubase + ((qkv_bytes + 255) & ~(size_t)255);
    p = (endA > endB) ? endA : endB;
    (void)ws_size;

    hipMemsetAsync(cnt, 0, (size_t)NN * 4, stream);
    hipMemsetAsync(h0a, 0, (size_t)NN * HH * 4, stream);
    hipMemsetAsync(h1a, 0, (size_t)NN * HH * 4, stream);
    deg_init_kernel<<<(NN + 255) / 256, 256, 0, stream>>>(deg);
    edge_accum_kernel<<<(EE + 255) / 256, 256, 0, stream>>>(ei, ea, deg, cnt);
    dinv_kernel<<<(NN + 255) / 256, 256, 0, stream>>>(deg, dinv);
    scan_kernel<<<1, 1024, 0, stream>>>(cnt, rowptr, cursor);
    fill_kernel<<<(EE + 255) / 256, 256, 0, stream>>>(ei, ea, dinv, cursor, colIdx, valArr);
    transpose_kernel<<<(TT * NN * FF + 255) / 256, 256, 0, stream>>>(x, xT);
    ipwT_kernel<<<(192 * 64 + 255) / 256, 256, 0, stream>>>(ipw, ipwT);

    // all-t x aggregation (linear GCN: aggregate-then-project)
    gather_raw32<<<dim3(NN / 8, TT), 256, 0, stream>>>(xT, dinv, rowptr, colIdx, valArr, aggx);
    // g0 for all t
    gemm64<32, 0><<<dim3((TT * NN + 63) / 64, 1), 256, 0, stream>>>(
        aggx, Wg0, nullptr, nullptr, 64, bg0, nullptr, nullptr, g0all, 64, TT * NN);

    // persistent cooperative GRU loop
    {
        GruParams P;
        P.xT = xT; P.g0all = g0all;
        P.Wu0 = Wu0; P.Wr0 = Wr0; P.Wc0 = Wc0;
        P.bu0 = bu0; P.br0 = br0; P.bc0 = bc0;
        P.Wg1 = Wg1; P.bg1 = bg1;
        P.Wu1 = Wu1; P.Wr1 = Wr1; P.Wc1 = Wc1;
        P.bu1 = bu1; P.br1 = br1; P.bc1 = bc1;
        P.dinv = dinv; P.rowptr = rowptr; P.colIdx = colIdx; P.valArr = valArr;
        P.h0a = h0a; P.h0b = h0b; P.h1a = h1a; P.h1b = h1b;
        P.u = u; P.rh = rh; P.pre1u = pre1u; P.pre1r = pre1r; P.pre1c = pre1c;
        P.hseq = hseq;

        int occ = 0;
        hipOccupancyMaxActiveBlocksPerMultiprocessor(&occ, gru_persistent, 256, 0);
        if (occ < 1) occ = 1;
        int dev = 0;
        hipGetDevice(&dev);
        int cus = 0;
        hipDeviceGetAttribute(&cus, hipDeviceAttributeMultiprocessorCount, dev);
        if (cus < 1) cus = 256;
        int grid = occ * cus;
        if (grid > 3 * NT) grid = 3 * NT;   // largest phase job count
        void* args[] = { (void*)&P };
        hipLaunchCooperativeKernel((void*)gru_persistent, dim3(grid), dim3(256),
                                   args, 0, stream);
    }

    // qkv = hseq @ ipw.T + ipb  (3 column strips)
    gemm64<64, 1><<<dim3((TT * NN + 63) / 64, 3), 256, 0, stream>>>(
        hseq, ipwT, ipwT + 64, ipwT + 128, 192, ipb, ipb + 64, ipb + 128,
        qkv, 192, TT * NN);

    attn_core<<<NN / 4, 256, 0, stream>>>(qkv, opw, opb, ow, ob, out);
}

// Round 5
// 11695.110 us; speedup vs baseline: 1.9427x; 1.9427x over previous
//
#include <hip/hip_runtime.h>
#include <math.h>

#define NN 20000
#define FF 32
#define TT 12
#define HH 64
#define EE 320000
#define OUTD 12

__device__ __forceinline__ float sigmoidf_(float x) { return 1.f / (1.f + expf(-x)); }

// ---------------- preprocessing ----------------

__global__ void deg_init_kernel(float* deg) {
    int i = blockIdx.x * 256 + threadIdx.x;
    if (i < NN) deg[i] = 1.0f;   // self-loop weight 1
}

__global__ void edge_accum_kernel(const int* ei, const float* ea, float* deg, int* cnt) {
    int e = blockIdx.x * 256 + threadIdx.x;
    if (e >= EE) return;
    int d = ei[EE + e];
    float w = ea[e * 2 + 1];
    atomicAdd(&deg[d], w);
    atomicAdd(&cnt[d], 1);
}

__global__ void dinv_kernel(const float* deg, float* dinv) {
    int i = blockIdx.x * 256 + threadIdx.x;
    if (i < NN) dinv[i] = rsqrtf(deg[i]);
}

__global__ void scan_kernel(const int* cnt, int* rowptr, int* cursor) {
    __shared__ int wsum[16];
    int tid = threadIdx.x;
    int lane = tid & 63, w = tid >> 6;
    int run = 0;
    for (int base = 0; base < NN; base += 1024) {
        int idx = base + tid;
        int c = (idx < NN) ? cnt[idx] : 0;
        int v = c;
        #pragma unroll
        for (int off = 1; off < 64; off <<= 1) {
            int t = __shfl_up(v, off, 64);
            if (lane >= off) v += t;
        }
        if (lane == 63) wsum[w] = v;
        __syncthreads();
        if (tid < 16) {
            int x = wsum[tid];
            #pragma unroll
            for (int off = 1; off < 16; off <<= 1) {
                int t = __shfl_up(x, off, 64);
                if (tid >= off) x += t;
            }
            wsum[tid] = x;
        }
        __syncthreads();
        int waveoff = (w > 0) ? wsum[w - 1] : 0;
        int excl = run + waveoff + (v - c);
        if (idx < NN) { rowptr[idx] = excl; cursor[idx] = excl; }
        run += wsum[15];
        __syncthreads();
    }
    if (tid == 0) rowptr[NN] = run;
}

__global__ void fill_kernel(const int* ei, const float* ea, const float* dinv,
                            int* cursor, int* colIdx, float* valArr) {
    int e = blockIdx.x * 256 + threadIdx.x;
    if (e >= EE) return;
    int s = ei[e], d = ei[EE + e];
    float w = ea[e * 2 + 1];
    int pos = atomicAdd(&cursor[d], 1);
    colIdx[pos] = s;
    valArr[pos] = dinv[s] * w * dinv[d];
}

__global__ void transpose_kernel(const float* x, float* xT) {
    int i = blockIdx.x * 256 + threadIdx.x;
    if (i >= TT * NN * FF) return;
    int f = i & 31;
    int rest = i >> 5;
    int n = rest % NN;
    int t = rest / NN;
    xT[i] = x[n * (FF * TT) + f * TT + t];
}

__global__ void ipwT_kernel(const float* ipw, float* ipwT) {
    int i = blockIdx.x * 256 + threadIdx.x;
    if (i >= 192 * 64) return;
    int k = i / 192, j = i % 192;
    ipwT[i] = ipw[j * 64 + k];
}

// raw normalized aggregation, width-32 (x for all t at once)
__global__ void gather_raw32(const float* __restrict__ srcbase, const float* __restrict__ dinv,
                             const int* __restrict__ rowptr, const int* __restrict__ colIdx,
                             const float* __restrict__ valArr, float* __restrict__ dstbase) {
    const float* src = srcbase + (size_t)blockIdx.y * NN * 32;
    float* dst = dstbase + (size_t)blockIdx.y * NN * 32;
    int node = blockIdx.x * 8 + threadIdx.x / 32;
    int lane = threadIdx.x % 32;
    float di = dinv[node];
    float acc = di * di * src[node * 32 + lane];
    int s = rowptr[node], e = rowptr[node + 1];
    int j = s;
    for (; j + 3 < e; j += 4) {
        int c0 = colIdx[j], c1 = colIdx[j + 1], c2 = colIdx[j + 2], c3 = colIdx[j + 3];
        float v0 = valArr[j], v1 = valArr[j + 1], v2 = valArr[j + 2], v3 = valArr[j + 3];
        acc += v0 * src[c0 * 32 + lane] + v1 * src[c1 * 32 + lane]
             + v2 * src[c2 * 32 + lane] + v3 * src[c3 * 32 + lane];
    }
    for (; j < e; ++j) acc += valArr[j] * src[colIdx[j] * 32 + lane];
    dst[node * 32 + lane] = acc;
}

// ---------------- standalone tiled GEMM (pre/post phases) ----------------
// EPI 0: out0 = sigmoid(acc + bias);  EPI 1: out0[row*ostr + y*64 + col] = acc + bias
template<int K, int EPI>
__launch_bounds__(256, 2)
__global__ void gemm64(const float* __restrict__ A1,
                       const float* __restrict__ B0, const float* __restrict__ B1,
                       const float* __restrict__ B2, int brstride,
                       const float* __restrict__ b0, const float* __restrict__ b1,
                       const float* __restrict__ b2,
                       float* __restrict__ out0, int ostr, int nrows) {
    __shared__ __align__(16) float AsT[32 * 68];
    __shared__ __align__(16) float Bs[32 * 68];
    const int tid = threadIdx.x;
    const int tx = tid & 15, ty = tid >> 4;
    const int row0 = blockIdx.x * 64;
    const int y = blockIdx.y;
    const float* B = (y == 0) ? B0 : ((y == 1) ? B1 : B2);
    const float* bias = (y == 0) ? b0 : ((y == 1) ? b1 : b2);

    float acc[4][4];
    #pragma unroll
    for (int i = 0; i < 4; ++i)
        #pragma unroll
        for (int j = 0; j < 4; ++j) acc[i][j] = 0.f;

    for (int kc = 0; kc < K; kc += 32) {
        #pragma unroll
        for (int i = 0; i < 8; ++i) {
            int idx = tid + i * 256;
            int kk = idx & 31, rr = idx >> 5;
            int grow = row0 + rr;
            AsT[kk * 68 + rr] = (grow < nrows) ? A1[(size_t)grow * K + kc + kk] : 0.f;
        }
        #pragma unroll
        for (int i = 0; i < 8; ++i) {
            int idx = tid + i * 256;
            int kk = idx >> 6, cc = idx & 63;
            Bs[kk * 68 + cc] = B[(size_t)(kc + kk) * brstride + cc];
        }
        __syncthreads();
        #pragma unroll
        for (int k = 0; k < 32; ++k) {
            float4 a4 = *reinterpret_cast<const float4*>(&AsT[k * 68 + ty * 4]);
            float4 b4 = *reinterpret_cast<const float4*>(&Bs[k * 68 + tx * 4]);
            float av[4] = {a4.x, a4.y, a4.z, a4.w};
            float bv[4] = {b4.x, b4.y, b4.z, b4.w};
            #pragma unroll
            for (int i = 0; i < 4; ++i)
                #pragma unroll
                for (int j = 0; j < 4; ++j) acc[i][j] += av[i] * bv[j];
        }
        __syncthreads();
    }

    #pragma unroll
    for (int i = 0; i < 4; ++i) {
        int row = row0 + ty * 4 + i;
        if (row >= nrows) continue;
        int colb = tx * 4;
        float4 r4;
        float* rv = (float*)&r4;
        if constexpr (EPI == 0) {
            #pragma unroll
            for (int j = 0; j < 4; ++j) rv[j] = sigmoidf_(acc[i][j] + bias[colb + j]);
            *reinterpret_cast<float4*>(&out0[(size_t)row * 64 + colb]) = r4;
        } else {
            #pragma unroll
            for (int j = 0; j < 4; ++j) rv[j] = acc[i][j] + bias[colb + j];
            *reinterpret_cast<float4*>(&out0[(size_t)row * ostr + y * 64 + colb]) = r4;
        }
    }
}

// ---------------- fused cell0: u,r,c,h0',y0 per 32-row tile ----------------
// u = sig([x|g0|h0]@Wu0+bu0); r = sig(...Wr0+br0); rh=r*h0
// c = tanh([x|g0|rh]@Wc0+bc0); h0' = u*h0+(1-u)*c -> h0n
// y0 = h0'@Wg1 (no bias; bias applied post-gather in cell1)
__launch_bounds__(256, 3)
__global__ void cell0_kernel(const float* __restrict__ xt, const float* __restrict__ g0,
                             const float* __restrict__ h0c,
                             const float* __restrict__ Wu0, const float* __restrict__ Wr0,
                             const float* __restrict__ Wc0,
                             const float* __restrict__ bu0, const float* __restrict__ br0,
                             const float* __restrict__ bc0,
                             const float* __restrict__ Wg1,
                             float* __restrict__ h0n, float* __restrict__ y0) {
    __shared__ __align__(16) float AS[32 * 34];    // [k][row] chunk
    __shared__ __align__(16) float BS[32 * 132];   // [k][col] chunk (up to 128 cols)
    __shared__ __align__(16) float UT[32 * 68];
    __shared__ __align__(16) float RT[32 * 68];
    __shared__ __align__(16) float HT[32 * 68];
    const int tid = threadIdx.x;
    const int tx = tid & 15, ty = tid >> 4;   // tx: cols, ty: 2 rows each
    const int row0 = blockIdx.x * 32;         // 625 * 32 == 20000 exactly

    // ---- GEMM1: [u|r] (K=160, 128 cols) ----
    float acc[2][8];
    #pragma unroll
    for (int i = 0; i < 2; ++i)
        #pragma unroll
        for (int j = 0; j < 8; ++j) acc[i][j] = 0.f;

    for (int kc = 0; kc < 160; kc += 32) {
        #pragma unroll
        for (int i = 0; i < 4; ++i) {
            int idx = tid + i * 256;
            int kk = idx & 31, rr = idx >> 5;
            int k = kc + kk, grow = row0 + rr;
            float v;
            if (k < 32) v = xt[(size_t)grow * 32 + k];
            else if (k < 96) v = g0[(size_t)grow * 64 + (k - 32)];
            else v = h0c[(size_t)grow * 64 + (k - 96)];
            AS[kk * 34 + rr] = v;
        }
        #pragma unroll
        for (int i = 0; i < 16; ++i) {
            int idx = tid + i * 256;
            int kk = idx >> 7, cc = idx & 127;
            BS[kk * 132 + cc] = (cc < 64) ? Wu0[(kc + kk) * 64 + cc]
                                          : Wr0[(kc + kk) * 64 + (cc - 64)];
        }
        __syncthreads();
        #pragma unroll
        for (int k = 0; k < 32; ++k) {
            float2 a2 = *reinterpret_cast<const float2*>(&AS[k * 34 + ty * 2]);
            float4 b0 = *reinterpret_cast<const float4*>(&BS[k * 132 + tx * 8]);
            float4 b1 = *reinterpret_cast<const float4*>(&BS[k * 132 + tx * 8 + 4]);
            float bv[8] = {b0.x, b0.y, b0.z, b0.w, b1.x, b1.y, b1.z, b1.w};
            #pragma unroll
            for (int j = 0; j < 8; ++j) {
                acc[0][j] += a2.x * bv[j];
                acc[1][j] += a2.y * bv[j];
            }
        }
        __syncthreads();
    }
    // epilogue 1: u -> UT, rh = sig(r)*h0 -> RT
    #pragma unroll
    for (int i = 0; i < 2; ++i) {
        int row = ty * 2 + i, grow = row0 + row;
        if (tx < 8) {
            int colb = tx * 8;
            #pragma unroll
            for (int jj = 0; jj < 8; ++jj)
                UT[row * 68 + colb + jj] = sigmoidf_(acc[i][jj] + bu0[colb + jj]);
        } else {
            int cc = tx * 8 - 64;
            float4 h4a = *reinterpret_cast<const float4*>(&h0c[(size_t)grow * 64 + cc]);
            float4 h4b = *reinterpret_cast<const float4*>(&h0c[(size_t)grow * 64 + cc + 4]);
            const float* ha = (const float*)&h4a;
            const float* hb = (const float*)&h4b;
            #pragma unroll
            for (int jj = 0; jj < 4; ++jj)
                RT[row * 68 + cc + jj] = sigmoidf_(acc[i][jj] + br0[cc + jj]) * ha[jj];
            #pragma unroll
            for (int jj = 0; jj < 4; ++jj)
                RT[row * 68 + cc + 4 + jj] = sigmoidf_(acc[i][4 + jj] + br0[cc + 4 + jj]) * hb[jj];
        }
    }
    __syncthreads();

    // ---- GEMM2: c (K=160, 64 cols), tail of A from RT ----
    float acc2[2][4];
    #pragma unroll
    for (int i = 0; i < 2; ++i)
        #pragma unroll
        for (int j = 0; j < 4; ++j) acc2[i][j] = 0.f;

    for (int kc = 0; kc < 160; kc += 32) {
        #pragma unroll
        for (int i = 0; i < 4; ++i) {
            int idx = tid + i * 256;
            int kk = idx & 31, rr = idx >> 5;
            int k = kc + kk, grow = row0 + rr;
            float v;
            if (k < 32) v = xt[(size_t)grow * 32 + k];
            else if (k < 96) v = g0[(size_t)grow * 64 + (k - 32)];
            else v = RT[rr * 68 + (k - 96)];
            AS[kk * 34 + rr] = v;
        }
        #pragma unroll
        for (int i = 0; i < 8; ++i) {
            int idx = tid + i * 256;
            int kk = idx >> 6, cc = idx & 63;
            BS[kk * 132 + cc] = Wc0[(kc + kk) * 64 + cc];
        }
        __syncthreads();
        #pragma unroll
        for (int k = 0; k < 32; ++k) {
            float2 a2 = *reinterpret_cast<const float2*>(&AS[k * 34 + ty * 2]);
            float4 b4 = *reinterpret_cast<const float4*>(&BS[k * 132 + tx * 4]);
            float bv[4] = {b4.x, b4.y, b4.z, b4.w};
            #pragma unroll
            for (int j = 0; j < 4; ++j) {
                acc2[0][j] += a2.x * bv[j];
                acc2[1][j] += a2.y * bv[j];
            }
        }
        __syncthreads();
    }
    // epilogue 2: h0' = u*h0+(1-u)*c -> h0n (global) and HT (LDS)
    #pragma unroll
    for (int i = 0; i < 2; ++i) {
        int row = ty * 2 + i, grow = row0 + row;
        int colb = tx * 4;
        float4 h4 = *reinterpret_cast<const float4*>(&h0c[(size_t)grow * 64 + colb]);
        const float* hv = (const float*)&h4;
        float4 r4; float* rv = (float*)&r4;
        #pragma unroll
        for (int jj = 0; jj < 4; ++jj) {
            float cv = tanhf(acc2[i][jj] + bc0[colb + jj]);
            float uu = UT[row * 68 + colb + jj];
            rv[jj] = uu * hv[jj] + (1.f - uu) * cv;
        }
        *reinterpret_cast<float4*>(&h0n[(size_t)grow * 64 + colb]) = r4;
        #pragma unroll
        for (int jj = 0; jj < 4; ++jj) HT[row * 68 + colb + jj] = rv[jj];
    }
    __syncthreads();

    // ---- GEMM3: y0 = h0' @ Wg1 (K=64, 64 cols), A from HT ----
    float acc3[2][4];
    #pragma unroll
    for (int i = 0; i < 2; ++i)
        #pragma unroll
        for (int j = 0; j < 4; ++j) acc3[i][j] = 0.f;

    for (int kc = 0; kc < 64; kc += 32) {
        #pragma unroll
        for (int i = 0; i < 8; ++i) {
            int idx = tid + i * 256;
            int kk = idx >> 6, cc = idx & 63;
            BS[kk * 132 + cc] = Wg1[(kc + kk) * 64 + cc];
        }
        __syncthreads();
        #pragma unroll
        for (int k = 0; k < 32; ++k) {
            float a0 = HT[(ty * 2) * 68 + kc + k];
            float a1 = HT[(ty * 2 + 1) * 68 + kc + k];
            float4 b4 = *reinterpret_cast<const float4*>(&BS[k * 132 + tx * 4]);
            float bv[4] = {b4.x, b4.y, b4.z, b4.w};
            #pragma unroll
            for (int j = 0; j < 4; ++j) {
                acc3[0][j] += a0 * bv[j];
                acc3[1][j] += a1 * bv[j];
            }
        }
        __syncthreads();
    }
    #pragma unroll
    for (int i = 0; i < 2; ++i) {
        int grow = row0 + ty * 2 + i;
        float4 r4; float* rv = (float*)&r4;
        #pragma unroll
        for (int jj = 0; jj < 4; ++jj) rv[jj] = acc3[i][jj];
        *reinterpret_cast<float4*>(&y0[(size_t)grow * 64 + tx * 4]) = r4;
    }
}

// ---------------- fused cell1: gather(y0)->g1, u1,r1,c1,h1' per 32-row tile ----------------
__launch_bounds__(256, 3)
__global__ void cell1_kernel(const float* __restrict__ h0n, const float* __restrict__ y0,
                             const float* __restrict__ h1c,
                             const float* __restrict__ bg1,
                             const float* __restrict__ Wu1, const float* __restrict__ Wr1,
                             const float* __restrict__ Wc1,
                             const float* __restrict__ bu1, const float* __restrict__ br1,
                             const float* __restrict__ bc1,
                             const float* __restrict__ dinv, const int* __restrict__ rowptr,
                             const int* __restrict__ colIdx, const float* __restrict__ valArr,
                             float* __restrict__ h1n, float* __restrict__ hseqT) {
    __shared__ __align__(16) float AS[32 * 34];
    __shared__ __align__(16) float BS[32 * 132];
    __shared__ __align__(16) float G1T[32 * 68];
    __shared__ __align__(16) float UT[32 * 68];
    __shared__ __align__(16) float RT[32 * 68];
    const int tid = threadIdx.x;
    const int tx = tid & 15, ty = tid >> 4;
    const int row0 = blockIdx.x * 32;

    // ---- gather y0 for this tile's 32 nodes -> g1 = sigmoid(agg + bg1) ----
    {
        int wv = tid >> 6, lane = tid & 63;
        for (int q = 0; q < 8; ++q) {
            int nl = wv * 8 + q;
            int node = row0 + nl;
            float di = dinv[node];
            float a = di * di * y0[(size_t)node * 64 + lane];
            int s = rowptr[node], e = rowptr[node + 1];
            int j = s;
            for (; j + 3 < e; j += 4) {
                int c0 = colIdx[j], c1 = colIdx[j + 1], c2 = colIdx[j + 2], c3 = colIdx[j + 3];
                float v0 = valArr[j], v1 = valArr[j + 1], v2 = valArr[j + 2], v3 = valArr[j + 3];
                a += v0 * y0[(size_t)c0 * 64 + lane] + v1 * y0[(size_t)c1 * 64 + lane]
                   + v2 * y0[(size_t)c2 * 64 + lane] + v3 * y0[(size_t)c3 * 64 + lane];
            }
            for (; j < e; ++j) a += valArr[j] * y0[(size_t)colIdx[j] * 64 + lane];
            G1T[nl * 68 + lane] = sigmoidf_(a + bg1[lane]);
        }
    }
    __syncthreads();

    // ---- GEMM: [u1|r1] (K=192, 128 cols) ----
    float acc[2][8];
    #pragma unroll
    for (int i = 0; i < 2; ++i)
        #pragma unroll
        for (int j = 0; j < 8; ++j) acc[i][j] = 0.f;

    for (int kc = 0; kc < 192; kc += 32) {
        #pragma unroll
        for (int i = 0; i < 4; ++i) {
            int idx = tid + i * 256;
            int kk = idx & 31, rr = idx >> 5;
            int k = kc + kk, grow = row0 + rr;
            float v;
            if (k < 64) v = h0n[(size_t)grow * 64 + k];
            else if (k < 128) v = G1T[rr * 68 + (k - 64)];
            else v = h1c[(size_t)grow * 64 + (k - 128)];
            AS[kk * 34 + rr] = v;
        }
        #pragma unroll
        for (int i = 0; i < 16; ++i) {
            int idx = tid + i * 256;
            int kk = idx >> 7, cc = idx & 127;
            BS[kk * 132 + cc] = (cc < 64) ? Wu1[(kc + kk) * 64 + cc]
                                          : Wr1[(kc + kk) * 64 + (cc - 64)];
        }
        __syncthreads();
        #pragma unroll
        for (int k = 0; k < 32; ++k) {
            float2 a2 = *reinterpret_cast<const float2*>(&AS[k * 34 + ty * 2]);
            float4 b0 = *reinterpret_cast<const float4*>(&BS[k * 132 + tx * 8]);
            float4 b1 = *reinterpret_cast<const float4*>(&BS[k * 132 + tx * 8 + 4]);
            float bv[8] = {b0.x, b0.y, b0.z, b0.w, b1.x, b1.y, b1.z, b1.w};
            #pragma unroll
            for (int j = 0; j < 8; ++j) {
                acc[0][j] += a2.x * bv[j];
                acc[1][j] += a2.y * bv[j];
            }
        }
        __syncthreads();
    }
    #pragma unroll
    for (int i = 0; i < 2; ++i) {
        int row = ty * 2 + i, grow = row0 + row;
        if (tx < 8) {
            int colb = tx * 8;
            #pragma unroll
            for (int jj = 0; jj < 8; ++jj)
                UT[row * 68 + colb + jj] = sigmoidf_(acc[i][jj] + bu1[colb + jj]);
        } else {
            int cc = tx * 8 - 64;
            float4 h4a = *reinterpret_cast<const float4*>(&h1c[(size_t)grow * 64 + cc]);
            float4 h4b = *reinterpret_cast<const float4*>(&h1c[(size_t)grow * 64 + cc + 4]);
            const float* ha = (const float*)&h4a;
            const float* hb = (const float*)&h4b;
            #pragma unroll
            for (int jj = 0; jj < 4; ++jj)
                RT[row * 68 + cc + jj] = sigmoidf_(acc[i][jj] + br1[cc + jj]) * ha[jj];
            #pragma unroll
            for (int jj = 0; jj < 4; ++jj)
                RT[row * 68 + cc + 4 + jj] = sigmoidf_(acc[i][4 + jj] + br1[cc + 4 + jj]) * hb[jj];
        }
    }
    __syncthreads();

    // ---- GEMM: c1 (K=192, 64 cols), tail from RT ----
    float acc2[2][4];
    #pragma unroll
    for (int i = 0; i < 2; ++i)
        #pragma unroll
        for (int j = 0; j < 4; ++j) acc2[i][j] = 0.f;

    for (int kc = 0; kc < 192; kc += 32) {
        #pragma unroll
        for (int i = 0; i < 4; ++i) {
            int idx = tid + i * 256;
            int kk = idx & 31, rr = idx >> 5;
            int k = kc + kk, grow = row0 + rr;
            float v;
            if (k < 64) v = h0n[(size_t)grow * 64 + k];
            else if (k < 128) v = G1T[rr * 68 + (k - 64)];
            else v = RT[rr * 68 + (k - 128)];
            AS[kk * 34 + rr] = v;
        }
        #pragma unroll
        for (int i = 0; i < 8; ++i) {
            int idx = tid + i * 256;
            int kk = idx >> 6, cc = idx & 63;
            BS[kk * 132 + cc] = Wc1[(kc + kk) * 64 + cc];
        }
        __syncthreads();
        #pragma unroll
        for (int k = 0; k < 32; ++k) {
            float2 a2 = *reinterpret_cast<const float2*>(&AS[k * 34 + ty * 2]);
            float4 b4 = *reinterpret_cast<const float4*>(&BS[k * 132 + tx * 4]);
            float bv[4] = {b4.x, b4.y, b4.z, b4.w};
            #pragma unroll
            for (int j = 0; j < 4; ++j) {
                acc2[0][j] += a2.x * bv[j];
                acc2[1][j] += a2.y * bv[j];
            }
        }
        __syncthreads();
    }
    #pragma unroll
    for (int i = 0; i < 2; ++i) {
        int row = ty * 2 + i, grow = row0 + row;
        int colb = tx * 4;
        float4 h4 = *reinterpret_cast<const float4*>(&h1c[(size_t)grow * 64 + colb]);
        const float* hv = (const float*)&h4;
        float4 r4; float* rv = (float*)&r4;
        #pragma unroll
        for (int jj = 0; jj < 4; ++jj) {
            float cv = tanhf(acc2[i][jj] + bc1[colb + jj]);
            float uu = UT[row * 68 + colb + jj];
            rv[jj] = uu * hv[jj] + (1.f - uu) * cv;
        }
        *reinterpret_cast<float4*>(&h1n[(size_t)grow * 64 + colb]) = r4;
        *reinterpret_cast<float4*>(&hseqT[(size_t)grow * 64 + colb]) = r4;
    }
}

// ---------------- attention core ----------------
__global__ void attn_core(const float* __restrict__ qkv,
                          const float* __restrict__ opw, const float* __restrict__ opb,
                          const float* __restrict__ ow, const float* __restrict__ ob,
                          float* __restrict__ out) {
    __shared__ float smem[4 * 2768];
    int w = threadIdx.x >> 6;
    int lane = threadIdx.x & 63;
    int node = blockIdx.x * 4 + w;
    float* shq = smem + w * 2768;
    float* sp  = shq + 2352;
    float* sob = shq + 2640;
    float* sha = shq + 2704;

    for (int idx = lane; idx < TT * 192; idx += 64) {
        int t = idx / 192, j = idx - t * 192;
        shq[t * 196 + j] = qkv[((size_t)t * NN + node) * 192 + j];
    }
    __syncthreads();

    if (lane < 24) {
        int hd = lane / 12, tq = lane % 12;
        const float* qrow = shq + tq * 196 + hd * 32;
        float sc[12];
        float mx = -1e30f;
        #pragma unroll
        for (int s = 0; s < 12; ++s) {
            const float* krow = shq + s * 196 + 64 + hd * 32;
            float a = 0.f;
            #pragma unroll
            for (int d = 0; d < 32; ++d) a += qrow[d] * krow[d];
            a *= 0.17677669529663687f;
            sc[s] = a; mx = fmaxf(mx, a);
        }
        float sum = 0.f;
        #pragma unroll
        for (int s = 0; s < 12; ++s) { sc[s] = expf(sc[s] - mx); sum += sc[s]; }
        float inv = 1.f / sum;
        #pragma unroll
        for (int s = 0; s < 12; ++s) sp[(hd * 12 + tq) * 12 + s] = sc[s] * inv;
    }
    __syncthreads();

    {
        int d = lane, hd = d >> 5;
        float acc = 0.f;
        #pragma unroll
        for (int s = 0; s < 12; ++s) {
            float ts = 0.f;
            #pragma unroll
            for (int t = 0; t < 12; ++t) ts += sp[(hd * 12 + t) * 12 + s];
            acc += ts * shq[s * 196 + 128 + d];
        }
        sob[d] = acc * (1.f / 12.f);
    }
    __syncthreads();

    {
        int d = lane;
        float acc = opb[d];
        const float* wrow = opw + d * 64;
        #pragma unroll
        for (int k = 0; k < 64; ++k) acc += sob[k] * wrow[k];
        sha[d] = acc;
    }
    __syncthreads();

    if (lane < OUTD) {
        float acc = ob[lane];
        #pragma unroll
        for (int k = 0; k < 64; ++k) acc += sha[k] * ow[k * OUTD + lane];
        out[(size_t)node * OUTD + lane] = acc;
    }
}

// ---------------- launcher ----------------

extern "C" void kernel_launch(void* const* d_in, const int* in_sizes, int n_in,
                              void* d_out, int out_size, void* d_ws, size_t ws_size,
                              hipStream_t stream) {
    const float* x   = (const float*)d_in[0];
    const int*   ei  = (const int*)d_in[1];
    const float* ea  = (const float*)d_in[2];
    const float* Wg0 = (const float*)d_in[3];
    const float* bg0 = (const float*)d_in[4];
    const float* Wu0 = (const float*)d_in[5];
    const float* bu0 = (const float*)d_in[6];
    const float* Wr0 = (const float*)d_in[7];
    const float* br0 = (const float*)d_in[8];
    const float* Wc0 = (const float*)d_in[9];
    const float* bc0 = (const float*)d_in[10];
    const float* Wg1 = (const float*)d_in[11];
    const float* bg1 = (const float*)d_in[12];
    const float* Wu1 = (const float*)d_in[13];
    const float* bu1 = (const float*)d_in[14];
    const float* Wr1 = (const float*)d_in[15];
    const float* br1 = (const float*)d_in[16];
    const float* Wc1 = (const float*)d_in[17];
    const float* bc1 = (const float*)d_in[18];
    const float* ipw = (const float*)d_in[19];
    const float* ipb = (const float*)d_in[20];
    const float* opw = (const float*)d_in[21];
    const float* opb = (const float*)d_in[22];
    const float* ow  = (const float*)d_in[23];
    const float* ob  = (const float*)d_in[24];
    float* out = (float*)d_out;

    char* p = (char*)d_ws;
    auto alloc = [&](size_t bytes) { char* r = p; p += (bytes + 255) & ~(size_t)255; return (void*)r; };
    // persistent across the call
    float* hseq = (float*)alloc((size_t)TT * NN * HH * 4);
    float* ipwT = (float*)alloc((size_t)64 * 192 * 4);
    // union: loop-phase buffers vs qkv
    char* ubase = p;
    float* xT     = (float*)alloc((size_t)TT * NN * FF * 4);
    float* aggx   = (float*)alloc((size_t)TT * NN * FF * 4);
    float* g0all  = (float*)alloc((size_t)TT * NN * HH * 4);
    float* deg    = (float*)alloc((size_t)NN * 4);
    float* dinv   = (float*)alloc((size_t)NN * 4);
    int*   cnt    = (int*)  alloc((size_t)NN * 4);
    int*   rowptr = (int*)  alloc((size_t)(NN + 1) * 4);
    int*   cursor = (int*)  alloc((size_t)NN * 4);
    int*   colIdx = (int*)  alloc((size_t)EE * 4);
    float* valArr = (float*)alloc((size_t)EE * 4);
    float* y0     = (float*)alloc((size_t)NN * HH * 4);
    float* h0a    = (float*)alloc((size_t)NN * HH * 4);
    float* h0b    = (float*)alloc((size_t)NN * HH * 4);
    float* h1a    = (float*)alloc((size_t)NN * HH * 4);
    float* h1b    = (float*)alloc((size_t)NN * HH * 4);
    size_t qkv_bytes = (size_t)TT * NN * 192 * 4;
    float* qkv = (float*)ubase;
    char* endA = p;
    char* endB = ubase + ((qkv_bytes + 255) & ~(size_t)255);
    p = (endA > endB) ? endA : endB;
    (void)ws_size;

    hipMemsetAsync(cnt, 0, (size_t)NN * 4, stream);
    hipMemsetAsync(h0a, 0, (size_t)NN * HH * 4, stream);
    hipMemsetAsync(h1a, 0, (size_t)NN * HH * 4, stream);
    deg_init_kernel<<<(NN + 255) / 256, 256, 0, stream>>>(deg);
    edge_accum_kernel<<<(EE + 255) / 256, 256, 0, stream>>>(ei, ea, deg, cnt);
    dinv_kernel<<<(NN + 255) / 256, 256, 0, stream>>>(deg, dinv);
    scan_kernel<<<1, 1024, 0, stream>>>(cnt, rowptr, cursor);
    fill_kernel<<<(EE + 255) / 256, 256, 0, stream>>>(ei, ea, dinv, cursor, colIdx, valArr);
    transpose_kernel<<<(TT * NN * FF + 255) / 256, 256, 0, stream>>>(x, xT);
    ipwT_kernel<<<(192 * 64 + 255) / 256, 256, 0, stream>>>(ipw, ipwT);

    // all-t x aggregation (linear GCN: aggregate-then-project)
    gather_raw32<<<dim3(NN / 8, TT), 256, 0, stream>>>(xT, dinv, rowptr, colIdx, valArr, aggx);
    // g0 for all t: sigmoid(aggx @ Wg0 + bg0)
    gemm64<32, 0><<<dim3((TT * NN + 63) / 64, 1), 256, 0, stream>>>(
        aggx, Wg0, nullptr, nullptr, 64, bg0, nullptr, nullptr, g0all, 64, TT * NN);

    const int CB = NN / 32;   // 625
    for (int t = 0; t < TT; ++t) {
        const float* xt = xT + (size_t)t * NN * FF;
        const float* g0 = g0all + (size_t)t * NN * HH;
        float* h0_in  = (t & 1) ? h0b : h0a;
        float* h0_out = (t & 1) ? h0a : h0b;
        float* h1_in  = (t & 1) ? h1b : h1a;
        float* h1_out = (t & 1) ? h1a : h1b;
        cell0_kernel<<<CB, 256, 0, stream>>>(
            xt, g0, h0_in, Wu0, Wr0, Wc0, bu0, br0, bc0, Wg1, h0_out, y0);
        cell1_kernel<<<CB, 256, 0, stream>>>(
            h0_out, y0, h1_in, bg1, Wu1, Wr1, Wc1, bu1, br1, bc1,
            dinv, rowptr, colIdx, valArr, h1_out, hseq + (size_t)t * NN * HH);
    }

    // qkv = hseq @ ipw.T + ipb  (3 column strips)
    gemm64<64, 1><<<dim3((TT * NN + 63) / 64, 3), 256, 0, stream>>>(
        hseq, ipwT, ipwT + 64, ipwT + 128, 192, ipb, ipb + 64, ipb + 128,
        qkv, 192, TT * NN);

    attn_core<<<NN / 4, 256, 0, stream>>>(qkv, opw, opb, ow, ob, out);
}

// Round 6
// 1337.205 us; speedup vs baseline: 16.9904x; 8.7459x over previous
//
#include <hip/hip_runtime.h>
#include <math.h>

#define NN 20000
#define FF 32
#define TT 12
#define HH 64
#define EE 320000
#define OUTD 12

typedef __attribute__((ext_vector_type(8))) short short8;
typedef __attribute__((ext_vector_type(4))) float floatx4;

__device__ __forceinline__ float sigmoidf_(float x) { return 1.f / (1.f + expf(-x)); }

__device__ __forceinline__ short bf16rne(float f) {
    union { float f; unsigned u; } v; v.f = f;
    unsigned u = v.u;
    u += 0x7fffu + ((u >> 16) & 1u);
    return (short)(u >> 16);
}

// load 8 consecutive fp32, convert to bf16 A/B fragment
__device__ __forceinline__ short8 afrag_f32(const float* p) {
    float4 a = *reinterpret_cast<const float4*>(p);
    float4 b = *reinterpret_cast<const float4*>(p + 4);
    short8 f;
    f[0] = bf16rne(a.x); f[1] = bf16rne(a.y); f[2] = bf16rne(a.z); f[3] = bf16rne(a.w);
    f[4] = bf16rne(b.x); f[5] = bf16rne(b.y); f[6] = bf16rne(b.z); f[7] = bf16rne(b.w);
    return f;
}

#define MFMA(a, b, c) __builtin_amdgcn_mfma_f32_16x16x32_bf16((a), (b), (c), 0, 0, 0)

// ---------------- preprocessing ----------------

__global__ void deg_init_kernel(float* deg) {
    int i = blockIdx.x * 256 + threadIdx.x;
    if (i < NN) deg[i] = 1.0f;
}

__global__ void edge_accum_kernel(const int* ei, const float* ea, float* deg, int* cnt) {
    int e = blockIdx.x * 256 + threadIdx.x;
    if (e >= EE) return;
    int d = ei[EE + e];
    float w = ea[e * 2 + 1];
    atomicAdd(&deg[d], w);
    atomicAdd(&cnt[d], 1);
}

__global__ void dinv_kernel(const float* deg, float* dinv) {
    int i = blockIdx.x * 256 + threadIdx.x;
    if (i < NN) dinv[i] = rsqrtf(deg[i]);
}

__global__ void scan_kernel(const int* cnt, int* rowptr, int* cursor) {
    __shared__ int wsum[16];
    int tid = threadIdx.x;
    int lane = tid & 63, w = tid >> 6;
    int run = 0;
    for (int base = 0; base < NN; base += 1024) {
        int idx = base + tid;
        int c = (idx < NN) ? cnt[idx] : 0;
        int v = c;
        #pragma unroll
        for (int off = 1; off < 64; off <<= 1) {
            int t = __shfl_up(v, off, 64);
            if (lane >= off) v += t;
        }
        if (lane == 63) wsum[w] = v;
        __syncthreads();
        if (tid < 16) {
            int x = wsum[tid];
            #pragma unroll
            for (int off = 1; off < 16; off <<= 1) {
                int t = __shfl_up(x, off, 64);
                if (tid >= off) x += t;
            }
            wsum[tid] = x;
        }
        __syncthreads();
        int waveoff = (w > 0) ? wsum[w - 1] : 0;
        int excl = run + waveoff + (v - c);
        if (idx < NN) { rowptr[idx] = excl; cursor[idx] = excl; }
        run += wsum[15];
        __syncthreads();
    }
    if (tid == 0) rowptr[NN] = run;
}

__global__ void fill_kernel(const int* ei, const float* ea, const float* dinv,
                            int* cursor, int* colIdx, float* valArr) {
    int e = blockIdx.x * 256 + threadIdx.x;
    if (e >= EE) return;
    int s = ei[e], d = ei[EE + e];
    float w = ea[e * 2 + 1];
    int pos = atomicAdd(&cursor[d], 1);
    colIdx[pos] = s;
    valArr[pos] = dinv[s] * w * dinv[d];
}

__global__ void transpose_kernel(const float* x, float* xT) {
    int i = blockIdx.x * 256 + threadIdx.x;
    if (i >= TT * NN * FF) return;
    int f = i & 31;
    int rest = i >> 5;
    int n = rest % NN;
    int t = rest / NN;
    xT[i] = x[n * (FF * TT) + f * TT + t];
}

// W (K,64) fp32 -> WT [64][K] bf16
__global__ void wconv_T(const float* W, short* WT, int K) {
    int i = blockIdx.x * 256 + threadIdx.x;
    if (i >= 64 * K) return;
    int n = i / K, k = i - n * K;
    WT[i] = bf16rne(W[(size_t)k * 64 + n]);
}
// identity convert (ipw already [n][k])
__global__ void wconv_I(const float* W, short* WT, int total) {
    int i = blockIdx.x * 256 + threadIdx.x;
    if (i < total) WT[i] = bf16rne(W[i]);
}

// raw normalized aggregation, width-32 (x for all t)
__global__ void gather_raw32(const float* __restrict__ srcbase, const float* __restrict__ dinv,
                             const int* __restrict__ rowptr, const int* __restrict__ colIdx,
                             const float* __restrict__ valArr, float* __restrict__ dstbase) {
    const float* src = srcbase + (size_t)blockIdx.y * NN * 32;
    float* dst = dstbase + (size_t)blockIdx.y * NN * 32;
    int node = blockIdx.x * 8 + threadIdx.x / 32;
    int lane = threadIdx.x % 32;
    float di = dinv[node];
    float acc = di * di * src[node * 32 + lane];
    int s = rowptr[node], e = rowptr[node + 1];
    int j = s;
    for (; j + 3 < e; j += 4) {
        int c0 = colIdx[j], c1 = colIdx[j + 1], c2 = colIdx[j + 2], c3 = colIdx[j + 3];
        float v0 = valArr[j], v1 = valArr[j + 1], v2 = valArr[j + 2], v3 = valArr[j + 3];
        acc += v0 * src[c0 * 32 + lane] + v1 * src[c1 * 32 + lane]
             + v2 * src[c2 * 32 + lane] + v3 * src[c3 * 32 + lane];
    }
    for (; j < e; ++j) acc += valArr[j] * src[colIdx[j] * 32 + lane];
    dst[node * 32 + lane] = acc;
}

// gather y0 + sigmoid epilogue -> g1 (one wave per node)
__global__ void gather_g1(const float* __restrict__ y0, const float* __restrict__ dinv,
                          const int* __restrict__ rowptr, const int* __restrict__ colIdx,
                          const float* __restrict__ valArr, const float* __restrict__ bg1,
                          float* __restrict__ g1) {
    int node = blockIdx.x * 4 + (threadIdx.x >> 6);
    int lane = threadIdx.x & 63;
    float di = dinv[node];
    float acc = di * di * y0[(size_t)node * 64 + lane];
    int s = rowptr[node], e = rowptr[node + 1];
    int j = s;
    for (; j + 3 < e; j += 4) {
        int c0 = colIdx[j], c1 = colIdx[j + 1], c2 = colIdx[j + 2], c3 = colIdx[j + 3];
        float v0 = valArr[j], v1 = valArr[j + 1], v2 = valArr[j + 2], v3 = valArr[j + 3];
        acc += v0 * y0[(size_t)c0 * 64 + lane] + v1 * y0[(size_t)c1 * 64 + lane]
             + v2 * y0[(size_t)c2 * 64 + lane] + v3 * y0[(size_t)c3 * 64 + lane];
    }
    for (; j < e; ++j) acc += valArr[j] * y0[(size_t)colIdx[j] * 64 + lane];
    g1[(size_t)node * 64 + lane] = sigmoidf_(acc + bg1[lane]);
}

// ---------------- MFMA kernels ----------------
// Conventions (m89/m91-verified): A[m=lane&15][k=quad*8+j]; B^T[n=lane&15][k=quad*8+j];
// C/D: col=lane&15, row=quad*4+reg.

// g0all = sigmoid(aggx @ Wg0 + bg0), rows = T*N, K=32
__launch_bounds__(256, 2)
__global__ void mfma_g0(const float* __restrict__ aggx, const short* __restrict__ Wg0T,
                        const float* __restrict__ bg0, float* __restrict__ g0all) {
    int tid = threadIdx.x;
    int wv = tid >> 6, lane = tid & 63;
    int quad = lane >> 4, ln = lane & 15;
    int m0 = blockIdx.x * 64 + wv * 16;
    short8 af = afrag_f32(aggx + (size_t)(m0 + ln) * 32 + quad * 8);
    floatx4 z = {0.f, 0.f, 0.f, 0.f};
    floatx4 acc[4] = {z, z, z, z};
    #pragma unroll
    for (int ct = 0; ct < 4; ++ct) {
        short8 bf = *reinterpret_cast<const short8*>(Wg0T + (size_t)(ct * 16 + ln) * 32 + quad * 8);
        acc[ct] = MFMA(af, bf, acc[ct]);
    }
    #pragma unroll
    for (int ct = 0; ct < 4; ++ct) {
        int col = ct * 16 + ln;
        float bb = bg0[col];
        #pragma unroll
        for (int r = 0; r < 4; ++r) {
            int row = m0 + quad * 4 + r;
            g0all[(size_t)row * 64 + col] = sigmoidf_(acc[ct][r] + bb);
        }
    }
}

// qkv = hseq @ ipw.T + ipb, rows = T*N, K=64, 192 cols
__launch_bounds__(256, 2)
__global__ void mfma_qkv(const float* __restrict__ hseq, const short* __restrict__ ipwB,
                         const float* __restrict__ ipb, float* __restrict__ qkv) {
    int tid = threadIdx.x;
    int wv = tid >> 6, lane = tid & 63;
    int quad = lane >> 4, ln = lane & 15;
    int m0 = blockIdx.x * 64 + wv * 16;
    short8 af0 = afrag_f32(hseq + (size_t)(m0 + ln) * 64 + quad * 8);
    short8 af1 = afrag_f32(hseq + (size_t)(m0 + ln) * 64 + 32 + quad * 8);
    floatx4 z = {0.f, 0.f, 0.f, 0.f};
    floatx4 acc[12];
    #pragma unroll
    for (int ct = 0; ct < 12; ++ct) acc[ct] = z;
    #pragma unroll
    for (int ct = 0; ct < 12; ++ct) {
        const short* br = ipwB + (size_t)(ct * 16 + ln) * 64;
        acc[ct] = MFMA(af0, *reinterpret_cast<const short8*>(br + quad * 8), acc[ct]);
        acc[ct] = MFMA(af1, *reinterpret_cast<const short8*>(br + 32 + quad * 8), acc[ct]);
    }
    #pragma unroll
    for (int ct = 0; ct < 12; ++ct) {
        int col = ct * 16 + ln;
        float bb = ipb[col];
        #pragma unroll
        for (int r = 0; r < 4; ++r) {
            int row = m0 + quad * 4 + r;
            qkv[(size_t)row * 192 + col] = acc[ct][r] + bb;
        }
    }
}

// fused cell0: u,r (K=160) -> rh via LDS -> c (K=160) -> h0' -> y0 = h0'@Wg1 (K=64)
__launch_bounds__(256, 2)
__global__ void mfma_cell0(const float* __restrict__ xt, const float* __restrict__ g0,
                           const float* __restrict__ h0c,
                           const short* __restrict__ Wu0T, const short* __restrict__ Wr0T,
                           const short* __restrict__ Wc0T, const short* __restrict__ Wg1T,
                           const float* __restrict__ bu0, const float* __restrict__ br0,
                           const float* __restrict__ bc0,
                           float* __restrict__ h0n, float* __restrict__ y0) {
    __shared__ short lds[4 * 16 * 72];
    int tid = threadIdx.x;
    int wv = tid >> 6, lane = tid & 63;
    int quad = lane >> 4, ln = lane & 15;
    int m0 = blockIdx.x * 64 + wv * 16;
    int arow = m0 + ln; if (arow > NN - 1) arow = NN - 1;
    short* T = lds + wv * (16 * 72);

    // A fragments for K=160: x(1 chunk) g0(2) h0(2)
    short8 af[5];
    af[0] = afrag_f32(xt + (size_t)arow * 32 + quad * 8);
    af[1] = afrag_f32(g0 + (size_t)arow * 64 + quad * 8);
    af[2] = afrag_f32(g0 + (size_t)arow * 64 + 32 + quad * 8);
    af[3] = afrag_f32(h0c + (size_t)arow * 64 + quad * 8);
    af[4] = afrag_f32(h0c + (size_t)arow * 64 + 32 + quad * 8);

    floatx4 z = {0.f, 0.f, 0.f, 0.f};
    floatx4 aU[4] = {z, z, z, z};
    floatx4 aR[4] = {z, z, z, z};
    #pragma unroll
    for (int ct = 0; ct < 4; ++ct) {
        const short* bu = Wu0T + (size_t)(ct * 16 + ln) * 160;
        const short* br = Wr0T + (size_t)(ct * 16 + ln) * 160;
        #pragma unroll
        for (int kc = 0; kc < 5; ++kc) {
            int ko = kc * 32 + quad * 8;
            aU[ct] = MFMA(af[kc], *reinterpret_cast<const short8*>(bu + ko), aU[ct]);
            aR[ct] = MFMA(af[kc], *reinterpret_cast<const short8*>(br + ko), aR[ct]);
        }
    }
    // epilogue 1: u kept in regs, rh -> LDS (A-layout)
    float uu[4][4];
    #pragma unroll
    for (int ct = 0; ct < 4; ++ct) {
        int col = ct * 16 + ln;
        float bU = bu0[col], bR = br0[col];
        #pragma unroll
        for (int r = 0; r < 4; ++r) {
            int grow = m0 + quad * 4 + r;
            bool ok = grow < NN;
            uu[ct][r] = sigmoidf_(aU[ct][r] + bU);
            float hv = ok ? h0c[(size_t)grow * 64 + col] : 0.f;
            float rh = sigmoidf_(aR[ct][r] + bR) * hv;
            T[(quad * 4 + r) * 72 + col] = bf16rne(rh);
        }
    }
    __syncthreads();

    // c GEMM: chunks 0-2 reuse af, 3-4 from LDS rh
    short8 ar0 = *reinterpret_cast<const short8*>(T + ln * 72 + quad * 8);
    short8 ar1 = *reinterpret_cast<const short8*>(T + ln * 72 + 32 + quad * 8);
    floatx4 aC[4] = {z, z, z, z};
    #pragma unroll
    for (int ct = 0; ct < 4; ++ct) {
        const short* bc = Wc0T + (size_t)(ct * 16 + ln) * 160;
        #pragma unroll
        for (int kc = 0; kc < 3; ++kc)
            aC[ct] = MFMA(af[kc], *reinterpret_cast<const short8*>(bc + kc * 32 + quad * 8), aC[ct]);
        aC[ct] = MFMA(ar0, *reinterpret_cast<const short8*>(bc + 96 + quad * 8), aC[ct]);
        aC[ct] = MFMA(ar1, *reinterpret_cast<const short8*>(bc + 128 + quad * 8), aC[ct]);
    }
    __syncthreads();
    // epilogue 2: h0' -> global + LDS
    #pragma unroll
    for (int ct = 0; ct < 4; ++ct) {
        int col = ct * 16 + ln;
        float bC = bc0[col];
        #pragma unroll
        for (int r = 0; r < 4; ++r) {
            int grow = m0 + quad * 4 + r;
            bool ok = grow < NN;
            float hv = ok ? h0c[(size_t)grow * 64 + col] : 0.f;
            float cv = tanhf(aC[ct][r] + bC);
            float hn = uu[ct][r] * hv + (1.f - uu[ct][r]) * cv;
            if (ok) h0n[(size_t)grow * 64 + col] = hn;
            T[(quad * 4 + r) * 72 + col] = bf16rne(hn);
        }
    }
    __syncthreads();

    // y0 = h0' @ Wg1 (K=64)
    short8 ah0 = *reinterpret_cast<const short8*>(T + ln * 72 + quad * 8);
    short8 ah1 = *reinterpret_cast<const short8*>(T + ln * 72 + 32 + quad * 8);
    floatx4 aY[4] = {z, z, z, z};
    #pragma unroll
    for (int ct = 0; ct < 4; ++ct) {
        const short* bg = Wg1T + (size_t)(ct * 16 + ln) * 64;
        aY[ct] = MFMA(ah0, *reinterpret_cast<const short8*>(bg + quad * 8), aY[ct]);
        aY[ct] = MFMA(ah1, *reinterpret_cast<const short8*>(bg + 32 + quad * 8), aY[ct]);
    }
    #pragma unroll
    for (int ct = 0; ct < 4; ++ct) {
        int col = ct * 16 + ln;
        #pragma unroll
        for (int r = 0; r < 4; ++r) {
            int grow = m0 + quad * 4 + r;
            if (grow < NN) y0[(size_t)grow * 64 + col] = aY[ct][r];
        }
    }
}

// fused cell1: u1,r1 (K=192) -> rh1 via LDS -> c1 (K=192) -> h1' (+hseq)
__launch_bounds__(256, 2)
__global__ void mfma_cell1(const float* __restrict__ h0n, const float* __restrict__ g1,
                           const float* __restrict__ h1c,
                           const short* __restrict__ Wu1T, const short* __restrict__ Wr1T,
                           const short* __restrict__ Wc1T,
                           const float* __restrict__ bu1, const float* __restrict__ br1,
                           const float* __restrict__ bc1,
                           float* __restrict__ h1n, float* __restrict__ hs) {
    __shared__ short lds[4 * 16 * 72];
    int tid = threadIdx.x;
    int wv = tid >> 6, lane = tid & 63;
    int quad = lane >> 4, ln = lane & 15;
    int m0 = blockIdx.x * 64 + wv * 16;
    int arow = m0 + ln; if (arow > NN - 1) arow = NN - 1;
    short* T = lds + wv * (16 * 72);

    short8 af[6];
    af[0] = afrag_f32(h0n + (size_t)arow * 64 + quad * 8);
    af[1] = afrag_f32(h0n + (size_t)arow * 64 + 32 + quad * 8);
    af[2] = afrag_f32(g1 + (size_t)arow * 64 + quad * 8);
    af[3] = afrag_f32(g1 + (size_t)arow * 64 + 32 + quad * 8);
    af[4] = afrag_f32(h1c + (size_t)arow * 64 + quad * 8);
    af[5] = afrag_f32(h1c + (size_t)arow * 64 + 32 + quad * 8);

    floatx4 z = {0.f, 0.f, 0.f, 0.f};
    floatx4 aU[4] = {z, z, z, z};
    floatx4 aR[4] = {z, z, z, z};
    #pragma unroll
    for (int ct = 0; ct < 4; ++ct) {
        const short* bu = Wu1T + (size_t)(ct * 16 + ln) * 192;
        const short* br = Wr1T + (size_t)(ct * 16 + ln) * 192;
        #pragma unroll
        for (int kc = 0; kc < 6; ++kc) {
            int ko = kc * 32 + quad * 8;
            aU[ct] = MFMA(af[kc], *reinterpret_cast<const short8*>(bu + ko), aU[ct]);
            aR[ct] = MFMA(af[kc], *reinterpret_cast<const short8*>(br + ko), aR[ct]);
        }
    }
    float uu[4][4];
    #pragma unroll
    for (int ct = 0; ct < 4; ++ct) {
        int col = ct * 16 + ln;
        float bU = bu1[col], bR = br1[col];
        #pragma unroll
        for (int r = 0; r < 4; ++r) {
            int grow = m0 + quad * 4 + r;
            bool ok = grow < NN;
            uu[ct][r] = sigmoidf_(aU[ct][r] + bU);
            float hv = ok ? h1c[(size_t)grow * 64 + col] : 0.f;
            float rh = sigmoidf_(aR[ct][r] + bR) * hv;
            T[(quad * 4 + r) * 72 + col] = bf16rne(rh);
        }
    }
    __syncthreads();

    short8 ar0 = *reinterpret_cast<const short8*>(T + ln * 72 + quad * 8);
    short8 ar1 = *reinterpret_cast<const short8*>(T + ln * 72 + 32 + quad * 8);
    floatx4 aC[4] = {z, z, z, z};
    #pragma unroll
    for (int ct = 0; ct < 4; ++ct) {
        const short* bc = Wc1T + (size_t)(ct * 16 + ln) * 192;
        #pragma unroll
        for (int kc = 0; kc < 4; ++kc)
            aC[ct] = MFMA(af[kc], *reinterpret_cast<const short8*>(bc + kc * 32 + quad * 8), aC[ct]);
        aC[ct] = MFMA(ar0, *reinterpret_cast<const short8*>(bc + 128 + quad * 8), aC[ct]);
        aC[ct] = MFMA(ar1, *reinterpret_cast<const short8*>(bc + 160 + quad * 8), aC[ct]);
    }
    #pragma unroll
    for (int ct = 0; ct < 4; ++ct) {
        int col = ct * 16 + ln;
        float bC = bc1[col];
        #pragma unroll
        for (int r = 0; r < 4; ++r) {
            int grow = m0 + quad * 4 + r;
            if (grow >= NN) continue;
            float hv = h1c[(size_t)grow * 64 + col];
            float cv = tanhf(aC[ct][r] + bC);
            float hn = uu[ct][r] * hv + (1.f - uu[ct][r]) * cv;
            h1n[(size_t)grow * 64 + col] = hn;
            hs[(size_t)grow * 64 + col] = hn;
        }
    }
}

// ---------------- attention core ----------------
__global__ void attn_core(const float* __restrict__ qkv,
                          const float* __restrict__ opw, const float* __restrict__ opb,
                          const float* __restrict__ ow, const float* __restrict__ ob,
                          float* __restrict__ out) {
    __shared__ float smem[4 * 2768];
    int w = threadIdx.x >> 6;
    int lane = threadIdx.x & 63;
    int node = blockIdx.x * 4 + w;
    float* shq = smem + w * 2768;
    float* sp  = shq + 2352;
    float* sob = shq + 2640;
    float* sha = shq + 2704;

    for (int idx = lane; idx < TT * 192; idx += 64) {
        int t = idx / 192, j = idx - t * 192;
        shq[t * 196 + j] = qkv[((size_t)t * NN + node) * 192 + j];
    }
    __syncthreads();

    if (lane < 24) {
        int hd = lane / 12, tq = lane % 12;
        const float* qrow = shq + tq * 196 + hd * 32;
        float sc[12];
        float mx = -1e30f;
        #pragma unroll
        for (int s = 0; s < 12; ++s) {
            const float* krow = shq + s * 196 + 64 + hd * 32;
            float a = 0.f;
            #pragma unroll
            for (int d = 0; d < 32; ++d) a += qrow[d] * krow[d];
            a *= 0.17677669529663687f;
            sc[s] = a; mx = fmaxf(mx, a);
        }
        float sum = 0.f;
        #pragma unroll
        for (int s = 0; s < 12; ++s) { sc[s] = expf(sc[s] - mx); sum += sc[s]; }
        float inv = 1.f / sum;
        #pragma unroll
        for (int s = 0; s < 12; ++s) sp[(hd * 12 + tq) * 12 + s] = sc[s] * inv;
    }
    __syncthreads();

    {
        int d = lane, hd = d >> 5;
        float acc = 0.f;
        #pragma unroll
        for (int s = 0; s < 12; ++s) {
            float ts = 0.f;
            #pragma unroll
            for (int t = 0; t < 12; ++t) ts += sp[(hd * 12 + t) * 12 + s];
            acc += ts * shq[s * 196 + 128 + d];
        }
        sob[d] = acc * (1.f / 12.f);
    }
    __syncthreads();

    {
        int d = lane;
        float acc = opb[d];
        const float* wrow = opw + d * 64;
        #pragma unroll
        for (int k = 0; k < 64; ++k) acc += sob[k] * wrow[k];
        sha[d] = acc;
    }
    __syncthreads();

    if (lane < OUTD) {
        float acc = ob[lane];
        #pragma unroll
        for (int k = 0; k < 64; ++k) acc += sha[k] * ow[k * OUTD + lane];
        out[(size_t)node * OUTD + lane] = acc;
    }
}

// ---------------- launcher ----------------

extern "C" void kernel_launch(void* const* d_in, const int* in_sizes, int n_in,
                              void* d_out, int out_size, void* d_ws, size_t ws_size,
                              hipStream_t stream) {
    const float* x   = (const float*)d_in[0];
    const int*   ei  = (const int*)d_in[1];
    const float* ea  = (const float*)d_in[2];
    const float* Wg0 = (const float*)d_in[3];
    const float* bg0 = (const float*)d_in[4];
    const float* Wu0 = (const float*)d_in[5];
    const float* bu0 = (const float*)d_in[6];
    const float* Wr0 = (const float*)d_in[7];
    const float* br0 = (const float*)d_in[8];
    const float* Wc0 = (const float*)d_in[9];
    const float* bc0 = (const float*)d_in[10];
    const float* Wg1 = (const float*)d_in[11];
    const float* bg1 = (const float*)d_in[12];
    const float* Wu1 = (const float*)d_in[13];
    const float* bu1 = (const float*)d_in[14];
    const float* Wr1 = (const float*)d_in[15];
    const float* br1 = (const float*)d_in[16];
    const float* Wc1 = (const float*)d_in[17];
    const float* bc1 = (const float*)d_in[18];
    const float* ipw = (const float*)d_in[19];
    const float* ipb = (const float*)d_in[20];
    const float* opw = (const float*)d_in[21];
    const float* opb = (const float*)d_in[22];
    const float* ow  = (const float*)d_in[23];
    const float* ob  = (const float*)d_in[24];
    float* out = (float*)d_out;

    char* p = (char*)d_ws;
    auto alloc = [&](size_t bytes) { char* r = p; p += (bytes + 255) & ~(size_t)255; return (void*)r; };
    // persistent
    float* hseq  = (float*)alloc((size_t)TT * NN * HH * 4);
    short* Wg0T  = (short*)alloc((size_t)64 * 32 * 2);
    short* Wu0T  = (short*)alloc((size_t)64 * 160 * 2);
    short* Wr0T  = (short*)alloc((size_t)64 * 160 * 2);
    short* Wc0T  = (short*)alloc((size_t)64 * 160 * 2);
    short* Wg1T  = (short*)alloc((size_t)64 * 64 * 2);
    short* Wu1T  = (short*)alloc((size_t)64 * 192 * 2);
    short* Wr1T  = (short*)alloc((size_t)64 * 192 * 2);
    short* Wc1T  = (short*)alloc((size_t)64 * 192 * 2);
    short* ipwB  = (short*)alloc((size_t)192 * 64 * 2);
    float* dinv   = (float*)alloc((size_t)NN * 4);
    int*   rowptr = (int*)  alloc((size_t)(NN + 1) * 4);
    int*   colIdx = (int*)  alloc((size_t)EE * 4);
    float* valArr = (float*)alloc((size_t)EE * 4);
    // union: loop-phase buffers vs qkv (qkv written only after loop)
    char* ubase = p;
    float* xT     = (float*)alloc((size_t)TT * NN * FF * 4);
    float* aggx   = (float*)alloc((size_t)TT * NN * FF * 4);
    float* g0all  = (float*)alloc((size_t)TT * NN * HH * 4);
    float* deg    = (float*)alloc((size_t)NN * 4);
    int*   cnt    = (int*)  alloc((size_t)NN * 4);
    int*   cursor = (int*)  alloc((size_t)NN * 4);
    float* y0     = (float*)alloc((size_t)NN * HH * 4);
    float* g1     = (float*)alloc((size_t)NN * HH * 4);
    float* h0a    = (float*)alloc((size_t)NN * HH * 4);
    float* h0b    = (float*)alloc((size_t)NN * HH * 4);
    float* h1a    = (float*)alloc((size_t)NN * HH * 4);
    float* h1b    = (float*)alloc((size_t)NN * HH * 4);
    size_t qkv_bytes = (size_t)TT * NN * 192 * 4;
    float* qkv = (float*)ubase;
    char* endA = p;
    char* endB = ubase + ((qkv_bytes + 255) & ~(size_t)255);
    p = (endA > endB) ? endA : endB;
    (void)ws_size;

    hipMemsetAsync(cnt, 0, (size_t)NN * 4, stream);
    hipMemsetAsync(h0a, 0, (size_t)NN * HH * 4, stream);
    hipMemsetAsync(h1a, 0, (size_t)NN * HH * 4, stream);
    deg_init_kernel<<<(NN + 255) / 256, 256, 0, stream>>>(deg);
    edge_accum_kernel<<<(EE + 255) / 256, 256, 0, stream>>>(ei, ea, deg, cnt);
    dinv_kernel<<<(NN + 255) / 256, 256, 0, stream>>>(deg, dinv);
    scan_kernel<<<1, 1024, 0, stream>>>(cnt, rowptr, cursor);
    fill_kernel<<<(EE + 255) / 256, 256, 0, stream>>>(ei, ea, dinv, cursor, colIdx, valArr);
    transpose_kernel<<<(TT * NN * FF + 255) / 256, 256, 0, stream>>>(x, xT);

    wconv_T<<<(64 * 32 + 255) / 256, 256, 0, stream>>>(Wg0, Wg0T, 32);
    wconv_T<<<(64 * 160 + 255) / 256, 256, 0, stream>>>(Wu0, Wu0T, 160);
    wconv_T<<<(64 * 160 + 255) / 256, 256, 0, stream>>>(Wr0, Wr0T, 160);
    wconv_T<<<(64 * 160 + 255) / 256, 256, 0, stream>>>(Wc0, Wc0T, 160);
    wconv_T<<<(64 * 64 + 255) / 256, 256, 0, stream>>>(Wg1, Wg1T, 64);
    wconv_T<<<(64 * 192 + 255) / 256, 256, 0, stream>>>(Wu1, Wu1T, 192);
    wconv_T<<<(64 * 192 + 255) / 256, 256, 0, stream>>>(Wr1, Wr1T, 192);
    wconv_T<<<(64 * 192 + 255) / 256, 256, 0, stream>>>(Wc1, Wc1T, 192);
    wconv_I<<<(192 * 64 + 255) / 256, 256, 0, stream>>>(ipw, ipwB, 192 * 64);

    // aggregate x for all t, then g0 for all t
    gather_raw32<<<dim3(NN / 8, TT), 256, 0, stream>>>(xT, dinv, rowptr, colIdx, valArr, aggx);
    mfma_g0<<<(TT * NN) / 64, 256, 0, stream>>>(aggx, Wg0T, bg0, g0all);

    const int CB = (NN + 63) / 64;   // 313
    for (int t = 0; t < TT; ++t) {
        const float* xt = xT + (size_t)t * NN * FF;
        const float* g0 = g0all + (size_t)t * NN * HH;
        float* h0_in  = (t & 1) ? h0b : h0a;
        float* h0_out = (t & 1) ? h0a : h0b;
        float* h1_in  = (t & 1) ? h1b : h1a;
        float* h1_out = (t & 1) ? h1a : h1b;
        mfma_cell0<<<CB, 256, 0, stream>>>(
            xt, g0, h0_in, Wu0T, Wr0T, Wc0T, Wg1T, bu0, br0, bc0, h0_out, y0);
        gather_g1<<<NN / 4, 256, 0, stream>>>(y0, dinv, rowptr, colIdx, valArr, bg1, g1);
        mfma_cell1<<<CB, 256, 0, stream>>>(
            h0_out, g1, h1_in, Wu1T, Wr1T, Wc1T, bu1, br1, bc1,
            h1_out, hseq + (size_t)t * NN * HH);
    }

    mfma_qkv<<<(TT * NN) / 64, 256, 0, stream>>>(hseq, ipwB, ipb, qkv);
    attn_core<<<NN / 4, 256, 0, stream>>>(qkv, opw, opb, ow, ob, out);
}

// Round 7
// 1240.063 us; speedup vs baseline: 18.3214x; 1.0783x over previous
//
#include <hip/hip_runtime.h>
#include <math.h>

#define NN 20000
#define FF 32
#define TT 12
#define HH 64
#define EE 320000
#define OUTD 12

typedef __attribute__((ext_vector_type(8))) short short8;
typedef __attribute__((ext_vector_type(4))) float floatx4;

__device__ __forceinline__ float sigmoidf_(float x) { return 1.f / (1.f + expf(-x)); }

__device__ __forceinline__ unsigned short bf16rne(float f) {
    union { float f; unsigned u; } v; v.f = f;
    unsigned u = v.u;
    u += 0x7fffu + ((u >> 16) & 1u);
    return (unsigned short)(u >> 16);
}
__device__ __forceinline__ float lof(unsigned v) {
    union { unsigned u; float f; } x; x.u = v << 16; return x.f;
}
__device__ __forceinline__ float hif(unsigned v) {
    union { unsigned u; float f; } x; x.u = v & 0xffff0000u; return x.f;
}
__device__ __forceinline__ unsigned packbf(float a, float b) {
    return (unsigned)bf16rne(a) | ((unsigned)bf16rne(b) << 16);
}

#define MFMA(a, b, c) __builtin_amdgcn_mfma_f32_16x16x32_bf16((a), (b), (c), 0, 0, 0)

// ---------------- preprocessing ----------------

__global__ void deg_init_kernel(float* deg) {
    int i = blockIdx.x * 256 + threadIdx.x;
    if (i < NN) deg[i] = 1.0f;
}

__global__ void edge_accum_kernel(const int* ei, const float* ea, float* deg, int* cnt) {
    int e = blockIdx.x * 256 + threadIdx.x;
    if (e >= EE) return;
    int d = ei[EE + e];
    float w = ea[e * 2 + 1];
    atomicAdd(&deg[d], w);
    atomicAdd(&cnt[d], 1);
}

__global__ void dinv_kernel(const float* deg, float* dinv) {
    int i = blockIdx.x * 256 + threadIdx.x;
    if (i < NN) dinv[i] = rsqrtf(deg[i]);
}

__global__ void scan_kernel(const int* cnt, int* rowptr, int* cursor) {
    __shared__ int wsum[16];
    int tid = threadIdx.x;
    int lane = tid & 63, w = tid >> 6;
    int run = 0;
    for (int base = 0; base < NN; base += 1024) {
        int idx = base + tid;
        int c = (idx < NN) ? cnt[idx] : 0;
        int v = c;
        #pragma unroll
        for (int off = 1; off < 64; off <<= 1) {
            int t = __shfl_up(v, off, 64);
            if (lane >= off) v += t;
        }
        if (lane == 63) wsum[w] = v;
        __syncthreads();
        if (tid < 16) {
            int x = wsum[tid];
            #pragma unroll
            for (int off = 1; off < 16; off <<= 1) {
                int t = __shfl_up(x, off, 64);
                if (tid >= off) x += t;
            }
            wsum[tid] = x;
        }
        __syncthreads();
        int waveoff = (w > 0) ? wsum[w - 1] : 0;
        int excl = run + waveoff + (v - c);
        if (idx < NN) { rowptr[idx] = excl; cursor[idx] = excl; }
        run += wsum[15];
        __syncthreads();
    }
    if (tid == 0) rowptr[NN] = run;
}

__global__ void fill_kernel(const int* ei, const float* ea, const float* dinv,
                            int* cursor, int* colIdx, float* valArr) {
    int e = blockIdx.x * 256 + threadIdx.x;
    if (e >= EE) return;
    int s = ei[e], d = ei[EE + e];
    float w = ea[e * 2 + 1];
    int pos = atomicAdd(&cursor[d], 1);
    colIdx[pos] = s;
    valArr[pos] = dinv[s] * w * dinv[d];
}

// x (N,F,T) fp32 -> xTs (T,N,F) bf16
__global__ void transpose_kernel(const float* x, unsigned short* xTs) {
    int i = blockIdx.x * 256 + threadIdx.x;
    if (i >= TT * NN * FF) return;
    int f = i & 31;
    int rest = i >> 5;
    int n = rest % NN;
    int t = rest / NN;
    xTs[i] = bf16rne(x[n * (FF * TT) + f * TT + t]);
}

// all 9 weight conversions in one launch; *T variants transpose (K,64)->[64][K]
__global__ void wconv_all(const float* Wg0, const float* Wu0, const float* Wr0, const float* Wc0,
                          const float* Wg1, const float* Wu1, const float* Wr1, const float* Wc1,
                          const float* ipw,
                          short* Wg0T, short* Wu0T, short* Wr0T, short* Wc0T,
                          short* Wg1T, short* Wu1T, short* Wr1T, short* Wc1T, short* ipwB) {
    int i = blockIdx.x * 256 + threadIdx.x;
    if (i < 2048) { int n = i / 32, k = i % 32; Wg0T[i] = (short)bf16rne(Wg0[k * 64 + n]); return; }
    i -= 2048;
    if (i < 10240) { int n = i / 160, k = i % 160; Wu0T[i] = (short)bf16rne(Wu0[k * 64 + n]); return; }
    i -= 10240;
    if (i < 10240) { int n = i / 160, k = i % 160; Wr0T[i] = (short)bf16rne(Wr0[k * 64 + n]); return; }
    i -= 10240;
    if (i < 10240) { int n = i / 160, k = i % 160; Wc0T[i] = (short)bf16rne(Wc0[k * 64 + n]); return; }
    i -= 10240;
    if (i < 4096) { int n = i / 64, k = i % 64; Wg1T[i] = (short)bf16rne(Wg1[k * 64 + n]); return; }
    i -= 4096;
    if (i < 12288) { int n = i / 192, k = i % 192; Wu1T[i] = (short)bf16rne(Wu1[k * 64 + n]); return; }
    i -= 12288;
    if (i < 12288) { int n = i / 192, k = i % 192; Wr1T[i] = (short)bf16rne(Wr1[k * 64 + n]); return; }
    i -= 12288;
    if (i < 12288) { int n = i / 192, k = i % 192; Wc1T[i] = (short)bf16rne(Wc1[k * 64 + n]); return; }
    i -= 12288;
    if (i < 12288) { ipwB[i] = (short)bf16rne(ipw[i]); }
}

// bf16 aggregation over x planes: 16 lanes/node, 2 features per lane
__global__ void gather_raw32(const unsigned short* __restrict__ xTs, const float* __restrict__ dinv,
                             const int* __restrict__ rowptr, const int* __restrict__ colIdx,
                             const float* __restrict__ valArr, unsigned short* __restrict__ aggxs) {
    const unsigned* src = (const unsigned*)(xTs + (size_t)blockIdx.y * NN * 32);
    unsigned* dst = (unsigned*)(aggxs + (size_t)blockIdx.y * NN * 32);
    int node = blockIdx.x * 16 + (threadIdx.x >> 4);
    int l2 = threadIdx.x & 15;
    float di = dinv[node];
    float dd = di * di;
    unsigned v = src[node * 16 + l2];
    float a0 = dd * lof(v), a1 = dd * hif(v);
    int s = rowptr[node], e = rowptr[node + 1];
    int j = s;
    for (; j + 3 < e; j += 4) {
        int c0 = colIdx[j], c1 = colIdx[j + 1], c2 = colIdx[j + 2], c3 = colIdx[j + 3];
        float w0 = valArr[j], w1 = valArr[j + 1], w2 = valArr[j + 2], w3 = valArr[j + 3];
        unsigned v0 = src[c0 * 16 + l2], v1 = src[c1 * 16 + l2];
        unsigned v2 = src[c2 * 16 + l2], v3 = src[c3 * 16 + l2];
        a0 += w0 * lof(v0) + w1 * lof(v1) + w2 * lof(v2) + w3 * lof(v3);
        a1 += w0 * hif(v0) + w1 * hif(v1) + w2 * hif(v2) + w3 * hif(v3);
    }
    for (; j < e; ++j) {
        unsigned vv = src[colIdx[j] * 16 + l2];
        float w = valArr[j];
        a0 += w * lof(vv); a1 += w * hif(vv);
    }
    dst[node * 16 + l2] = packbf(a0, a1);
}

// gather y0 (bf16) + sigmoid -> g1 (bf16): 32 lanes/node, 2 features per lane
__global__ void gather_g1(const unsigned short* __restrict__ y0s, const float* __restrict__ dinv,
                          const int* __restrict__ rowptr, const int* __restrict__ colIdx,
                          const float* __restrict__ valArr, const float* __restrict__ bg1,
                          unsigned short* __restrict__ g1s) {
    const unsigned* yp = (const unsigned*)y0s;
    int node = blockIdx.x * 8 + (threadIdx.x >> 5);
    int l2 = threadIdx.x & 31;
    float di = dinv[node];
    float dd = di * di;
    unsigned v = yp[node * 32 + l2];
    float a0 = dd * lof(v), a1 = dd * hif(v);
    int s = rowptr[node], e = rowptr[node + 1];
    int j = s;
    for (; j + 3 < e; j += 4) {
        int c0 = colIdx[j], c1 = colIdx[j + 1], c2 = colIdx[j + 2], c3 = colIdx[j + 3];
        float w0 = valArr[j], w1 = valArr[j + 1], w2 = valArr[j + 2], w3 = valArr[j + 3];
        unsigned v0 = yp[c0 * 32 + l2], v1 = yp[c1 * 32 + l2];
        unsigned v2 = yp[c2 * 32 + l2], v3 = yp[c3 * 32 + l2];
        a0 += w0 * lof(v0) + w1 * lof(v1) + w2 * lof(v2) + w3 * lof(v3);
        a1 += w0 * hif(v0) + w1 * hif(v1) + w2 * hif(v2) + w3 * hif(v3);
    }
    for (; j < e; ++j) {
        unsigned vv = yp[colIdx[j] * 32 + l2];
        float w = valArr[j];
        a0 += w * lof(vv); a1 += w * hif(vv);
    }
    float g0v = sigmoidf_(a0 + bg1[2 * l2]);
    float g1v = sigmoidf_(a1 + bg1[2 * l2 + 1]);
    ((unsigned*)g1s)[node * 32 + l2] = packbf(g0v, g1v);
}

// ---------------- MFMA kernels ----------------
// A[m=lane&15][k=quad*8+j]; B^T[n=lane&15][k=quad*8+j]; C/D: col=lane&15, row=quad*4+reg.

// g0all = sigmoid(aggx @ Wg0 + bg0) -> bf16, rows = T*N, K=32
__launch_bounds__(256, 4)
__global__ void mfma_g0(const unsigned short* __restrict__ aggxs, const short* __restrict__ Wg0T,
                        const float* __restrict__ bg0, unsigned short* __restrict__ g0s) {
    int tid = threadIdx.x;
    int wv = tid >> 6, lane = tid & 63;
    int quad = lane >> 4, ln = lane & 15;
    int m0 = blockIdx.x * 64 + wv * 16;
    short8 af = *reinterpret_cast<const short8*>(aggxs + (size_t)(m0 + ln) * 32 + quad * 8);
    floatx4 z = {0.f, 0.f, 0.f, 0.f};
    floatx4 acc[4] = {z, z, z, z};
    #pragma unroll
    for (int ct = 0; ct < 4; ++ct) {
        short8 bf = *reinterpret_cast<const short8*>(Wg0T + (size_t)(ct * 16 + ln) * 32 + quad * 8);
        acc[ct] = MFMA(af, bf, acc[ct]);
    }
    #pragma unroll
    for (int ct = 0; ct < 4; ++ct) {
        int col = ct * 16 + ln;
        float bb = bg0[col];
        #pragma unroll
        for (int r = 0; r < 4; ++r) {
            int row = m0 + quad * 4 + r;
            g0s[(size_t)row * 64 + col] = bf16rne(sigmoidf_(acc[ct][r] + bb));
        }
    }
}

// qkv = hseq @ ipw.T + ipb -> bf16 node-major [n][t][192]
__launch_bounds__(256, 2)
__global__ void mfma_qkv(const unsigned short* __restrict__ hseqs, const short* __restrict__ ipwB,
                         const float* __restrict__ ipb, unsigned short* __restrict__ qkvs) {
    int tid = threadIdx.x;
    int wv = tid >> 6, lane = tid & 63;
    int quad = lane >> 4, ln = lane & 15;
    int m0 = blockIdx.x * 64 + wv * 16;
    short8 af0 = *reinterpret_cast<const short8*>(hseqs + (size_t)(m0 + ln) * 64 + quad * 8);
    short8 af1 = *reinterpret_cast<const short8*>(hseqs + (size_t)(m0 + ln) * 64 + 32 + quad * 8);
    floatx4 z = {0.f, 0.f, 0.f, 0.f};
    floatx4 acc[12];
    #pragma unroll
    for (int ct = 0; ct < 12; ++ct) acc[ct] = z;
    #pragma unroll
    for (int ct = 0; ct < 12; ++ct) {
        const short* br = ipwB + (size_t)(ct * 16 + ln) * 64;
        acc[ct] = MFMA(af0, *reinterpret_cast<const short8*>(br + quad * 8), acc[ct]);
        acc[ct] = MFMA(af1, *reinterpret_cast<const short8*>(br + 32 + quad * 8), acc[ct]);
    }
    #pragma unroll
    for (int ct = 0; ct < 12; ++ct) {
        int col = ct * 16 + ln;
        float bb = ipb[col];
        #pragma unroll
        for (int r = 0; r < 4; ++r) {
            int row = m0 + quad * 4 + r;   // = t*NN + n
            int t = row / NN;
            int n = row - t * NN;
            qkvs[((size_t)n * TT + t) * 192 + col] = bf16rne(acc[ct][r] + bb);
        }
    }
}

// fused cell0: u,r (K=160) -> rh via LDS -> c (K=160) -> h0' -> y0 = h0'@Wg1 (K=64)
__launch_bounds__(256, 4)
__global__ void mfma_cell0(const unsigned short* __restrict__ xt, const unsigned short* __restrict__ g0,
                           const float* __restrict__ h0f, const unsigned short* __restrict__ h0s,
                           const short* __restrict__ Wu0T, const short* __restrict__ Wr0T,
                           const short* __restrict__ Wc0T, const short* __restrict__ Wg1T,
                           const float* __restrict__ bu0, const float* __restrict__ br0,
                           const float* __restrict__ bc0,
                           float* __restrict__ h0nf, unsigned short* __restrict__ h0ns,
                           unsigned short* __restrict__ y0s) {
    __shared__ short lds[4 * 16 * 72];
    int tid = threadIdx.x;
    int wv = tid >> 6, lane = tid & 63;
    int quad = lane >> 4, ln = lane & 15;
    int m0 = blockIdx.x * 64 + wv * 16;
    int arow = m0 + ln; if (arow > NN - 1) arow = NN - 1;
    short* T = lds + wv * (16 * 72);

    short8 af[5];
    af[0] = *reinterpret_cast<const short8*>(xt + (size_t)arow * 32 + quad * 8);
    af[1] = *reinterpret_cast<const short8*>(g0 + (size_t)arow * 64 + quad * 8);
    af[2] = *reinterpret_cast<const short8*>(g0 + (size_t)arow * 64 + 32 + quad * 8);
    af[3] = *reinterpret_cast<const short8*>(h0s + (size_t)arow * 64 + quad * 8);
    af[4] = *reinterpret_cast<const short8*>(h0s + (size_t)arow * 64 + 32 + quad * 8);

    floatx4 z = {0.f, 0.f, 0.f, 0.f};
    floatx4 aU[4] = {z, z, z, z};
    floatx4 aR[4] = {z, z, z, z};
    #pragma unroll
    for (int ct = 0; ct < 4; ++ct) {
        const short* bu = Wu0T + (size_t)(ct * 16 + ln) * 160;
        const short* br = Wr0T + (size_t)(ct * 16 + ln) * 160;
        #pragma unroll
        for (int kc = 0; kc < 5; ++kc) {
            int ko = kc * 32 + quad * 8;
            aU[ct] = MFMA(af[kc], *reinterpret_cast<const short8*>(bu + ko), aU[ct]);
            aR[ct] = MFMA(af[kc], *reinterpret_cast<const short8*>(br + ko), aR[ct]);
        }
    }
    float uu[4][4];
    #pragma unroll
    for (int ct = 0; ct < 4; ++ct) {
        int col = ct * 16 + ln;
        float bU = bu0[col], bR = br0[col];
        #pragma unroll
        for (int r = 0; r < 4; ++r) {
            int grow = m0 + quad * 4 + r;
            bool ok = grow < NN;
            uu[ct][r] = sigmoidf_(aU[ct][r] + bU);
            float hv = ok ? h0f[(size_t)grow * 64 + col] : 0.f;
            float rh = sigmoidf_(aR[ct][r] + bR) * hv;
            T[(quad * 4 + r) * 72 + col] = (short)bf16rne(rh);
        }
    }
    __syncthreads();

    short8 ar0 = *reinterpret_cast<const short8*>(T + ln * 72 + quad * 8);
    short8 ar1 = *reinterpret_cast<const short8*>(T + ln * 72 + 32 + quad * 8);
    floatx4 aC[4] = {z, z, z, z};
    #pragma unroll
    for (int ct = 0; ct < 4; ++ct) {
        const short* bc = Wc0T + (size_t)(ct * 16 + ln) * 160;
        #pragma unroll
        for (int kc = 0; kc < 3; ++kc)
            aC[ct] = MFMA(af[kc], *reinterpret_cast<const short8*>(bc + kc * 32 + quad * 8), aC[ct]);
        aC[ct] = MFMA(ar0, *reinterpret_cast<const short8*>(bc + 96 + quad * 8), aC[ct]);
        aC[ct] = MFMA(ar1, *reinterpret_cast<const short8*>(bc + 128 + quad * 8), aC[ct]);
    }
    __syncthreads();
    #pragma unroll
    for (int ct = 0; ct < 4; ++ct) {
        int col = ct * 16 + ln;
        float bC = bc0[col];
        #pragma unroll
        for (int r = 0; r < 4; ++r) {
            int grow = m0 + quad * 4 + r;
            bool ok = grow < NN;
            float hv = ok ? h0f[(size_t)grow * 64 + col] : 0.f;
            float cv = tanhf(aC[ct][r] + bC);
            float hn = uu[ct][r] * hv + (1.f - uu[ct][r]) * cv;
            unsigned short hb = bf16rne(hn);
            if (ok) {
                h0nf[(size_t)grow * 64 + col] = hn;
                h0ns[(size_t)grow * 64 + col] = hb;
            }
            T[(quad * 4 + r) * 72 + col] = (short)hb;
        }
    }
    __syncthreads();

    short8 ah0 = *reinterpret_cast<const short8*>(T + ln * 72 + quad * 8);
    short8 ah1 = *reinterpret_cast<const short8*>(T + ln * 72 + 32 + quad * 8);
    floatx4 aY[4] = {z, z, z, z};
    #pragma unroll
    for (int ct = 0; ct < 4; ++ct) {
        const short* bg = Wg1T + (size_t)(ct * 16 + ln) * 64;
        aY[ct] = MFMA(ah0, *reinterpret_cast<const short8*>(bg + quad * 8), aY[ct]);
        aY[ct] = MFMA(ah1, *reinterpret_cast<const short8*>(bg + 32 + quad * 8), aY[ct]);
    }
    #pragma unroll
    for (int ct = 0; ct < 4; ++ct) {
        int col = ct * 16 + ln;
        #pragma unroll
        for (int r = 0; r < 4; ++r) {
            int grow = m0 + quad * 4 + r;
            if (grow < NN) y0s[(size_t)grow * 64 + col] = bf16rne(aY[ct][r]);
        }
    }
}

// fused cell1: u1,r1 (K=192) -> rh1 via LDS -> c1 (K=192) -> h1' (fp32 + bf16 shadow==hseq[t])
__launch_bounds__(256, 4)
__global__ void mfma_cell1(const unsigned short* __restrict__ h0s, const unsigned short* __restrict__ g1s,
                           const float* __restrict__ h1f, const unsigned short* __restrict__ h1s,
                           const short* __restrict__ Wu1T, const short* __restrict__ Wr1T,
                           const short* __restrict__ Wc1T,
                           const float* __restrict__ bu1, const float* __restrict__ br1,
                           const float* __restrict__ bc1,
                           float* __restrict__ h1nf, unsigned short* __restrict__ h1ns) {
    __shared__ short lds[4 * 16 * 72];
    int tid = threadIdx.x;
    int wv = tid >> 6, lane = tid & 63;
    int quad = lane >> 4, ln = lane & 15;
    int m0 = blockIdx.x * 64 + wv * 16;
    int arow = m0 + ln; if (arow > NN - 1) arow = NN - 1;
    short* T = lds + wv * (16 * 72);

    short8 af[6];
    af[0] = *reinterpret_cast<const short8*>(h0s + (size_t)arow * 64 + quad * 8);
    af[1] = *reinterpret_cast<const short8*>(h0s + (size_t)arow * 64 + 32 + quad * 8);
    af[2] = *reinterpret_cast<const short8*>(g1s + (size_t)arow * 64 + quad * 8);
    af[3] = *reinterpret_cast<const short8*>(g1s + (size_t)arow * 64 + 32 + quad * 8);
    af[4] = *reinterpret_cast<const short8*>(h1s + (size_t)arow * 64 + quad * 8);
    af[5] = *reinterpret_cast<const short8*>(h1s + (size_t)arow * 64 + 32 + quad * 8);

    floatx4 z = {0.f, 0.f, 0.f, 0.f};
    floatx4 aU[4] = {z, z, z, z};
    floatx4 aR[4] = {z, z, z, z};
    #pragma unroll
    for (int ct = 0; ct < 4; ++ct) {
        const short* bu = Wu1T + (size_t)(ct * 16 + ln) * 192;
        const short* br = Wr1T + (size_t)(ct * 16 + ln) * 192;
        #pragma unroll
        for (int kc = 0; kc < 6; ++kc) {
            int ko = kc * 32 + quad * 8;
            aU[ct] = MFMA(af[kc], *reinterpret_cast<const short8*>(bu + ko), aU[ct]);
            aR[ct] = MFMA(af[kc], *reinterpret_cast<const short8*>(br + ko), aR[ct]);
        }
    }
    float uu[4][4];
    #pragma unroll
    for (int ct = 0; ct < 4; ++ct) {
        int col = ct * 16 + ln;
        float bU = bu1[col], bR = br1[col];
        #pragma unroll
        for (int r = 0; r < 4; ++r) {
            int grow = m0 + quad * 4 + r;
            bool ok = grow < NN;
            uu[ct][r] = sigmoidf_(aU[ct][r] + bU);
            float hv = ok ? h1f[(size_t)grow * 64 + col] : 0.f;
            float rh = sigmoidf_(aR[ct][r] + bR) * hv;
            T[(quad * 4 + r) * 72 + col] = (short)bf16rne(rh);
        }
    }
    __syncthreads();

    short8 ar0 = *reinterpret_cast<const short8*>(T + ln * 72 + quad * 8);
    short8 ar1 = *reinterpret_cast<const short8*>(T + ln * 72 + 32 + quad * 8);
    floatx4 aC[4] = {z, z, z, z};
    #pragma unroll
    for (int ct = 0; ct < 4; ++ct) {
        const short* bc = Wc1T + (size_t)(ct * 16 + ln) * 192;
        #pragma unroll
        for (int kc = 0; kc < 4; ++kc)
            aC[ct] = MFMA(af[kc], *reinterpret_cast<const short8*>(bc + kc * 32 + quad * 8), aC[ct]);
        aC[ct] = MFMA(ar0, *reinterpret_cast<const short8*>(bc + 128 + quad * 8), aC[ct]);
        aC[ct] = MFMA(ar1, *reinterpret_cast<const short8*>(bc + 160 + quad * 8), aC[ct]);
    }
    #pragma unroll
    for (int ct = 0; ct < 4; ++ct) {
        int col = ct * 16 + ln;
        float bC = bc1[col];
        #pragma unroll
        for (int r = 0; r < 4; ++r) {
            int grow = m0 + quad * 4 + r;
            if (grow >= NN) continue;
            float hv = h1f[(size_t)grow * 64 + col];
            float cv = tanhf(aC[ct][r] + bC);
            float hn = uu[ct][r] * hv + (1.f - uu[ct][r]) * cv;
            h1nf[(size_t)grow * 64 + col] = hn;
            h1ns[(size_t)grow * 64 + col] = bf16rne(hn);
        }
    }
}

// ---------------- attention core: qkv bf16 node-major [n][t][192] ----------------
__global__ void attn_core(const unsigned short* __restrict__ qkvs,
                          const float* __restrict__ opw, const float* __restrict__ opb,
                          const float* __restrict__ ow, const float* __restrict__ ob,
                          float* __restrict__ out) {
    __shared__ float smem[4 * 2768];
    int w = threadIdx.x >> 6;
    int lane = threadIdx.x & 63;
    int node = blockIdx.x * 4 + w;
    float* shq = smem + w * 2768;
    float* sp  = shq + 2352;
    float* sob = shq + 2640;
    float* sha = shq + 2704;

    const unsigned* qn = (const unsigned*)(qkvs + (size_t)node * (TT * 192));
    for (int idx = lane; idx < TT * 96; idx += 64) {
        unsigned v = qn[idx];
        int t = idx / 96;
        int j = (idx - t * 96) * 2;
        shq[t * 196 + j] = lof(v);
        shq[t * 196 + j + 1] = hif(v);
    }
    __syncthreads();

    if (lane < 24) {
        int hd = lane / 12, tq = lane % 12;
        const float* qrow = shq + tq * 196 + hd * 32;
        float sc[12];
        float mx = -1e30f;
        #pragma unroll
        for (int s = 0; s < 12; ++s) {
            const float* krow = shq + s * 196 + 64 + hd * 32;
            float a = 0.f;
            #pragma unroll
            for (int d = 0; d < 32; ++d) a += qrow[d] * krow[d];
            a *= 0.17677669529663687f;
            sc[s] = a; mx = fmaxf(mx, a);
        }
        float sum = 0.f;
        #pragma unroll
        for (int s = 0; s < 12; ++s) { sc[s] = expf(sc[s] - mx); sum += sc[s]; }
        float inv = 1.f / sum;
        #pragma unroll
        for (int s = 0; s < 12; ++s) sp[(hd * 12 + tq) * 12 + s] = sc[s] * inv;
    }
    __syncthreads();

    {
        int d = lane, hd = d >> 5;
        float acc = 0.f;
        #pragma unroll
        for (int s = 0; s < 12; ++s) {
            float ts = 0.f;
            #pragma unroll
            for (int t = 0; t < 12; ++t) ts += sp[(hd * 12 + t) * 12 + s];
            acc += ts * shq[s * 196 + 128 + d];
        }
        sob[d] = acc * (1.f / 12.f);
    }
    __syncthreads();

    {
        int d = lane;
        float acc = opb[d];
        const float* wrow = opw + d * 64;
        #pragma unroll
        for (int k = 0; k < 64; ++k) acc += sob[k] * wrow[k];
        sha[d] = acc;
    }
    __syncthreads();

    if (lane < OUTD) {
        float acc = ob[lane];
        #pragma unroll
        for (int k = 0; k < 64; ++k) acc += sha[k] * ow[k * OUTD + lane];
        out[(size_t)node * OUTD + lane] = acc;
    }
}

// ---------------- launcher ----------------

extern "C" void kernel_launch(void* const* d_in, const int* in_sizes, int n_in,
                              void* d_out, int out_size, void* d_ws, size_t ws_size,
                              hipStream_t stream) {
    const float* x   = (const float*)d_in[0];
    const int*   ei  = (const int*)d_in[1];
    const float* ea  = (const float*)d_in[2];
    const float* Wg0 = (const float*)d_in[3];
    const float* bg0 = (const float*)d_in[4];
    const float* Wu0 = (const float*)d_in[5];
    const float* bu0 = (const float*)d_in[6];
    const float* Wr0 = (const float*)d_in[7];
    const float* br0 = (const float*)d_in[8];
    const float* Wc0 = (const float*)d_in[9];
    const float* bc0 = (const float*)d_in[10];
    const float* Wg1 = (const float*)d_in[11];
    const float* bg1 = (const float*)d_in[12];
    const float* Wu1 = (const float*)d_in[13];
    const float* bu1 = (const float*)d_in[14];
    const float* Wr1 = (const float*)d_in[15];
    const float* br1 = (const float*)d_in[16];
    const float* Wc1 = (const float*)d_in[17];
    const float* bc1 = (const float*)d_in[18];
    const float* ipw = (const float*)d_in[19];
    const float* ipb = (const float*)d_in[20];
    const float* opw = (const float*)d_in[21];
    const float* opb = (const float*)d_in[22];
    const float* ow  = (const float*)d_in[23];
    const float* ob  = (const float*)d_in[24];
    float* out = (float*)d_out;

    char* p = (char*)d_ws;
    auto alloc = [&](size_t bytes) { char* r = p; p += (bytes + 255) & ~(size_t)255; return (void*)r; };
    // persistent
    unsigned short* hseqs = (unsigned short*)alloc((size_t)TT * NN * HH * 2);
    unsigned short* h1s0  = (unsigned short*)alloc((size_t)NN * HH * 2);   // zero h1 shadow for t=0
    short* Wg0T = (short*)alloc((size_t)64 * 32 * 2);
    short* Wu0T = (short*)alloc((size_t)64 * 160 * 2);
    short* Wr0T = (short*)alloc((size_t)64 * 160 * 2);
    short* Wc0T = (short*)alloc((size_t)64 * 160 * 2);
    short* Wg1T = (short*)alloc((size_t)64 * 64 * 2);
    short* Wu1T = (short*)alloc((size_t)64 * 192 * 2);
    short* Wr1T = (short*)alloc((size_t)64 * 192 * 2);
    short* Wc1T = (short*)alloc((size_t)64 * 192 * 2);
    short* ipwB = (short*)alloc((size_t)192 * 64 * 2);
    float* dinv   = (float*)alloc((size_t)NN * 4);
    int*   rowptr = (int*)  alloc((size_t)(NN + 1) * 4);
    int*   colIdx = (int*)  alloc((size_t)EE * 4);
    float* valArr = (float*)alloc((size_t)EE * 4);
    // union: loop-phase buffers vs qkv (bf16, node-major)
    char* ubase = p;
    unsigned short* xTs   = (unsigned short*)alloc((size_t)TT * NN * FF * 2);
    unsigned short* aggxs = (unsigned short*)alloc((size_t)TT * NN * FF * 2);
    unsigned short* g0s   = (unsigned short*)alloc((size_t)TT * NN * HH * 2);
    float* deg    = (float*)alloc((size_t)NN * 4);
    int*   cnt    = (int*)  alloc((size_t)NN * 4);
    int*   cursor = (int*)  alloc((size_t)NN * 4);
    unsigned short* y0s = (unsigned short*)alloc((size_t)NN * HH * 2);
    unsigned short* g1s = (unsigned short*)alloc((size_t)NN * HH * 2);
    float* h0fa = (float*)alloc((size_t)NN * HH * 4);
    float* h0fb = (float*)alloc((size_t)NN * HH * 4);
    float* h1fa = (float*)alloc((size_t)NN * HH * 4);
    float* h1fb = (float*)alloc((size_t)NN * HH * 4);
    unsigned short* h0sa = (unsigned short*)alloc((size_t)NN * HH * 2);
    unsigned short* h0sb = (unsigned short*)alloc((size_t)NN * HH * 2);
    size_t qkv_bytes = (size_t)TT * NN * 192 * 2;
    unsigned short* qkvs = (unsigned short*)ubase;
    char* endA = p;
    char* endB = ubase + ((qkv_bytes + 255) & ~(size_t)255);
    p = (endA > endB) ? endA : endB;
    (void)ws_size;

    hipMemsetAsync(cnt, 0, (size_t)NN * 4, stream);
    hipMemsetAsync(h0fa, 0, (size_t)NN * HH * 4, stream);
    hipMemsetAsync(h1fa, 0, (size_t)NN * HH * 4, stream);
    hipMemsetAsync(h0sa, 0, (size_t)NN * HH * 2, stream);
    hipMemsetAsync(h1s0, 0, (size_t)NN * HH * 2, stream);
    deg_init_kernel<<<(NN + 255) / 256, 256, 0, stream>>>(deg);
    edge_accum_kernel<<<(EE + 255) / 256, 256, 0, stream>>>(ei, ea, deg, cnt);
    dinv_kernel<<<(NN + 255) / 256, 256, 0, stream>>>(deg, dinv);
    scan_kernel<<<1, 1024, 0, stream>>>(cnt, rowptr, cursor);
    fill_kernel<<<(EE + 255) / 256, 256, 0, stream>>>(ei, ea, dinv, cursor, colIdx, valArr);
    transpose_kernel<<<(TT * NN * FF + 255) / 256, 256, 0, stream>>>(x, xTs);
    wconv_all<<<(86016 + 255) / 256, 256, 0, stream>>>(
        Wg0, Wu0, Wr0, Wc0, Wg1, Wu1, Wr1, Wc1, ipw,
        Wg0T, Wu0T, Wr0T, Wc0T, Wg1T, Wu1T, Wr1T, Wc1T, ipwB);

    gather_raw32<<<dim3(NN / 16, TT), 256, 0, stream>>>(xTs, dinv, rowptr, colIdx, valArr, aggxs);
    mfma_g0<<<(TT * NN) / 64, 256, 0, stream>>>(aggxs, Wg0T, bg0, g0s);

    const int CB = (NN + 63) / 64;   // 313
    for (int t = 0; t < TT; ++t) {
        const unsigned short* xt = xTs + (size_t)t * NN * FF;
        const unsigned short* g0 = g0s + (size_t)t * NN * HH;
        float* h0f_in  = (t & 1) ? h0fb : h0fa;
        float* h0f_out = (t & 1) ? h0fa : h0fb;
        unsigned short* h0s_in  = (t & 1) ? h0sb : h0sa;
        unsigned short* h0s_out = (t & 1) ? h0sa : h0sb;
        float* h1f_in  = (t & 1) ? h1fb : h1fa;
        float* h1f_out = (t & 1) ? h1fa : h1fb;
        const unsigned short* h1s_in = (t == 0) ? h1s0 : (hseqs + (size_t)(t - 1) * NN * HH);
        unsigned short* h1s_out = hseqs + (size_t)t * NN * HH;

        mfma_cell0<<<CB, 256, 0, stream>>>(
            xt, g0, h0f_in, h0s_in, Wu0T, Wr0T, Wc0T, Wg1T, bu0, br0, bc0,
            h0f_out, h0s_out, y0s);
        gather_g1<<<NN / 8, 256, 0, stream>>>(y0s, dinv, rowptr, colIdx, valArr, bg1, g1s);
        mfma_cell1<<<CB, 256, 0, stream>>>(
            h0s_out, g1s, h1f_in, h1s_in, Wu1T, Wr1T, Wc1T, bu1, br1, bc1,
            h1f_out, h1s_out);
    }

    mfma_qkv<<<(TT * NN) / 64, 256, 0, stream>>>(hseqs, ipwB, ipb, qkvs);
    attn_core<<<NN / 4, 256, 0, stream>>>(qkvs, opw, opb, ow, ob, out);
}

// Round 8
// 1019.732 us; speedup vs baseline: 22.2800x; 1.2161x over previous
//
#include <hip/hip_runtime.h>
#include <math.h>

#define NN 20000
#define FF 32
#define TT 12
#define HH 64
#define EE 320000
#define OUTD 12
#define CB 313   // ceil(NN/64)

typedef __attribute__((ext_vector_type(8))) short short8;
typedef __attribute__((ext_vector_type(4))) float floatx4;

__device__ __forceinline__ float sigmoidf_(float x) { return 1.f / (1.f + expf(-x)); }

__device__ __forceinline__ unsigned short bf16rne(float f) {
    union { float f; unsigned u; } v; v.f = f;
    unsigned u = v.u;
    u += 0x7fffu + ((u >> 16) & 1u);
    return (unsigned short)(u >> 16);
}
__device__ __forceinline__ float lof(unsigned v) {
    union { unsigned u; float f; } x; x.u = v << 16; return x.f;
}
__device__ __forceinline__ float hif(unsigned v) {
    union { unsigned u; float f; } x; x.u = v & 0xffff0000u; return x.f;
}
__device__ __forceinline__ unsigned packbf(float a, float b) {
    return (unsigned)bf16rne(a) | ((unsigned)bf16rne(b) << 16);
}

#define MFMA(a, b, c) __builtin_amdgcn_mfma_f32_16x16x32_bf16((a), (b), (c), 0, 0, 0)

// ---------------- preprocessing ----------------

__global__ void deg_init_kernel(float* deg) {
    int i = blockIdx.x * 256 + threadIdx.x;
    if (i < NN) deg[i] = 1.0f;
}

__global__ void edge_accum_kernel(const int* ei, const float* ea, float* deg, int* cnt) {
    int e = blockIdx.x * 256 + threadIdx.x;
    if (e >= EE) return;
    int d = ei[EE + e];
    float w = ea[e * 2 + 1];
    atomicAdd(&deg[d], w);
    atomicAdd(&cnt[d], 1);
}

__global__ void dinv_kernel(const float* deg, float* dinv) {
    int i = blockIdx.x * 256 + threadIdx.x;
    if (i < NN) dinv[i] = rsqrtf(deg[i]);
}

__global__ void scan_kernel(const int* cnt, int* rowptr, int* cursor) {
    __shared__ int wsum[16];
    int tid = threadIdx.x;
    int lane = tid & 63, w = tid >> 6;
    int run = 0;
    for (int base = 0; base < NN; base += 1024) {
        int idx = base + tid;
        int c = (idx < NN) ? cnt[idx] : 0;
        int v = c;
        #pragma unroll
        for (int off = 1; off < 64; off <<= 1) {
            int t = __shfl_up(v, off, 64);
            if (lane >= off) v += t;
        }
        if (lane == 63) wsum[w] = v;
        __syncthreads();
        if (tid < 16) {
            int x = wsum[tid];
            #pragma unroll
            for (int off = 1; off < 16; off <<= 1) {
                int t = __shfl_up(x, off, 64);
                if (tid >= off) x += t;
            }
            wsum[tid] = x;
        }
        __syncthreads();
        int waveoff = (w > 0) ? wsum[w - 1] : 0;
        int excl = run + waveoff + (v - c);
        if (idx < NN) { rowptr[idx] = excl; cursor[idx] = excl; }
        run += wsum[15];
        __syncthreads();
    }
    if (tid == 0) rowptr[NN] = run;
}

__global__ void fill_kernel(const int* ei, const float* ea, const float* dinv,
                            int* cursor, int* colIdx, float* valArr) {
    int e = blockIdx.x * 256 + threadIdx.x;
    if (e >= EE) return;
    int s = ei[e], d = ei[EE + e];
    float w = ea[e * 2 + 1];
    int pos = atomicAdd(&cursor[d], 1);
    colIdx[pos] = s;
    valArr[pos] = dinv[s] * w * dinv[d];
}

// x (N,F,T) fp32 -> xTs (T,N,F) bf16
__global__ void transpose_kernel(const float* x, unsigned short* xTs) {
    int i = blockIdx.x * 256 + threadIdx.x;
    if (i >= TT * NN * FF) return;
    int f = i & 31;
    int rest = i >> 5;
    int n = rest % NN;
    int t = rest / NN;
    xTs[i] = bf16rne(x[n * (FF * TT) + f * TT + t]);
}

// all 9 weight conversions in one launch; *T variants transpose (K,64)->[64][K]
__global__ void wconv_all(const float* Wg0, const float* Wu0, const float* Wr0, const float* Wc0,
                          const float* Wg1, const float* Wu1, const float* Wr1, const float* Wc1,
                          const float* ipw,
                          short* Wg0T, short* Wu0T, short* Wr0T, short* Wc0T,
                          short* Wg1T, short* Wu1T, short* Wr1T, short* Wc1T, short* ipwB) {
    int i = blockIdx.x * 256 + threadIdx.x;
    if (i < 2048) { int n = i / 32, k = i % 32; Wg0T[i] = (short)bf16rne(Wg0[k * 64 + n]); return; }
    i -= 2048;
    if (i < 10240) { int n = i / 160, k = i % 160; Wu0T[i] = (short)bf16rne(Wu0[k * 64 + n]); return; }
    i -= 10240;
    if (i < 10240) { int n = i / 160, k = i % 160; Wr0T[i] = (short)bf16rne(Wr0[k * 64 + n]); return; }
    i -= 10240;
    if (i < 10240) { int n = i / 160, k = i % 160; Wc0T[i] = (short)bf16rne(Wc0[k * 64 + n]); return; }
    i -= 10240;
    if (i < 4096) { int n = i / 64, k = i % 64; Wg1T[i] = (short)bf16rne(Wg1[k * 64 + n]); return; }
    i -= 4096;
    if (i < 12288) { int n = i / 192, k = i % 192; Wu1T[i] = (short)bf16rne(Wu1[k * 64 + n]); return; }
    i -= 12288;
    if (i < 12288) { int n = i / 192, k = i % 192; Wr1T[i] = (short)bf16rne(Wr1[k * 64 + n]); return; }
    i -= 12288;
    if (i < 12288) { int n = i / 192, k = i % 192; Wc1T[i] = (short)bf16rne(Wc1[k * 64 + n]); return; }
    i -= 12288;
    if (i < 12288) { ipwB[i] = (short)bf16rne(ipw[i]); }
}

// bf16 aggregation over x planes: 16 lanes/node, 2 features per lane
__global__ void gather_raw32(const unsigned short* __restrict__ xTs, const float* __restrict__ dinv,
                             const int* __restrict__ rowptr, const int* __restrict__ colIdx,
                             const float* __restrict__ valArr, unsigned short* __restrict__ aggxs) {
    const unsigned* src = (const unsigned*)(xTs + (size_t)blockIdx.y * NN * 32);
    unsigned* dst = (unsigned*)(aggxs + (size_t)blockIdx.y * NN * 32);
    int node = blockIdx.x * 16 + (threadIdx.x >> 4);
    int l2 = threadIdx.x & 15;
    float di = dinv[node];
    float dd = di * di;
    unsigned v = src[node * 16 + l2];
    float a0 = dd * lof(v), a1 = dd * hif(v);
    int s = rowptr[node], e = rowptr[node + 1];
    int j = s;
    for (; j + 3 < e; j += 4) {
        int c0 = colIdx[j], c1 = colIdx[j + 1], c2 = colIdx[j + 2], c3 = colIdx[j + 3];
        float w0 = valArr[j], w1 = valArr[j + 1], w2 = valArr[j + 2], w3 = valArr[j + 3];
        unsigned v0 = src[c0 * 16 + l2], v1 = src[c1 * 16 + l2];
        unsigned v2 = src[c2 * 16 + l2], v3 = src[c3 * 16 + l2];
        a0 += w0 * lof(v0) + w1 * lof(v1) + w2 * lof(v2) + w3 * lof(v3);
        a1 += w0 * hif(v0) + w1 * hif(v1) + w2 * hif(v2) + w3 * hif(v3);
    }
    for (; j < e; ++j) {
        unsigned vv = src[colIdx[j] * 16 + l2];
        float w = valArr[j];
        a0 += w * lof(vv); a1 += w * hif(vv);
    }
    dst[node * 16 + l2] = packbf(a0, a1);
}

// gather y0 (bf16) + sigmoid -> g1 (bf16): 32 lanes/node
__global__ void gather_g1(const unsigned short* __restrict__ y0s, const float* __restrict__ dinv,
                          const int* __restrict__ rowptr, const int* __restrict__ colIdx,
                          const float* __restrict__ valArr, const float* __restrict__ bg1,
                          unsigned short* __restrict__ g1s) {
    const unsigned* yp = (const unsigned*)y0s;
    int node = blockIdx.x * 8 + (threadIdx.x >> 5);
    int l2 = threadIdx.x & 31;
    float di = dinv[node];
    float dd = di * di;
    unsigned v = yp[node * 32 + l2];
    float a0 = dd * lof(v), a1 = dd * hif(v);
    int s = rowptr[node], e = rowptr[node + 1];
    int j = s;
    for (; j + 3 < e; j += 4) {
        int c0 = colIdx[j], c1 = colIdx[j + 1], c2 = colIdx[j + 2], c3 = colIdx[j + 3];
        float w0 = valArr[j], w1 = valArr[j + 1], w2 = valArr[j + 2], w3 = valArr[j + 3];
        unsigned v0 = yp[c0 * 32 + l2], v1 = yp[c1 * 32 + l2];
        unsigned v2 = yp[c2 * 32 + l2], v3 = yp[c3 * 32 + l2];
        a0 += w0 * lof(v0) + w1 * lof(v1) + w2 * lof(v2) + w3 * lof(v3);
        a1 += w0 * hif(v0) + w1 * hif(v1) + w2 * hif(v2) + w3 * hif(v3);
    }
    for (; j < e; ++j) {
        unsigned vv = yp[colIdx[j] * 32 + l2];
        float w = valArr[j];
        a0 += w * lof(vv); a1 += w * hif(vv);
    }
    float g0v = sigmoidf_(a0 + bg1[2 * l2]);
    float g1v = sigmoidf_(a1 + bg1[2 * l2 + 1]);
    ((unsigned*)g1s)[node * 32 + l2] = packbf(g0v, g1v);
}

// ---------------- MFMA kernels ----------------
// A[m=lane&15][k=quad*8+j]; B^T[n=lane&15][k=quad*8+j]; C/D: col=lane&15, row=quad*4+reg.

// g0all = sigmoid(aggx @ Wg0 + bg0) -> bf16, rows = T*N, K=32
__launch_bounds__(256, 4)
__global__ void mfma_g0(const unsigned short* __restrict__ aggxs, const short* __restrict__ Wg0T,
                        const float* __restrict__ bg0, unsigned short* __restrict__ g0s) {
    int tid = threadIdx.x;
    int wv = tid >> 6, lane = tid & 63;
    int quad = lane >> 4, ln = lane & 15;
    int m0 = blockIdx.x * 64 + wv * 16;
    short8 af = *reinterpret_cast<const short8*>(aggxs + (size_t)(m0 + ln) * 32 + quad * 8);
    floatx4 z = {0.f, 0.f, 0.f, 0.f};
    floatx4 acc[4] = {z, z, z, z};
    #pragma unroll
    for (int ct = 0; ct < 4; ++ct) {
        short8 bf = *reinterpret_cast<const short8*>(Wg0T + (size_t)(ct * 16 + ln) * 32 + quad * 8);
        acc[ct] = MFMA(af, bf, acc[ct]);
    }
    #pragma unroll
    for (int ct = 0; ct < 4; ++ct) {
        int col = ct * 16 + ln;
        float bb = bg0[col];
        #pragma unroll
        for (int r = 0; r < 4; ++r) {
            int row = m0 + quad * 4 + r;
            g0s[(size_t)row * 64 + col] = bf16rne(sigmoidf_(acc[ct][r] + bb));
        }
    }
}

// qkv = hseq @ ipw.T + ipb -> bf16 node-major padded [n][16][192]
__launch_bounds__(256, 2)
__global__ void mfma_qkv(const unsigned short* __restrict__ hseqs, const short* __restrict__ ipwB,
                         const float* __restrict__ ipb, unsigned short* __restrict__ qkvs) {
    int tid = threadIdx.x;
    int wv = tid >> 6, lane = tid & 63;
    int quad = lane >> 4, ln = lane & 15;
    int m0 = blockIdx.x * 64 + wv * 16;
    short8 af0 = *reinterpret_cast<const short8*>(hseqs + (size_t)(m0 + ln) * 64 + quad * 8);
    short8 af1 = *reinterpret_cast<const short8*>(hseqs + (size_t)(m0 + ln) * 64 + 32 + quad * 8);
    floatx4 z = {0.f, 0.f, 0.f, 0.f};
    floatx4 acc[12];
    #pragma unroll
    for (int ct = 0; ct < 12; ++ct) acc[ct] = z;
    #pragma unroll
    for (int ct = 0; ct < 12; ++ct) {
        const short* br = ipwB + (size_t)(ct * 16 + ln) * 64;
        acc[ct] = MFMA(af0, *reinterpret_cast<const short8*>(br + quad * 8), acc[ct]);
        acc[ct] = MFMA(af1, *reinterpret_cast<const short8*>(br + 32 + quad * 8), acc[ct]);
    }
    #pragma unroll
    for (int ct = 0; ct < 12; ++ct) {
        int col = ct * 16 + ln;
        float bb = ipb[col];
        #pragma unroll
        for (int r = 0; r < 4; ++r) {
            int row = m0 + quad * 4 + r;   // = t*NN + n
            int t = row / NN;
            int n = row - t * NN;
            qkvs[((size_t)n * 16 + t) * 192 + col] = bf16rne(acc[ct][r] + bb);
        }
    }
}

// ---- cell bodies (per-wave 64-row... 16-row tile each, m0 includes wave offset) ----

__device__ __forceinline__ void cell0_body(
    int m0, short* T,
    const unsigned short* __restrict__ xt, const unsigned short* __restrict__ g0,
    const float* __restrict__ h0f, const unsigned short* __restrict__ h0s,
    const short* __restrict__ Wu0T, const short* __restrict__ Wr0T,
    const short* __restrict__ Wc0T, const short* __restrict__ Wg1T,
    const float* __restrict__ bu0, const float* __restrict__ br0,
    const float* __restrict__ bc0,
    float* __restrict__ h0nf, unsigned short* __restrict__ h0ns,
    unsigned short* __restrict__ y0s) {
    int lane = threadIdx.x & 63;
    int quad = lane >> 4, ln = lane & 15;
    int arow = m0 + ln; if (arow > NN - 1) arow = NN - 1;

    short8 af[5];
    af[0] = *reinterpret_cast<const short8*>(xt + (size_t)arow * 32 + quad * 8);
    af[1] = *reinterpret_cast<const short8*>(g0 + (size_t)arow * 64 + quad * 8);
    af[2] = *reinterpret_cast<const short8*>(g0 + (size_t)arow * 64 + 32 + quad * 8);
    af[3] = *reinterpret_cast<const short8*>(h0s + (size_t)arow * 64 + quad * 8);
    af[4] = *reinterpret_cast<const short8*>(h0s + (size_t)arow * 64 + 32 + quad * 8);

    floatx4 z = {0.f, 0.f, 0.f, 0.f};
    floatx4 aU[4] = {z, z, z, z};
    floatx4 aR[4] = {z, z, z, z};
    #pragma unroll
    for (int ct = 0; ct < 4; ++ct) {
        const short* bu = Wu0T + (size_t)(ct * 16 + ln) * 160;
        const short* br = Wr0T + (size_t)(ct * 16 + ln) * 160;
        #pragma unroll
        for (int kc = 0; kc < 5; ++kc) {
            int ko = kc * 32 + quad * 8;
            aU[ct] = MFMA(af[kc], *reinterpret_cast<const short8*>(bu + ko), aU[ct]);
            aR[ct] = MFMA(af[kc], *reinterpret_cast<const short8*>(br + ko), aR[ct]);
        }
    }
    float uu[4][4];
    #pragma unroll
    for (int ct = 0; ct < 4; ++ct) {
        int col = ct * 16 + ln;
        float bU = bu0[col], bR = br0[col];
        #pragma unroll
        for (int r = 0; r < 4; ++r) {
            int grow = m0 + quad * 4 + r;
            bool ok = grow < NN;
            uu[ct][r] = sigmoidf_(aU[ct][r] + bU);
            float hv = ok ? h0f[(size_t)grow * 64 + col] : 0.f;
            float rh = sigmoidf_(aR[ct][r] + bR) * hv;
            T[(quad * 4 + r) * 72 + col] = (short)bf16rne(rh);
        }
    }
    __syncthreads();

    short8 ar0 = *reinterpret_cast<const short8*>(T + ln * 72 + quad * 8);
    short8 ar1 = *reinterpret_cast<const short8*>(T + ln * 72 + 32 + quad * 8);
    floatx4 aC[4] = {z, z, z, z};
    #pragma unroll
    for (int ct = 0; ct < 4; ++ct) {
        const short* bc = Wc0T + (size_t)(ct * 16 + ln) * 160;
        #pragma unroll
        for (int kc = 0; kc < 3; ++kc)
            aC[ct] = MFMA(af[kc], *reinterpret_cast<const short8*>(bc + kc * 32 + quad * 8), aC[ct]);
        aC[ct] = MFMA(ar0, *reinterpret_cast<const short8*>(bc + 96 + quad * 8), aC[ct]);
        aC[ct] = MFMA(ar1, *reinterpret_cast<const short8*>(bc + 128 + quad * 8), aC[ct]);
    }
    __syncthreads();
    #pragma unroll
    for (int ct = 0; ct < 4; ++ct) {
        int col = ct * 16 + ln;
        float bC = bc0[col];
        #pragma unroll
        for (int r = 0; r < 4; ++r) {
            int grow = m0 + quad * 4 + r;
            bool ok = grow < NN;
            float hv = ok ? h0f[(size_t)grow * 64 + col] : 0.f;
            float cv = tanhf(aC[ct][r] + bC);
            float hn = uu[ct][r] * hv + (1.f - uu[ct][r]) * cv;
            unsigned short hb = bf16rne(hn);
            if (ok) {
                h0nf[(size_t)grow * 64 + col] = hn;
                h0ns[(size_t)grow * 64 + col] = hb;
            }
            T[(quad * 4 + r) * 72 + col] = (short)hb;
        }
    }
    __syncthreads();

    short8 ah0 = *reinterpret_cast<const short8*>(T + ln * 72 + quad * 8);
    short8 ah1 = *reinterpret_cast<const short8*>(T + ln * 72 + 32 + quad * 8);
    floatx4 aY[4] = {z, z, z, z};
    #pragma unroll
    for (int ct = 0; ct < 4; ++ct) {
        const short* bg = Wg1T + (size_t)(ct * 16 + ln) * 64;
        aY[ct] = MFMA(ah0, *reinterpret_cast<const short8*>(bg + quad * 8), aY[ct]);
        aY[ct] = MFMA(ah1, *reinterpret_cast<const short8*>(bg + 32 + quad * 8), aY[ct]);
    }
    #pragma unroll
    for (int ct = 0; ct < 4; ++ct) {
        int col = ct * 16 + ln;
        #pragma unroll
        for (int r = 0; r < 4; ++r) {
            int grow = m0 + quad * 4 + r;
            if (grow < NN) y0s[(size_t)grow * 64 + col] = bf16rne(aY[ct][r]);
        }
    }
}

__device__ __forceinline__ void cell1_body(
    int m0, short* T,
    const unsigned short* __restrict__ h0s, const unsigned short* __restrict__ g1s,
    const float* __restrict__ h1f, const unsigned short* __restrict__ h1s,
    const short* __restrict__ Wu1T, const short* __restrict__ Wr1T,
    const short* __restrict__ Wc1T,
    const float* __restrict__ bu1, const float* __restrict__ br1,
    const float* __restrict__ bc1,
    float* __restrict__ h1nf, unsigned short* __restrict__ h1ns) {
    int lane = threadIdx.x & 63;
    int quad = lane >> 4, ln = lane & 15;
    int arow = m0 + ln; if (arow > NN - 1) arow = NN - 1;

    short8 af[6];
    af[0] = *reinterpret_cast<const short8*>(h0s + (size_t)arow * 64 + quad * 8);
    af[1] = *reinterpret_cast<const short8*>(h0s + (size_t)arow * 64 + 32 + quad * 8);
    af[2] = *reinterpret_cast<const short8*>(g1s + (size_t)arow * 64 + quad * 8);
    af[3] = *reinterpret_cast<const short8*>(g1s + (size_t)arow * 64 + 32 + quad * 8);
    af[4] = *reinterpret_cast<const short8*>(h1s + (size_t)arow * 64 + quad * 8);
    af[5] = *reinterpret_cast<const short8*>(h1s + (size_t)arow * 64 + 32 + quad * 8);

    floatx4 z = {0.f, 0.f, 0.f, 0.f};
    floatx4 aU[4] = {z, z, z, z};
    floatx4 aR[4] = {z, z, z, z};
    #pragma unroll
    for (int ct = 0; ct < 4; ++ct) {
        const short* bu = Wu1T + (size_t)(ct * 16 + ln) * 192;
        const short* br = Wr1T + (size_t)(ct * 16 + ln) * 192;
        #pragma unroll
        for (int kc = 0; kc < 6; ++kc) {
            int ko = kc * 32 + quad * 8;
            aU[ct] = MFMA(af[kc], *reinterpret_cast<const short8*>(bu + ko), aU[ct]);
            aR[ct] = MFMA(af[kc], *reinterpret_cast<const short8*>(br + ko), aR[ct]);
        }
    }
    float uu[4][4];
    #pragma unroll
    for (int ct = 0; ct < 4; ++ct) {
        int col = ct * 16 + ln;
        float bU = bu1[col], bR = br1[col];
        #pragma unroll
        for (int r = 0; r < 4; ++r) {
            int grow = m0 + quad * 4 + r;
            bool ok = grow < NN;
            uu[ct][r] = sigmoidf_(aU[ct][r] + bU);
            float hv = ok ? h1f[(size_t)grow * 64 + col] : 0.f;
            float rh = sigmoidf_(aR[ct][r] + bR) * hv;
            T[(quad * 4 + r) * 72 + col] = (short)bf16rne(rh);
        }
    }
    __syncthreads();

    short8 ar0 = *reinterpret_cast<const short8*>(T + ln * 72 + quad * 8);
    short8 ar1 = *reinterpret_cast<const short8*>(T + ln * 72 + 32 + quad * 8);
    floatx4 aC[4] = {z, z, z, z};
    #pragma unroll
    for (int ct = 0; ct < 4; ++ct) {
        const short* bc = Wc1T + (size_t)(ct * 16 + ln) * 192;
        #pragma unroll
        for (int kc = 0; kc < 4; ++kc)
            aC[ct] = MFMA(af[kc], *reinterpret_cast<const short8*>(bc + kc * 32 + quad * 8), aC[ct]);
        aC[ct] = MFMA(ar0, *reinterpret_cast<const short8*>(bc + 128 + quad * 8), aC[ct]);
        aC[ct] = MFMA(ar1, *reinterpret_cast<const short8*>(bc + 160 + quad * 8), aC[ct]);
    }
    #pragma unroll
    for (int ct = 0; ct < 4; ++ct) {
        int col = ct * 16 + ln;
        float bC = bc1[col];
        #pragma unroll
        for (int r = 0; r < 4; ++r) {
            int grow = m0 + quad * 4 + r;
            if (grow >= NN) continue;
            float hv = h1f[(size_t)grow * 64 + col];
            float cv = tanhf(aC[ct][r] + bC);
            float hn = uu[ct][r] * hv + (1.f - uu[ct][r]) * cv;
            h1nf[(size_t)grow * 64 + col] = hn;
            h1ns[(size_t)grow * 64 + col] = bf16rne(hn);
        }
    }
}

// standalone cell0 (t=0 bootstrap)
__launch_bounds__(256, 4)
__global__ void mfma_cell0(const unsigned short* xt, const unsigned short* g0,
                           const float* h0f, const unsigned short* h0s,
                           const short* Wu0T, const short* Wr0T, const short* Wc0T, const short* Wg1T,
                           const float* bu0, const float* br0, const float* bc0,
                           float* h0nf, unsigned short* h0ns, unsigned short* y0s) {
    __shared__ short lds[4 * 16 * 72];
    int wv = threadIdx.x >> 6;
    cell0_body(blockIdx.x * 64 + wv * 16, lds + wv * (16 * 72),
               xt, g0, h0f, h0s, Wu0T, Wr0T, Wc0T, Wg1T, bu0, br0, bc0, h0nf, h0ns, y0s);
}

// merged step: blocks [0,CB) = cell1 for t; blocks [CB,2CB) = cell0 for t+1 (independent)
__launch_bounds__(256, 4)
__global__ void mfma_step(
    const unsigned short* h0s_cur, const unsigned short* g1s,
    const float* h1f_in, const unsigned short* h1s_in,
    const short* Wu1T, const short* Wr1T, const short* Wc1T,
    const float* bu1, const float* br1, const float* bc1,
    float* h1f_out, unsigned short* h1s_out,
    const unsigned short* xt_next, const unsigned short* g0_next, const float* h0f_cur,
    const short* Wu0T, const short* Wr0T, const short* Wc0T, const short* Wg1T,
    const float* bu0, const float* br0, const float* bc0,
    float* h0f_next, unsigned short* h0s_next, unsigned short* y0s) {
    __shared__ short lds[4 * 16 * 72];
    int wv = threadIdx.x >> 6;
    short* T = lds + wv * (16 * 72);
    if (blockIdx.x < CB) {
        cell1_body(blockIdx.x * 64 + wv * 16, T, h0s_cur, g1s, h1f_in, h1s_in,
                   Wu1T, Wr1T, Wc1T, bu1, br1, bc1, h1f_out, h1s_out);
    } else {
        cell0_body((blockIdx.x - CB) * 64 + wv * 16, T, xt_next, g0_next, h0f_cur, h0s_cur,
                   Wu0T, Wr0T, Wc0T, Wg1T, bu0, br0, bc0, h0f_next, h0s_next, y0s);
    }
}

// ---------------- attention: MFMA scores + shuffle softmax, one wave per node ----------------
// qkvs: bf16 node-major padded [n][16][192]; t=12..15 garbage, masked.
__launch_bounds__(256, 8)
__global__ void attn_core(const unsigned short* __restrict__ qkvs,
                          const float* __restrict__ opw, const float* __restrict__ opb,
                          const float* __restrict__ ow, const float* __restrict__ ob,
                          float* __restrict__ out) {
    __shared__ float smem[4 * 176];
    int wv = threadIdx.x >> 6, lane = threadIdx.x & 63;
    int node = blockIdx.x * 4 + wv;
    int quad = lane >> 4, ln = lane & 15;
    float* W   = smem + wv * 176;   // [2][16] head-major weights w[ts]
    float* sob = W + 32;            // obar[64]
    float* sha = W + 96;            // h_attn[64]
    const unsigned short* base = qkvs + (size_t)node * (16 * 192);

    floatx4 z = {0.f, 0.f, 0.f, 0.f};
    floatx4 sc[2];
    #pragma unroll
    for (int h = 0; h < 2; ++h) {
        short8 aQ = *reinterpret_cast<const short8*>(base + ln * 192 + h * 32 + quad * 8);
        short8 bK = *reinterpret_cast<const short8*>(base + ln * 192 + 64 + h * 32 + quad * 8);
        sc[h] = MFMA(aQ, bK, z);   // rows=tq(quad*4+r), cols=ts(ln)
    }
    const float scl = 0.17677669529663687f;   // 1/sqrt(32)
    bool colok = ln < 12;
    #pragma unroll
    for (int h = 0; h < 2; ++h) {
        float p[4];
        #pragma unroll
        for (int r = 0; r < 4; ++r) {
            float v = colok ? sc[h][r] * scl : -1e30f;
            float m = v;
            m = fmaxf(m, __shfl_xor(m, 1, 64));
            m = fmaxf(m, __shfl_xor(m, 2, 64));
            m = fmaxf(m, __shfl_xor(m, 4, 64));
            m = fmaxf(m, __shfl_xor(m, 8, 64));
            float e = colok ? expf(v - m) : 0.f;
            float s = e;
            s += __shfl_xor(s, 1, 64);
            s += __shfl_xor(s, 2, 64);
            s += __shfl_xor(s, 4, 64);
            s += __shfl_xor(s, 8, 64);
            p[r] = e / s;
        }
        // w[ts] = sum over valid tq rows (quads 0-2 hold tq 0..11) / 12
        float ts = (quad < 3) ? (p[0] + p[1] + p[2] + p[3]) : 0.f;
        ts += __shfl_xor(ts, 16, 64);
        ts += __shfl_xor(ts, 32, 64);
        if (quad == 0) W[h * 16 + ln] = ts * (1.f / 12.f);
    }
    __syncthreads();

    // obar[d] = sum_ts w[hd][ts] * V[ts][d]
    {
        int d = lane, hd = d >> 5, dd = d & 31;
        float acc = 0.f;
        #pragma unroll
        for (int ts = 0; ts < 12; ++ts)
            acc += W[hd * 16 + ts] * lof((unsigned)base[ts * 192 + 128 + hd * 32 + dd]);
        sob[d] = acc;
    }
    __syncthreads();

    {
        int d = lane;
        float acc = opb[d];
        const float* wrow = opw + d * 64;
        #pragma unroll
        for (int k = 0; k < 64; ++k) acc += sob[k] * wrow[k];
        sha[d] = acc;
    }
    __syncthreads();

    if (lane < OUTD) {
        float acc = ob[lane];
        #pragma unroll
        for (int k = 0; k < 64; ++k) acc += sha[k] * ow[k * OUTD + lane];
        out[(size_t)node * OUTD + lane] = acc;
    }
}

// ---------------- launcher ----------------

extern "C" void kernel_launch(void* const* d_in, const int* in_sizes, int n_in,
                              void* d_out, int out_size, void* d_ws, size_t ws_size,
                              hipStream_t stream) {
    const float* x   = (const float*)d_in[0];
    const int*   ei  = (const int*)d_in[1];
    const float* ea  = (const float*)d_in[2];
    const float* Wg0 = (const float*)d_in[3];
    const float* bg0 = (const float*)d_in[4];
    const float* Wu0 = (const float*)d_in[5];
    const float* bu0 = (const float*)d_in[6];
    const float* Wr0 = (const float*)d_in[7];
    const float* br0 = (const float*)d_in[8];
    const float* Wc0 = (const float*)d_in[9];
    const float* bc0 = (const float*)d_in[10];
    const float* Wg1 = (const float*)d_in[11];
    const float* bg1 = (const float*)d_in[12];
    const float* Wu1 = (const float*)d_in[13];
    const float* bu1 = (const float*)d_in[14];
    const float* Wr1 = (const float*)d_in[15];
    const float* br1 = (const float*)d_in[16];
    const float* Wc1 = (const float*)d_in[17];
    const float* bc1 = (const float*)d_in[18];
    const float* ipw = (const float*)d_in[19];
    const float* ipb = (const float*)d_in[20];
    const float* opw = (const float*)d_in[21];
    const float* opb = (const float*)d_in[22];
    const float* ow  = (const float*)d_in[23];
    const float* ob  = (const float*)d_in[24];
    float* out = (float*)d_out;

    char* p = (char*)d_ws;
    auto alloc = [&](size_t bytes) { char* r = p; p += (bytes + 255) & ~(size_t)255; return (void*)r; };
    // persistent
    unsigned short* hseqs = (unsigned short*)alloc((size_t)TT * NN * HH * 2);
    unsigned short* h1s0  = (unsigned short*)alloc((size_t)NN * HH * 2);
    short* Wg0T = (short*)alloc((size_t)64 * 32 * 2);
    short* Wu0T = (short*)alloc((size_t)64 * 160 * 2);
    short* Wr0T = (short*)alloc((size_t)64 * 160 * 2);
    short* Wc0T = (short*)alloc((size_t)64 * 160 * 2);
    short* Wg1T = (short*)alloc((size_t)64 * 64 * 2);
    short* Wu1T = (short*)alloc((size_t)64 * 192 * 2);
    short* Wr1T = (short*)alloc((size_t)64 * 192 * 2);
    short* Wc1T = (short*)alloc((size_t)64 * 192 * 2);
    short* ipwB = (short*)alloc((size_t)192 * 64 * 2);
    float* dinv   = (float*)alloc((size_t)NN * 4);
    int*   rowptr = (int*)  alloc((size_t)(NN + 1) * 4);
    int*   colIdx = (int*)  alloc((size_t)EE * 4);
    float* valArr = (float*)alloc((size_t)EE * 4);
    // union: loop-phase buffers vs qkv (bf16, node-major, padded to 16 t-slots)
    char* ubase = p;
    unsigned short* xTs   = (unsigned short*)alloc((size_t)TT * NN * FF * 2);
    unsigned short* aggxs = (unsigned short*)alloc((size_t)TT * NN * FF * 2);
    unsigned short* g0s   = (unsigned short*)alloc((size_t)TT * NN * HH * 2);
    float* deg    = (float*)alloc((size_t)NN * 4);
    int*   cnt    = (int*)  alloc((size_t)NN * 4);
    int*   cursor = (int*)  alloc((size_t)NN * 4);
    unsigned short* y0s = (unsigned short*)alloc((size_t)NN * HH * 2);
    unsigned short* g1s = (unsigned short*)alloc((size_t)NN * HH * 2);
    float* h0f0 = (float*)alloc((size_t)NN * HH * 4);
    float* h0f1 = (float*)alloc((size_t)NN * HH * 4);
    float* h1f0 = (float*)alloc((size_t)NN * HH * 4);
    float* h1f1 = (float*)alloc((size_t)NN * HH * 4);
    unsigned short* h0s0 = (unsigned short*)alloc((size_t)NN * HH * 2);
    unsigned short* h0s1 = (unsigned short*)alloc((size_t)NN * HH * 2);
    size_t qkv_bytes = (size_t)NN * 16 * 192 * 2;
    unsigned short* qkvs = (unsigned short*)ubase;
    char* endA = p;
    char* endB = ubase + ((qkv_bytes + 255) & ~(size_t)255);
    p = (endA > endB) ? endA : endB;
    (void)ws_size;

    hipMemsetAsync(cnt, 0, (size_t)NN * 4, stream);
    hipMemsetAsync(h0f1, 0, (size_t)NN * HH * 4, stream);
    hipMemsetAsync(h1f1, 0, (size_t)NN * HH * 4, stream);
    hipMemsetAsync(h0s1, 0, (size_t)NN * HH * 2, stream);
    hipMemsetAsync(h1s0, 0, (size_t)NN * HH * 2, stream);
    deg_init_kernel<<<(NN + 255) / 256, 256, 0, stream>>>(deg);
    edge_accum_kernel<<<(EE + 255) / 256, 256, 0, stream>>>(ei, ea, deg, cnt);
    dinv_kernel<<<(NN + 255) / 256, 256, 0, stream>>>(deg, dinv);
    scan_kernel<<<1, 1024, 0, stream>>>(cnt, rowptr, cursor);
    fill_kernel<<<(EE + 255) / 256, 256, 0, stream>>>(ei, ea, dinv, cursor, colIdx, valArr);
    transpose_kernel<<<(TT * NN * FF + 255) / 256, 256, 0, stream>>>(x, xTs);
    wconv_all<<<(86016 + 255) / 256, 256, 0, stream>>>(
        Wg0, Wu0, Wr0, Wc0, Wg1, Wu1, Wr1, Wc1, ipw,
        Wg0T, Wu0T, Wr0T, Wc0T, Wg1T, Wu1T, Wr1T, Wc1T, ipwB);

    gather_raw32<<<dim3(NN / 16, TT), 256, 0, stream>>>(xTs, dinv, rowptr, colIdx, valArr, aggxs);
    mfma_g0<<<(TT * NN) / 64, 256, 0, stream>>>(aggxs, Wg0T, bg0, g0s);

    float* h0f[2] = {h0f0, h0f1};
    unsigned short* h0s[2] = {h0s0, h0s1};
    float* h1f[2] = {h1f0, h1f1};

    // C0[0]: reads zeroed buf[1], writes buf[0]
    mfma_cell0<<<CB, 256, 0, stream>>>(
        xTs, g0s, h0f[1], h0s[1], Wu0T, Wr0T, Wc0T, Wg1T, bu0, br0, bc0,
        h0f[0], h0s[0], y0s);

    for (int t = 0; t < TT; ++t) {
        gather_g1<<<NN / 8, 256, 0, stream>>>(y0s, dinv, rowptr, colIdx, valArr, bg1, g1s);
        int tn = (t < TT - 1) ? (t + 1) : t;   // dummy ptrs for t=11 (cell0 part not launched)
        int grid = (t < TT - 1) ? 2 * CB : CB;
        mfma_step<<<grid, 256, 0, stream>>>(
            h0s[t & 1], g1s, h1f[(t + 1) & 1],
            (t == 0) ? h1s0 : (hseqs + (size_t)(t - 1) * NN * HH),
            Wu1T, Wr1T, Wc1T, bu1, br1, bc1,
            h1f[t & 1], hseqs + (size_t)t * NN * HH,
            xTs + (size_t)tn * NN * FF, g0s + (size_t)tn * NN * HH, h0f[t & 1],
            Wu0T, Wr0T, Wc0T, Wg1T, bu0, br0, bc0,
            h0f[(t + 1) & 1], h0s[(t + 1) & 1], y0s);
    }

    mfma_qkv<<<(TT * NN) / 64, 256, 0, stream>>>(hseqs, ipwB, ipb, qkvs);
    attn_core<<<NN / 4, 256, 0, stream>>>(qkvs, opw, opb, ow, ob, out);
}

// Round 9
// 1004.619 us; speedup vs baseline: 22.6152x; 1.0150x over previous
//
#include <hip/hip_runtime.h>
#include <math.h>

#define NN 20000
#define FF 32
#define TT 12
#define HH 64
#define EE 320000
#define OUTD 12
#define CB 313   // ceil(NN/64)

typedef __attribute__((ext_vector_type(8))) short short8;
typedef __attribute__((ext_vector_type(4))) float floatx4;

__device__ __forceinline__ float sigmoidf_(float x) { return 1.f / (1.f + expf(-x)); }

__device__ __forceinline__ unsigned short bf16rne(float f) {
    union { float f; unsigned u; } v; v.f = f;
    unsigned u = v.u;
    u += 0x7fffu + ((u >> 16) & 1u);
    return (unsigned short)(u >> 16);
}
__device__ __forceinline__ float lof(unsigned v) {
    union { unsigned u; float f; } x; x.u = v << 16; return x.f;
}
__device__ __forceinline__ float hif(unsigned v) {
    union { unsigned u; float f; } x; x.u = v & 0xffff0000u; return x.f;
}
__device__ __forceinline__ unsigned packbf(float a, float b) {
    return (unsigned)bf16rne(a) | ((unsigned)bf16rne(b) << 16);
}

#define MFMA(a, b, c) __builtin_amdgcn_mfma_f32_16x16x32_bf16((a), (b), (c), 0, 0, 0)

// ---------------- preprocessing ----------------

__global__ void deg_init_kernel(float* deg) {
    int i = blockIdx.x * 256 + threadIdx.x;
    if (i < NN) deg[i] = 1.0f;
}

__global__ void edge_accum_kernel(const int* ei, const float* ea, float* deg, int* cnt) {
    int e = blockIdx.x * 256 + threadIdx.x;
    if (e >= EE) return;
    int d = ei[EE + e];
    float w = ea[e * 2 + 1];
    atomicAdd(&deg[d], w);
    atomicAdd(&cnt[d], 1);
}

__global__ void dinv_kernel(const float* deg, float* dinv) {
    int i = blockIdx.x * 256 + threadIdx.x;
    if (i < NN) dinv[i] = rsqrtf(deg[i]);
}

__global__ void scan_kernel(const int* cnt, int* rowptr, int* cursor) {
    __shared__ int wsum[16];
    int tid = threadIdx.x;
    int lane = tid & 63, w = tid >> 6;
    int run = 0;
    for (int base = 0; base < NN; base += 1024) {
        int idx = base + tid;
        int c = (idx < NN) ? cnt[idx] : 0;
        int v = c;
        #pragma unroll
        for (int off = 1; off < 64; off <<= 1) {
            int t = __shfl_up(v, off, 64);
            if (lane >= off) v += t;
        }
        if (lane == 63) wsum[w] = v;
        __syncthreads();
        if (tid < 16) {
            int x = wsum[tid];
            #pragma unroll
            for (int off = 1; off < 16; off <<= 1) {
                int t = __shfl_up(x, off, 64);
                if (tid >= off) x += t;
            }
            wsum[tid] = x;
        }
        __syncthreads();
        int waveoff = (w > 0) ? wsum[w - 1] : 0;
        int excl = run + waveoff + (v - c);
        if (idx < NN) { rowptr[idx] = excl; cursor[idx] = excl; }
        run += wsum[15];
        __syncthreads();
    }
    if (tid == 0) rowptr[NN] = run;
}

__global__ void fill_kernel(const int* ei, const float* ea, const float* dinv,
                            int* cursor, int* colIdx, float* valArr) {
    int e = blockIdx.x * 256 + threadIdx.x;
    if (e >= EE) return;
    int s = ei[e], d = ei[EE + e];
    float w = ea[e * 2 + 1];
    int pos = atomicAdd(&cursor[d], 1);
    colIdx[pos] = s;
    valArr[pos] = dinv[s] * w * dinv[d];
}

// x (N,F,T) fp32 -> xTs (T,N,F) bf16
__global__ void transpose_kernel(const float* x, unsigned short* xTs) {
    int i = blockIdx.x * 256 + threadIdx.x;
    if (i >= TT * NN * FF) return;
    int f = i & 31;
    int rest = i >> 5;
    int n = rest % NN;
    int t = rest / NN;
    xTs[i] = bf16rne(x[n * (FF * TT) + f * TT + t]);
}

// all 9 weight conversions in one launch; *T variants transpose (K,64)->[64][K]
__global__ void wconv_all(const float* Wg0, const float* Wu0, const float* Wr0, const float* Wc0,
                          const float* Wg1, const float* Wu1, const float* Wr1, const float* Wc1,
                          const float* ipw,
                          short* Wg0T, short* Wu0T, short* Wr0T, short* Wc0T,
                          short* Wg1T, short* Wu1T, short* Wr1T, short* Wc1T, short* ipwB) {
    int i = blockIdx.x * 256 + threadIdx.x;
    if (i < 2048) { int n = i / 32, k = i % 32; Wg0T[i] = (short)bf16rne(Wg0[k * 64 + n]); return; }
    i -= 2048;
    if (i < 10240) { int n = i / 160, k = i % 160; Wu0T[i] = (short)bf16rne(Wu0[k * 64 + n]); return; }
    i -= 10240;
    if (i < 10240) { int n = i / 160, k = i % 160; Wr0T[i] = (short)bf16rne(Wr0[k * 64 + n]); return; }
    i -= 10240;
    if (i < 10240) { int n = i / 160, k = i % 160; Wc0T[i] = (short)bf16rne(Wc0[k * 64 + n]); return; }
    i -= 10240;
    if (i < 4096) { int n = i / 64, k = i % 64; Wg1T[i] = (short)bf16rne(Wg1[k * 64 + n]); return; }
    i -= 4096;
    if (i < 12288) { int n = i / 192, k = i % 192; Wu1T[i] = (short)bf16rne(Wu1[k * 64 + n]); return; }
    i -= 12288;
    if (i < 12288) { int n = i / 192, k = i % 192; Wr1T[i] = (short)bf16rne(Wr1[k * 64 + n]); return; }
    i -= 12288;
    if (i < 12288) { int n = i / 192, k = i % 192; Wc1T[i] = (short)bf16rne(Wc1[k * 64 + n]); return; }
    i -= 12288;
    if (i < 12288) { ipwB[i] = (short)bf16rne(ipw[i]); }
}

// bf16 aggregation over x planes: 16 lanes/node, 2 features per lane
__global__ void gather_raw32(const unsigned short* __restrict__ xTs, const float* __restrict__ dinv,
                             const int* __restrict__ rowptr, const int* __restrict__ colIdx,
                             const float* __restrict__ valArr, unsigned short* __restrict__ aggxs) {
    const unsigned* src = (const unsigned*)(xTs + (size_t)blockIdx.y * NN * 32);
    unsigned* dst = (unsigned*)(aggxs + (size_t)blockIdx.y * NN * 32);
    int node = blockIdx.x * 16 + (threadIdx.x >> 4);
    int l2 = threadIdx.x & 15;
    float di = dinv[node];
    float dd = di * di;
    unsigned v = src[node * 16 + l2];
    float a0 = dd * lof(v), a1 = dd * hif(v);
    int s = rowptr[node], e = rowptr[node + 1];
    int j = s;
    for (; j + 3 < e; j += 4) {
        int c0 = colIdx[j], c1 = colIdx[j + 1], c2 = colIdx[j + 2], c3 = colIdx[j + 3];
        float w0 = valArr[j], w1 = valArr[j + 1], w2 = valArr[j + 2], w3 = valArr[j + 3];
        unsigned v0 = src[c0 * 16 + l2], v1 = src[c1 * 16 + l2];
        unsigned v2 = src[c2 * 16 + l2], v3 = src[c3 * 16 + l2];
        a0 += w0 * lof(v0) + w1 * lof(v1) + w2 * lof(v2) + w3 * lof(v3);
        a1 += w0 * hif(v0) + w1 * hif(v1) + w2 * hif(v2) + w3 * hif(v3);
    }
    for (; j < e; ++j) {
        unsigned vv = src[colIdx[j] * 16 + l2];
        float w = valArr[j];
        a0 += w * lof(vv); a1 += w * hif(vv);
    }
    dst[node * 16 + l2] = packbf(a0, a1);
}

// gather y0 (bf16) + sigmoid -> g1 (bf16): 32 lanes/node
__global__ void gather_g1(const unsigned short* __restrict__ y0s, const float* __restrict__ dinv,
                          const int* __restrict__ rowptr, const int* __restrict__ colIdx,
                          const float* __restrict__ valArr, const float* __restrict__ bg1,
                          unsigned short* __restrict__ g1s) {
    const unsigned* yp = (const unsigned*)y0s;
    int node = blockIdx.x * 8 + (threadIdx.x >> 5);
    int l2 = threadIdx.x & 31;
    float di = dinv[node];
    float dd = di * di;
    unsigned v = yp[node * 32 + l2];
    float a0 = dd * lof(v), a1 = dd * hif(v);
    int s = rowptr[node], e = rowptr[node + 1];
    int j = s;
    for (; j + 3 < e; j += 4) {
        int c0 = colIdx[j], c1 = colIdx[j + 1], c2 = colIdx[j + 2], c3 = colIdx[j + 3];
        float w0 = valArr[j], w1 = valArr[j + 1], w2 = valArr[j + 2], w3 = valArr[j + 3];
        unsigned v0 = yp[c0 * 32 + l2], v1 = yp[c1 * 32 + l2];
        unsigned v2 = yp[c2 * 32 + l2], v3 = yp[c3 * 32 + l2];
        a0 += w0 * lof(v0) + w1 * lof(v1) + w2 * lof(v2) + w3 * lof(v3);
        a1 += w0 * hif(v0) + w1 * hif(v1) + w2 * hif(v2) + w3 * hif(v3);
    }
    for (; j < e; ++j) {
        unsigned vv = yp[colIdx[j] * 32 + l2];
        float w = valArr[j];
        a0 += w * lof(vv); a1 += w * hif(vv);
    }
    float g0v = sigmoidf_(a0 + bg1[2 * l2]);
    float g1v = sigmoidf_(a1 + bg1[2 * l2 + 1]);
    ((unsigned*)g1s)[node * 32 + l2] = packbf(g0v, g1v);
}

// ---------------- MFMA kernels ----------------
// A[m=lane&15][k=quad*8+j]; B^T[n=lane&15][k=quad*8+j]; C/D: col=lane&15, row=quad*4+reg.

// g0all = sigmoid(aggx @ Wg0 + bg0) -> bf16, rows = T*N, K=32
__launch_bounds__(256, 4)
__global__ void mfma_g0(const unsigned short* __restrict__ aggxs, const short* __restrict__ Wg0T,
                        const float* __restrict__ bg0, unsigned short* __restrict__ g0s) {
    int tid = threadIdx.x;
    int wv = tid >> 6, lane = tid & 63;
    int quad = lane >> 4, ln = lane & 15;
    int m0 = blockIdx.x * 64 + wv * 16;
    short8 af = *reinterpret_cast<const short8*>(aggxs + (size_t)(m0 + ln) * 32 + quad * 8);
    floatx4 z = {0.f, 0.f, 0.f, 0.f};
    floatx4 acc[4] = {z, z, z, z};
    #pragma unroll
    for (int ct = 0; ct < 4; ++ct) {
        short8 bf = *reinterpret_cast<const short8*>(Wg0T + (size_t)(ct * 16 + ln) * 32 + quad * 8);
        acc[ct] = MFMA(af, bf, acc[ct]);
    }
    #pragma unroll
    for (int ct = 0; ct < 4; ++ct) {
        int col = ct * 16 + ln;
        float bb = bg0[col];
        #pragma unroll
        for (int r = 0; r < 4; ++r) {
            int row = m0 + quad * 4 + r;
            g0s[(size_t)row * 64 + col] = bf16rne(sigmoidf_(acc[ct][r] + bb));
        }
    }
}

// ---- cell bodies (per-wave 16-row tile, wave-private LDS slice T; no block barriers) ----

__device__ __forceinline__ void cell0_body(
    int m0, short* T,
    const unsigned short* __restrict__ xt, const unsigned short* __restrict__ g0,
    const float* __restrict__ h0f, const unsigned short* __restrict__ h0s,
    const short* __restrict__ Wu0T, const short* __restrict__ Wr0T,
    const short* __restrict__ Wc0T, const short* __restrict__ Wg1T,
    const float* __restrict__ bu0, const float* __restrict__ br0,
    const float* __restrict__ bc0,
    float* __restrict__ h0nf, unsigned short* __restrict__ h0ns,
    unsigned short* __restrict__ y0s) {
    int lane = threadIdx.x & 63;
    int quad = lane >> 4, ln = lane & 15;
    int arow = m0 + ln; if (arow > NN - 1) arow = NN - 1;

    short8 af[5];
    af[0] = *reinterpret_cast<const short8*>(xt + (size_t)arow * 32 + quad * 8);
    af[1] = *reinterpret_cast<const short8*>(g0 + (size_t)arow * 64 + quad * 8);
    af[2] = *reinterpret_cast<const short8*>(g0 + (size_t)arow * 64 + 32 + quad * 8);
    af[3] = *reinterpret_cast<const short8*>(h0s + (size_t)arow * 64 + quad * 8);
    af[4] = *reinterpret_cast<const short8*>(h0s + (size_t)arow * 64 + 32 + quad * 8);

    floatx4 z = {0.f, 0.f, 0.f, 0.f};
    floatx4 aU[4] = {z, z, z, z};
    floatx4 aR[4] = {z, z, z, z};
    #pragma unroll
    for (int ct = 0; ct < 4; ++ct) {
        const short* bu = Wu0T + (size_t)(ct * 16 + ln) * 160;
        const short* br = Wr0T + (size_t)(ct * 16 + ln) * 160;
        #pragma unroll
        for (int kc = 0; kc < 5; ++kc) {
            int ko = kc * 32 + quad * 8;
            aU[ct] = MFMA(af[kc], *reinterpret_cast<const short8*>(bu + ko), aU[ct]);
            aR[ct] = MFMA(af[kc], *reinterpret_cast<const short8*>(br + ko), aR[ct]);
        }
    }
    float uu[4][4];
    #pragma unroll
    for (int ct = 0; ct < 4; ++ct) {
        int col = ct * 16 + ln;
        float bU = bu0[col], bR = br0[col];
        #pragma unroll
        for (int r = 0; r < 4; ++r) {
            int grow = m0 + quad * 4 + r;
            bool ok = grow < NN;
            uu[ct][r] = sigmoidf_(aU[ct][r] + bU);
            float hv = ok ? h0f[(size_t)grow * 64 + col] : 0.f;
            float rh = sigmoidf_(aR[ct][r] + bR) * hv;
            T[(quad * 4 + r) * 72 + col] = (short)bf16rne(rh);
        }
    }
    __threadfence_block();   // wave-private LDS: order only, no block convoy

    short8 ar0 = *reinterpret_cast<const short8*>(T + ln * 72 + quad * 8);
    short8 ar1 = *reinterpret_cast<const short8*>(T + ln * 72 + 32 + quad * 8);
    floatx4 aC[4] = {z, z, z, z};
    #pragma unroll
    for (int ct = 0; ct < 4; ++ct) {
        const short* bc = Wc0T + (size_t)(ct * 16 + ln) * 160;
        #pragma unroll
        for (int kc = 0; kc < 3; ++kc)
            aC[ct] = MFMA(af[kc], *reinterpret_cast<const short8*>(bc + kc * 32 + quad * 8), aC[ct]);
        aC[ct] = MFMA(ar0, *reinterpret_cast<const short8*>(bc + 96 + quad * 8), aC[ct]);
        aC[ct] = MFMA(ar1, *reinterpret_cast<const short8*>(bc + 128 + quad * 8), aC[ct]);
    }
    __threadfence_block();
    #pragma unroll
    for (int ct = 0; ct < 4; ++ct) {
        int col = ct * 16 + ln;
        float bC = bc0[col];
        #pragma unroll
        for (int r = 0; r < 4; ++r) {
            int grow = m0 + quad * 4 + r;
            bool ok = grow < NN;
            float hv = ok ? h0f[(size_t)grow * 64 + col] : 0.f;
            float cv = tanhf(aC[ct][r] + bC);
            float hn = uu[ct][r] * hv + (1.f - uu[ct][r]) * cv;
            unsigned short hb = bf16rne(hn);
            if (ok) {
                h0nf[(size_t)grow * 64 + col] = hn;
                h0ns[(size_t)grow * 64 + col] = hb;
            }
            T[(quad * 4 + r) * 72 + col] = (short)hb;
        }
    }
    __threadfence_block();

    short8 ah0 = *reinterpret_cast<const short8*>(T + ln * 72 + quad * 8);
    short8 ah1 = *reinterpret_cast<const short8*>(T + ln * 72 + 32 + quad * 8);
    floatx4 aY[4] = {z, z, z, z};
    #pragma unroll
    for (int ct = 0; ct < 4; ++ct) {
        const short* bg = Wg1T + (size_t)(ct * 16 + ln) * 64;
        aY[ct] = MFMA(ah0, *reinterpret_cast<const short8*>(bg + quad * 8), aY[ct]);
        aY[ct] = MFMA(ah1, *reinterpret_cast<const short8*>(bg + 32 + quad * 8), aY[ct]);
    }
    #pragma unroll
    for (int ct = 0; ct < 4; ++ct) {
        int col = ct * 16 + ln;
        #pragma unroll
        for (int r = 0; r < 4; ++r) {
            int grow = m0 + quad * 4 + r;
            if (grow < NN) y0s[(size_t)grow * 64 + col] = bf16rne(aY[ct][r]);
        }
    }
}

__device__ __forceinline__ void cell1_body(
    int m0, short* T,
    const unsigned short* __restrict__ h0s, const unsigned short* __restrict__ g1s,
    const float* __restrict__ h1f, const unsigned short* __restrict__ h1s,
    const short* __restrict__ Wu1T, const short* __restrict__ Wr1T,
    const short* __restrict__ Wc1T,
    const float* __restrict__ bu1, const float* __restrict__ br1,
    const float* __restrict__ bc1,
    float* __restrict__ h1nf, unsigned short* __restrict__ h1ns) {
    int lane = threadIdx.x & 63;
    int quad = lane >> 4, ln = lane & 15;
    int arow = m0 + ln; if (arow > NN - 1) arow = NN - 1;

    short8 af[6];
    af[0] = *reinterpret_cast<const short8*>(h0s + (size_t)arow * 64 + quad * 8);
    af[1] = *reinterpret_cast<const short8*>(h0s + (size_t)arow * 64 + 32 + quad * 8);
    af[2] = *reinterpret_cast<const short8*>(g1s + (size_t)arow * 64 + quad * 8);
    af[3] = *reinterpret_cast<const short8*>(g1s + (size_t)arow * 64 + 32 + quad * 8);
    af[4] = *reinterpret_cast<const short8*>(h1s + (size_t)arow * 64 + quad * 8);
    af[5] = *reinterpret_cast<const short8*>(h1s + (size_t)arow * 64 + 32 + quad * 8);

    floatx4 z = {0.f, 0.f, 0.f, 0.f};
    floatx4 aU[4] = {z, z, z, z};
    floatx4 aR[4] = {z, z, z, z};
    #pragma unroll
    for (int ct = 0; ct < 4; ++ct) {
        const short* bu = Wu1T + (size_t)(ct * 16 + ln) * 192;
        const short* br = Wr1T + (size_t)(ct * 16 + ln) * 192;
        #pragma unroll
        for (int kc = 0; kc < 6; ++kc) {
            int ko = kc * 32 + quad * 8;
            aU[ct] = MFMA(af[kc], *reinterpret_cast<const short8*>(bu + ko), aU[ct]);
            aR[ct] = MFMA(af[kc], *reinterpret_cast<const short8*>(br + ko), aR[ct]);
        }
    }
    float uu[4][4];
    #pragma unroll
    for (int ct = 0; ct < 4; ++ct) {
        int col = ct * 16 + ln;
        float bU = bu1[col], bR = br1[col];
        #pragma unroll
        for (int r = 0; r < 4; ++r) {
            int grow = m0 + quad * 4 + r;
            bool ok = grow < NN;
            uu[ct][r] = sigmoidf_(aU[ct][r] + bU);
            float hv = ok ? h1f[(size_t)grow * 64 + col] : 0.f;
            float rh = sigmoidf_(aR[ct][r] + bR) * hv;
            T[(quad * 4 + r) * 72 + col] = (short)bf16rne(rh);
        }
    }
    __threadfence_block();

    short8 ar0 = *reinterpret_cast<const short8*>(T + ln * 72 + quad * 8);
    short8 ar1 = *reinterpret_cast<const short8*>(T + ln * 72 + 32 + quad * 8);
    floatx4 aC[4] = {z, z, z, z};
    #pragma unroll
    for (int ct = 0; ct < 4; ++ct) {
        const short* bc = Wc1T + (size_t)(ct * 16 + ln) * 192;
        #pragma unroll
        for (int kc = 0; kc < 4; ++kc)
            aC[ct] = MFMA(af[kc], *reinterpret_cast<const short8*>(bc + kc * 32 + quad * 8), aC[ct]);
        aC[ct] = MFMA(ar0, *reinterpret_cast<const short8*>(bc + 128 + quad * 8), aC[ct]);
        aC[ct] = MFMA(ar1, *reinterpret_cast<const short8*>(bc + 160 + quad * 8), aC[ct]);
    }
    #pragma unroll
    for (int ct = 0; ct < 4; ++ct) {
        int col = ct * 16 + ln;
        float bC = bc1[col];
        #pragma unroll
        for (int r = 0; r < 4; ++r) {
            int grow = m0 + quad * 4 + r;
            if (grow >= NN) continue;
            float hv = h1f[(size_t)grow * 64 + col];
            float cv = tanhf(aC[ct][r] + bC);
            float hn = uu[ct][r] * hv + (1.f - uu[ct][r]) * cv;
            h1nf[(size_t)grow * 64 + col] = hn;
            h1ns[(size_t)grow * 64 + col] = bf16rne(hn);
        }
    }
}

// standalone cell0 (t=0 bootstrap)
__launch_bounds__(256, 4)
__global__ void mfma_cell0(const unsigned short* xt, const unsigned short* g0,
                           const float* h0f, const unsigned short* h0s,
                           const short* Wu0T, const short* Wr0T, const short* Wc0T, const short* Wg1T,
                           const float* bu0, const float* br0, const float* bc0,
                           float* h0nf, unsigned short* h0ns, unsigned short* y0s) {
    __shared__ short lds[4 * 16 * 72];
    int wv = threadIdx.x >> 6;
    cell0_body(blockIdx.x * 64 + wv * 16, lds + wv * (16 * 72),
               xt, g0, h0f, h0s, Wu0T, Wr0T, Wc0T, Wg1T, bu0, br0, bc0, h0nf, h0ns, y0s);
}

// merged step: blocks [0,CB) = cell1 for t; blocks [CB,2CB) = cell0 for t+1 (independent)
__launch_bounds__(256, 4)
__global__ void mfma_step(
    const unsigned short* h0s_cur, const unsigned short* g1s,
    const float* h1f_in, const unsigned short* h1s_in,
    const short* Wu1T, const short* Wr1T, const short* Wc1T,
    const float* bu1, const float* br1, const float* bc1,
    float* h1f_out, unsigned short* h1s_out,
    const unsigned short* xt_next, const unsigned short* g0_next, const float* h0f_cur,
    const short* Wu0T, const short* Wr0T, const short* Wc0T, const short* Wg1T,
    const float* bu0, const float* br0, const float* bc0,
    float* h0f_next, unsigned short* h0s_next, unsigned short* y0s) {
    __shared__ short lds[4 * 16 * 72];
    int wv = threadIdx.x >> 6;
    short* T = lds + wv * (16 * 72);
    if (blockIdx.x < CB) {
        cell1_body(blockIdx.x * 64 + wv * 16, T, h0s_cur, g1s, h1f_in, h1s_in,
                   Wu1T, Wr1T, Wc1T, bu1, br1, bc1, h1f_out, h1s_out);
    } else {
        cell0_body((blockIdx.x - CB) * 64 + wv * 16, T, xt_next, g0_next, h0f_cur, h0s_cur,
                   Wu0T, Wr0T, Wc0T, Wg1T, bu0, br0, bc0, h0f_next, h0s_next, y0s);
    }
}

// ---------------- fused qkv + attention: one wave per node ----------------
// Per wave: qkv tile (16 t-slots x 192) via MFMA from hseqs -> per-wave LDS (stride 200),
// then scores MFMA + shuffle softmax + PV + projections. No block barriers (wave-private LDS).
__launch_bounds__(256, 4)
__global__ void attn_fused(const unsigned short* __restrict__ hseqs,
                           const short* __restrict__ ipwB, const float* __restrict__ ipb,
                           const float* __restrict__ opw, const float* __restrict__ opb,
                           const float* __restrict__ ow, const float* __restrict__ ob,
                           float* __restrict__ out) {
    __shared__ unsigned short qtile[4][16 * 200];   // stride 200 shorts = 400B -> 2-way bank aliasing (free)
    __shared__ float fbuf[4][176];
    int wv = threadIdx.x >> 6, lane = threadIdx.x & 63;
    int node = blockIdx.x * 4 + wv;
    int quad = lane >> 4, ln = lane & 15;
    unsigned short* q = qtile[wv];
    float* W   = fbuf[wv];       // [2][16] head-major mean-prob weights
    float* sob = W + 32;         // obar[64]
    float* sha = W + 96;         // h_attn[64]

    // ---- qkv tile: A[m=t=ln][k] = hseq[ln][node][k] (zero rows for ln>=12) ----
    short8 zero8 = {0, 0, 0, 0, 0, 0, 0, 0};
    short8 af0 = zero8, af1 = zero8;
    if (ln < TT) {
        const unsigned short* hp = hseqs + ((size_t)ln * NN + node) * 64;
        af0 = *reinterpret_cast<const short8*>(hp + quad * 8);
        af1 = *reinterpret_cast<const short8*>(hp + 32 + quad * 8);
    }
    floatx4 z = {0.f, 0.f, 0.f, 0.f};
    #pragma unroll
    for (int ct = 0; ct < 12; ++ct) {
        const short* br = ipwB + (size_t)(ct * 16 + ln) * 64;
        floatx4 acc = MFMA(af0, *reinterpret_cast<const short8*>(br + quad * 8), z);
        acc = MFMA(af1, *reinterpret_cast<const short8*>(br + 32 + quad * 8), acc);
        int col = ct * 16 + ln;
        float bb = ipb[col];
        #pragma unroll
        for (int r = 0; r < 4; ++r)
            q[(quad * 4 + r) * 200 + col] = bf16rne(acc[r] + bb);
    }
    __threadfence_block();

    // ---- scores: S[tq][ts] per head via one MFMA each ----
    floatx4 sc[2];
    #pragma unroll
    for (int h = 0; h < 2; ++h) {
        short8 aQ = *reinterpret_cast<const short8*>(q + ln * 200 + h * 32 + quad * 8);
        short8 bK = *reinterpret_cast<const short8*>(q + ln * 200 + 64 + h * 32 + quad * 8);
        sc[h] = MFMA(aQ, bK, z);   // rows=tq(quad*4+r), cols=ts(ln)
    }
    const float scl = 0.17677669529663687f;   // 1/sqrt(32)
    bool colok = ln < 12;
    #pragma unroll
    for (int h = 0; h < 2; ++h) {
        float p[4];
        #pragma unroll
        for (int r = 0; r < 4; ++r) {
            float v = colok ? sc[h][r] * scl : -1e30f;
            float m = v;
            m = fmaxf(m, __shfl_xor(m, 1, 64));
            m = fmaxf(m, __shfl_xor(m, 2, 64));
            m = fmaxf(m, __shfl_xor(m, 4, 64));
            m = fmaxf(m, __shfl_xor(m, 8, 64));
            float e = colok ? expf(v - m) : 0.f;
            float s = e;
            s += __shfl_xor(s, 1, 64);
            s += __shfl_xor(s, 2, 64);
            s += __shfl_xor(s, 4, 64);
            s += __shfl_xor(s, 8, 64);
            p[r] = e / s;
        }
        float ts = (quad < 3) ? (p[0] + p[1] + p[2] + p[3]) : 0.f;   // tq 0..11 only
        ts += __shfl_xor(ts, 16, 64);
        ts += __shfl_xor(ts, 32, 64);
        if (quad == 0) W[h * 16 + ln] = ts * (1.f / 12.f);
    }
    __threadfence_block();

    // ---- obar[d] = sum_ts w[hd][ts] * V[ts][d] (V from LDS) ----
    {
        int d = lane, hd = d >> 5, dd = d & 31;
        float acc = 0.f;
        #pragma unroll
        for (int ts = 0; ts < 12; ++ts)
            acc += W[hd * 16 + ts] * lof((unsigned)q[ts * 200 + 128 + hd * 32 + dd]);
        sob[d] = acc;
    }
    __threadfence_block();

    {
        int d = lane;
        float acc = opb[d];
        const float* wrow = opw + d * 64;
        #pragma unroll
        for (int k = 0; k < 64; ++k) acc += sob[k] * wrow[k];
        sha[d] = acc;
    }
    __threadfence_block();

    if (lane < OUTD) {
        float acc = ob[lane];
        #pragma unroll
        for (int k = 0; k < 64; ++k) acc += sha[k] * ow[k * OUTD + lane];
        out[(size_t)node * OUTD + lane] = acc;
    }
}

// ---------------- launcher ----------------

extern "C" void kernel_launch(void* const* d_in, const int* in_sizes, int n_in,
                              void* d_out, int out_size, void* d_ws, size_t ws_size,
                              hipStream_t stream) {
    const float* x   = (const float*)d_in[0];
    const int*   ei  = (const int*)d_in[1];
    const float* ea  = (const float*)d_in[2];
    const float* Wg0 = (const float*)d_in[3];
    const float* bg0 = (const float*)d_in[4];
    const float* Wu0 = (const float*)d_in[5];
    const float* bu0 = (const float*)d_in[6];
    const float* Wr0 = (const float*)d_in[7];
    const float* br0 = (const float*)d_in[8];
    const float* Wc0 = (const float*)d_in[9];
    const float* bc0 = (const float*)d_in[10];
    const float* Wg1 = (const float*)d_in[11];
    const float* bg1 = (const float*)d_in[12];
    const float* Wu1 = (const float*)d_in[13];
    const float* bu1 = (const float*)d_in[14];
    const float* Wr1 = (const float*)d_in[15];
    const float* br1 = (const float*)d_in[16];
    const float* Wc1 = (const float*)d_in[17];
    const float* bc1 = (const float*)d_in[18];
    const float* ipw = (const float*)d_in[19];
    const float* ipb = (const float*)d_in[20];
    const float* opw = (const float*)d_in[21];
    const float* opb = (const float*)d_in[22];
    const float* ow  = (const float*)d_in[23];
    const float* ob  = (const float*)d_in[24];
    float* out = (float*)d_out;

    char* p = (char*)d_ws;
    auto alloc = [&](size_t bytes) { char* r = p; p += (bytes + 255) & ~(size_t)255; return (void*)r; };
    // persistent
    unsigned short* hseqs = (unsigned short*)alloc((size_t)TT * NN * HH * 2);
    unsigned short* h1s0  = (unsigned short*)alloc((size_t)NN * HH * 2);
    short* Wg0T = (short*)alloc((size_t)64 * 32 * 2);
    short* Wu0T = (short*)alloc((size_t)64 * 160 * 2);
    short* Wr0T = (short*)alloc((size_t)64 * 160 * 2);
    short* Wc0T = (short*)alloc((size_t)64 * 160 * 2);
    short* Wg1T = (short*)alloc((size_t)64 * 64 * 2);
    short* Wu1T = (short*)alloc((size_t)64 * 192 * 2);
    short* Wr1T = (short*)alloc((size_t)64 * 192 * 2);
    short* Wc1T = (short*)alloc((size_t)64 * 192 * 2);
    short* ipwB = (short*)alloc((size_t)192 * 64 * 2);
    float* dinv   = (float*)alloc((size_t)NN * 4);
    int*   rowptr = (int*)  alloc((size_t)(NN + 1) * 4);
    int*   colIdx = (int*)  alloc((size_t)EE * 4);
    float* valArr = (float*)alloc((size_t)EE * 4);
    unsigned short* xTs   = (unsigned short*)alloc((size_t)TT * NN * FF * 2);
    unsigned short* aggxs = (unsigned short*)alloc((size_t)TT * NN * FF * 2);
    unsigned short* g0s   = (unsigned short*)alloc((size_t)TT * NN * HH * 2);
    float* deg    = (float*)alloc((size_t)NN * 4);
    int*   cnt    = (int*)  alloc((size_t)NN * 4);
    int*   cursor = (int*)  alloc((size_t)NN * 4);
    unsigned short* y0s = (unsigned short*)alloc((size_t)NN * HH * 2);
    unsigned short* g1s = (unsigned short*)alloc((size_t)NN * HH * 2);
    float* h0f0 = (float*)alloc((size_t)NN * HH * 4);
    float* h0f1 = (float*)alloc((size_t)NN * HH * 4);
    float* h1f0 = (float*)alloc((size_t)NN * HH * 4);
    float* h1f1 = (float*)alloc((size_t)NN * HH * 4);
    unsigned short* h0s0 = (unsigned short*)alloc((size_t)NN * HH * 2);
    unsigned short* h0s1 = (unsigned short*)alloc((size_t)NN * HH * 2);
    (void)ws_size;

    hipMemsetAsync(cnt, 0, (size_t)NN * 4, stream);
    hipMemsetAsync(h0f1, 0, (size_t)NN * HH * 4, stream);
    hipMemsetAsync(h1f1, 0, (size_t)NN * HH * 4, stream);
    hipMemsetAsync(h0s1, 0, (size_t)NN * HH * 2, stream);
    hipMemsetAsync(h1s0, 0, (size_t)NN * HH * 2, stream);
    deg_init_kernel<<<(NN + 255) / 256, 256, 0, stream>>>(deg);
    edge_accum_kernel<<<(EE + 255) / 256, 256, 0, stream>>>(ei, ea, deg, cnt);
    dinv_kernel<<<(NN + 255) / 256, 256, 0, stream>>>(deg, dinv);
    scan_kernel<<<1, 1024, 0, stream>>>(cnt, rowptr, cursor);
    fill_kernel<<<(EE + 255) / 256, 256, 0, stream>>>(ei, ea, dinv, cursor, colIdx, valArr);
    transpose_kernel<<<(TT * NN * FF + 255) / 256, 256, 0, stream>>>(x, xTs);
    wconv_all<<<(86016 + 255) / 256, 256, 0, stream>>>(
        Wg0, Wu0, Wr0, Wc0, Wg1, Wu1, Wr1, Wc1, ipw,
        Wg0T, Wu0T, Wr0T, Wc0T, Wg1T, Wu1T, Wr1T, Wc1T, ipwB);

    gather_raw32<<<dim3(NN / 16, TT), 256, 0, stream>>>(xTs, dinv, rowptr, colIdx, valArr, aggxs);
    mfma_g0<<<(TT * NN) / 64, 256, 0, stream>>>(aggxs, Wg0T, bg0, g0s);

    float* h0f[2] = {h0f0, h0f1};
    unsigned short* h0s[2] = {h0s0, h0s1};
    float* h1f[2] = {h1f0, h1f1};

    // C0[0]: reads zeroed buf[1], writes buf[0]
    mfma_cell0<<<CB, 256, 0, stream>>>(
        xTs, g0s, h0f[1], h0s[1], Wu0T, Wr0T, Wc0T, Wg1T, bu0, br0, bc0,
        h0f[0], h0s[0], y0s);

    for (int t = 0; t < TT; ++t) {
        gather_g1<<<NN / 8, 256, 0, stream>>>(y0s, dinv, rowptr, colIdx, valArr, bg1, g1s);
        int tn = (t < TT - 1) ? (t + 1) : t;   // dummy ptrs for t=11 (cell0 part not launched)
        int grid = (t < TT - 1) ? 2 * CB : CB;
        mfma_step<<<grid, 256, 0, stream>>>(
            h0s[t & 1], g1s, h1f[(t + 1) & 1],
            (t == 0) ? h1s0 : (hseqs + (size_t)(t - 1) * NN * HH),
            Wu1T, Wr1T, Wc1T, bu1, br1, bc1,
            h1f[t & 1], hseqs + (size_t)t * NN * HH,
            xTs + (size_t)tn * NN * FF, g0s + (size_t)tn * NN * HH, h0f[t & 1],
            Wu0T, Wr0T, Wc0T, Wg1T, bu0, br0, bc0,
            h0f[(t + 1) & 1], h0s[(t + 1) & 1], y0s);
    }

    attn_fused<<<NN / 4, 256, 0, stream>>>(hseqs, ipwB, ipb, opw, opb, ow, ob, out);
}